// Round 1
// baseline (1097.158 us; speedup 1.0000x reference)
//
#include <hip/hip_runtime.h>
#include <math.h>

#define B_    2
#define L_    2048
#define HID_  1024
#define H_    4
#define DK_   64
#define RATIO_ 4
#define HE_   16
#define DV_   128
#define T_    64
#define NC_   32   // L_/T_

__device__ __forceinline__ float sigmoidf_(float x){ return 1.f/(1.f+expf(-x)); }

// ---------------- generic f32 GEMM: C(MxN) = A(MxK) * B(NxK)^T ----------------
__global__ __launch_bounds__(256) void gemm_f32(const float* __restrict__ A, int lda,
    const float* __restrict__ Bm, int ldb, float* __restrict__ C, int ldc,
    int M, int N, int K)
{
  __shared__ float As[32][64];
  __shared__ float Bs[32][64];
  const int tid = threadIdx.x;
  const int row0 = blockIdx.y * 64;
  const int col0 = blockIdx.x * 64;
  const int tx = tid & 15, ty = tid >> 4;
  float acc[4][4] = {};
  for (int k0 = 0; k0 < K; k0 += 32) {
    #pragma unroll
    for (int ld = 0; ld < 2; ld++) {
      int id = tid + ld*256;
      int r  = id >> 3;          // 0..63
      int k4 = (id & 7) << 2;    // 0,4,...,28
      float4 av = *reinterpret_cast<const float4*>(&A[(size_t)(row0+r)*lda + k0 + k4]);
      As[k4+0][r] = av.x; As[k4+1][r] = av.y; As[k4+2][r] = av.z; As[k4+3][r] = av.w;
      float4 bv = make_float4(0.f,0.f,0.f,0.f);
      if (col0 + r < N) bv = *reinterpret_cast<const float4*>(&Bm[(size_t)(col0+r)*ldb + k0 + k4]);
      Bs[k4+0][r] = bv.x; Bs[k4+1][r] = bv.y; Bs[k4+2][r] = bv.z; Bs[k4+3][r] = bv.w;
    }
    __syncthreads();
    #pragma unroll
    for (int kk = 0; kk < 32; kk++) {
      float4 a4 = *reinterpret_cast<const float4*>(&As[kk][ty*4]);
      float4 b4 = *reinterpret_cast<const float4*>(&Bs[kk][tx*4]);
      float a[4] = {a4.x,a4.y,a4.z,a4.w};
      float b[4] = {b4.x,b4.y,b4.z,b4.w};
      #pragma unroll
      for (int i=0;i<4;i++)
        #pragma unroll
        for (int j=0;j<4;j++) acc[i][j] += a[i]*b[j];
    }
    __syncthreads();
  }
  #pragma unroll
  for (int i=0;i<4;i++) {
    int r = row0 + ty*4 + i;
    #pragma unroll
    for (int j=0;j<4;j++) {
      int cc = col0 + tx*4 + j;
      if (cc < N) C[(size_t)r*ldc + cc] = acc[i][j];
    }
  }
}

// ---------------- causal depthwise conv (KS=4) + SiLU ----------------
__global__ __launch_bounds__(256) void conv_silu(const float* __restrict__ in,
    const float* __restrict__ w, float* __restrict__ out, int C, int total)
{
  int n = blockIdx.x*256 + threadIdx.x;
  if (n >= total) return;
  int c = n % C;
  int t = (n / C) % L_;
  int b = n / (C*L_);
  size_t base = (size_t)b*L_*C + c;
  float acc = 0.f;
  #pragma unroll
  for (int s = 0; s < 4; s++) {
    int tt = t - 3 + s;
    if (tt >= 0) acc += in[base + (size_t)tt*C] * w[c*4+s];
  }
  out[n] = acc * sigmoidf_(acc);
}

// ---------------- routing (softmax over 3, top-2, tie->lower idx) + beta + g ----------------
__global__ __launch_bounds__(256) void routing(const float* __restrict__ qc,
    const float* __restrict__ b_lin, const float* __restrict__ a_lin,
    const float* __restrict__ Wg3, const float* __restrict__ A_log,
    const float* __restrict__ dt_bias, float* __restrict__ w_buf,
    float* __restrict__ bt_buf, float* __restrict__ g_buf)
{
  int n = blockIdx.x*256 + threadIdx.x;   // (b*L+l)*H + h, exactly 16384 threads
  int h  = n & 3;
  int bl = n >> 2;
  const float* q = qc + (size_t)bl*256 + h*64;
  float l0=0.f, l1=0.f, l2=0.f;
  for (int d=0; d<64; d++) {
    float qd = q[d];
    l0 += qd*Wg3[d]; l1 += qd*Wg3[64+d]; l2 += qd*Wg3[128+d];
  }
  float mx = fmaxf(l0, fmaxf(l1, l2));
  float e0 = expf(l0-mx), e1 = expf(l1-mx), e2 = expf(l2-mx);
  float inv_s = 1.f/(e0+e1+e2);
  float p0 = e0*inv_s, p1 = e1*inv_s, p2 = e2*inv_s;
  // top-1 (strict > keeps lower index on ties, matching jax top_k)
  int m1 = 0; float pm1 = p0;
  if (p1 > pm1) { m1 = 1; pm1 = p1; }
  if (p2 > pm1) { m1 = 2; pm1 = p2; }
  // top-2 among remaining two indices (ia < ib)
  int ia = (m1==0) ? 1 : 0;
  int ib = (m1==2) ? 1 : 2;
  float pa = (m1==0) ? p1 : p0;
  float pb = (m1==2) ? p1 : p2;
  int   m2  = (pb > pa) ? ib : ia;
  float pm2 = (pb > pa) ? pb : pa;
  float inv_w = 1.f/(pm1 + pm2);
  float w1 = 0.5f*pm1*inv_w;
  float w2 = 0.5f*pm2*inv_w;
  #pragma unroll
  for (int r = 0; r < 4; r++) {
    float wr = (r==0) ? 0.5f : (((r-1)==m1) ? w1 : (((r-1)==m2) ? w2 : 0.f));
    int he = h*4 + r;
    size_t gi = (size_t)bl*16 + he;
    w_buf[gi] = wr;
    float mask = (wr > 0.f) ? 1.f : 0.f;
    bt_buf[gi] = mask * sigmoidf_(b_lin[gi]);
    float av = a_lin[gi] + dt_bias[he];
    float sp = fmaxf(av, 0.f) + log1pf(expf(-fabsf(av)));
    g_buf[gi] = -expf(A_log[he]) * sp * mask;
  }
}

// ---------------- l2norm over rows of 64 (one wave per row) ----------------
__global__ __launch_bounds__(256) void l2norm_rows(float* __restrict__ v, float scale)
{
  int row  = blockIdx.x*4 + (threadIdx.x >> 6);
  int lane = threadIdx.x & 63;
  size_t idx = (size_t)row*64 + lane;
  float x = v[idx];
  float ss = x*x;
  #pragma unroll
  for (int off = 32; off > 0; off >>= 1) ss += __shfl_xor(ss, off);
  v[idx] = x * rsqrtf(ss + 1e-6f) * scale;
}

// ---------------- pass A: per-chunk recurrence from zero + transition matrix ----------------
// 192 threads: lanes 0..127 = value columns (S0, o0), lanes 128..191 = M columns (Mc, q~)
__global__ __launch_bounds__(192) void scan_chunk(
    const float* __restrict__ ke, const float* __restrict__ qe,
    const float* __restrict__ vc, const float* __restrict__ bt_buf,
    const float* __restrict__ g_buf, float* __restrict__ o_r,
    float* __restrict__ Qt, float* __restrict__ Mc, float* __restrict__ Bc)
{
  const int c  = blockIdx.x;
  const int he = blockIdx.y;
  const int b  = blockIdx.z;
  const int bhe = b*HE_ + he;
  const int h = he >> 2;
  __shared__ float Kl[T_*64];
  __shared__ float Ql[T_*64];
  __shared__ float EG[T_];
  __shared__ float BT[T_];
  const int tid = threadIdx.x;
  const size_t l0 = (size_t)b*L_ + (size_t)c*T_;
  for (int id = tid; id < T_*16; id += 192) {
    int t = id >> 4, d4 = (id & 15) << 2;
    size_t gi = ((l0 + t)*HE_ + he)*64 + d4;
    *reinterpret_cast<float4*>(&Kl[t*64 + d4]) = *reinterpret_cast<const float4*>(&ke[gi]);
    *reinterpret_cast<float4*>(&Ql[t*64 + d4]) = *reinterpret_cast<const float4*>(&qe[gi]);
  }
  if (tid < T_) {
    size_t gi = (l0 + tid)*HE_ + he;
    EG[tid] = expf(g_buf[gi]);
    BT[tid] = bt_buf[gi];
  }
  __syncthreads();
  const float4* K4 = reinterpret_cast<const float4*>(Kl);
  const float4* Q4 = reinterpret_cast<const float4*>(Ql);
  const bool isB = tid < 128;
  const int mcol = tid - 128;
  float S[64];
  #pragma unroll
  for (int i=0;i<64;i++) S[i] = (!isB && i==mcol) ? 1.f : 0.f;

  if (isB) {
    const int j = tid;
    for (int t = 0; t < T_; t++) {
      float eg = EG[t], bt = BT[t];
      float vj = vc[(l0 + t)*(H_*DV_) + h*DV_ + j];
      float4 kf[16];
      #pragma unroll
      for (int i=0;i<16;i++) kf[i] = K4[t*16+i];
      float d0=0,d1=0,d2=0,d3=0;
      #pragma unroll
      for (int i=0;i<16;i++){
        d0 += kf[i].x*S[4*i+0]; d1 += kf[i].y*S[4*i+1];
        d2 += kf[i].z*S[4*i+2]; d3 += kf[i].w*S[4*i+3];
      }
      float u = (vj - eg*((d0+d1)+(d2+d3))) * bt;
      #pragma unroll
      for (int i=0;i<16;i++){
        S[4*i+0] = S[4*i+0]*eg + kf[i].x*u;
        S[4*i+1] = S[4*i+1]*eg + kf[i].y*u;
        S[4*i+2] = S[4*i+2]*eg + kf[i].z*u;
        S[4*i+3] = S[4*i+3]*eg + kf[i].w*u;
      }
      float o0=0,o1=0,o2=0,o3=0;
      #pragma unroll
      for (int i=0;i<16;i++){
        float4 qq = Q4[t*16+i];
        o0 += qq.x*S[4*i+0]; o1 += qq.y*S[4*i+1];
        o2 += qq.z*S[4*i+2]; o3 += qq.w*S[4*i+3];
      }
      o_r[((l0 + t)*HE_ + he)*DV_ + j] = (o0+o1)+(o2+o3);
    }
    size_t bb = ((size_t)bhe*NC_ + c)*64*128;
    #pragma unroll
    for (int i=0;i<64;i++) Bc[bb + (size_t)i*128 + tid] = S[i];
  } else {
    for (int t = 0; t < T_; t++) {
      float eg = EG[t], bt = BT[t];
      float4 kf[16];
      #pragma unroll
      for (int i=0;i<16;i++) kf[i] = K4[t*16+i];
      float d0=0,d1=0,d2=0,d3=0;
      #pragma unroll
      for (int i=0;i<16;i++){
        d0 += kf[i].x*S[4*i+0]; d1 += kf[i].y*S[4*i+1];
        d2 += kf[i].z*S[4*i+2]; d3 += kf[i].w*S[4*i+3];
      }
      float f = -eg*bt*((d0+d1)+(d2+d3));
      #pragma unroll
      for (int i=0;i<16;i++){
        S[4*i+0] = S[4*i+0]*eg + kf[i].x*f;
        S[4*i+1] = S[4*i+1]*eg + kf[i].y*f;
        S[4*i+2] = S[4*i+2]*eg + kf[i].z*f;
        S[4*i+3] = S[4*i+3]*eg + kf[i].w*f;
      }
      float o0=0,o1=0,o2=0,o3=0;
      #pragma unroll
      for (int i=0;i<16;i++){
        float4 qq = Q4[t*16+i];
        o0 += qq.x*S[4*i+0]; o1 += qq.y*S[4*i+1];
        o2 += qq.z*S[4*i+2]; o3 += qq.w*S[4*i+3];
      }
      Qt[(((size_t)bhe*NC_ + c)*T_ + t)*64 + mcol] = (o0+o1)+(o2+o3);
    }
    size_t mb = ((size_t)bhe*NC_ + c)*64*64;
    #pragma unroll
    for (int i=0;i<64;i++) Mc[mb + (size_t)mcol*64 + i] = S[i];  // [m][i] column-major
  }
}

// ---------------- pass B: sequential compose of chunk-start states ----------------
__global__ __launch_bounds__(1024) void compose(const float* __restrict__ Mc,
    const float* __restrict__ Bc, float* __restrict__ SSb)
{
  __shared__ float SS[8192];   // [m][j], 64x128
  __shared__ float Ml[4096];   // [m][i], 64x64
  const int bhe = blockIdx.x;
  const int tid = threadIdx.x;
  const int j  = tid & 127;
  const int ih = tid >> 7;     // 8 groups of 8 i's
  for (int id = tid; id < 8192; id += 1024) SS[id] = 0.f;
  __syncthreads();
  for (int c = 0; c < NC_; c++) {
    size_t ob = ((size_t)bhe*NC_ + c)*8192;
    for (int id = tid; id < 8192; id += 1024) SSb[ob + id] = SS[id];
    if (c == NC_-1) break;
    size_t mb = ((size_t)bhe*NC_ + c)*4096;
    for (int id = tid; id < 4096; id += 1024) Ml[id] = Mc[mb + id];
    float acc[8];
    #pragma unroll
    for (int i = 0; i < 8; i++) acc[i] = Bc[ob + (size_t)(ih*8+i)*128 + j];
    __syncthreads();
    #pragma unroll 8
    for (int m = 0; m < 64; m++) {
      float ssm = SS[m*128 + j];
      #pragma unroll
      for (int i = 0; i < 8; i++) acc[i] += Ml[m*64 + ih*8 + i] * ssm;
    }
    __syncthreads();
    #pragma unroll
    for (int i = 0; i < 8; i++) SS[(ih*8+i)*128 + j] = acc[i];
    __syncthreads();
  }
}

// ---------------- pass C: o += q~^T * SS ----------------
__global__ __launch_bounds__(256) void correct(const float* __restrict__ SSb,
    const float* __restrict__ Qt, float* __restrict__ o_r)
{
  const int c = blockIdx.x;
  const int bhe = blockIdx.y;
  const int b = bhe >> 4, he = bhe & 15;
  __shared__ float SS[8192];
  __shared__ float Qs[4096];
  const int tid = threadIdx.x;
  size_t sb = ((size_t)bhe*NC_ + c)*8192;
  for (int id = tid; id < 8192; id += 256) SS[id] = SSb[sb + id];
  size_t qb = ((size_t)bhe*NC_ + c)*4096;
  for (int id = tid; id < 4096; id += 256) Qs[id] = Qt[qb + id];
  __syncthreads();
  const int j = tid & 127, th = tid >> 7;
  for (int tt = th*32; tt < th*32 + 32; tt++) {
    float a0=0,a1=0,a2=0,a3=0;
    #pragma unroll
    for (int m = 0; m < 64; m += 4) {
      a0 += Qs[tt*64+m+0]*SS[(m+0)*128+j];
      a1 += Qs[tt*64+m+1]*SS[(m+1)*128+j];
      a2 += Qs[tt*64+m+2]*SS[(m+2)*128+j];
      a3 += Qs[tt*64+m+3]*SS[(m+3)*128+j];
    }
    size_t oi = (((size_t)b*L_ + c*T_ + tt)*HE_ + he)*DV_ + j;
    o_r[oi] += (a0+a1)+(a2+a3);
  }
}

// ---------------- expert combine + RMSNorm*SiLU(gate) ----------------
__global__ __launch_bounds__(128) void combine(const float* __restrict__ o_r,
    const float* __restrict__ w_buf, const float* __restrict__ g_lin,
    const float* __restrict__ norm_w, float* __restrict__ o_fin)
{
  int n  = blockIdx.x;   // (b*L+l)*H + h
  int h  = n & 3;
  int bl = n >> 2;
  int j  = threadIdx.x;
  size_t wb = (size_t)bl*16 + h*4;
  size_t ob = wb*128 + j;
  float oc = 0.f;
  #pragma unroll
  for (int r = 0; r < 4; r++) oc += w_buf[wb+r] * o_r[ob + (size_t)r*128];
  float ss = oc*oc;
  #pragma unroll
  for (int off = 32; off > 0; off >>= 1) ss += __shfl_xor(ss, off);
  __shared__ float red[2];
  if ((threadIdx.x & 63) == 0) red[threadIdx.x >> 6] = ss;
  __syncthreads();
  float mean = (red[0] + red[1]) * (1.f/128.f);
  float sc = rsqrtf(mean + 1e-5f);
  float gv = g_lin[(size_t)bl*512 + h*128 + j];
  o_fin[(size_t)bl*512 + h*128 + j] = oc * sc * norm_w[j] * (gv * sigmoidf_(gv));
}

extern "C" void kernel_launch(void* const* d_in, const int* in_sizes, int n_in,
                              void* d_out, int out_size, void* d_ws, size_t ws_size,
                              hipStream_t stream)
{
  (void)in_sizes; (void)n_in; (void)out_size; (void)ws_size;
  const float* x       = (const float*)d_in[0];
  const float* Wq      = (const float*)d_in[1];
  const float* Wk      = (const float*)d_in[2];
  const float* Wv      = (const float*)d_in[3];
  const float* Wb      = (const float*)d_in[4];
  const float* Wa      = (const float*)d_in[5];
  const float* Wg      = (const float*)d_in[6];
  const float* Wo      = (const float*)d_in[7];
  const float* conv_q  = (const float*)d_in[8];
  const float* conv_k  = (const float*)d_in[9];
  const float* conv_v  = (const float*)d_in[10];
  const float* Wq_exp  = (const float*)d_in[11];
  const float* Wk_exp  = (const float*)d_in[12];
  const float* W_gate  = (const float*)d_in[13];
  const float* A_log   = (const float*)d_in[14];
  const float* dt_bias = (const float*)d_in[15];
  const float* norm_w  = (const float*)d_in[16];
  float* out = (float*)d_out;

  const size_t BL = (size_t)B_*L_;   // 4096
  float* p = (float*)d_ws;
  float* q_lin  = p; p += BL*256;
  float* k_lin  = p; p += BL*256;
  float* v_lin  = p; p += BL*512;
  float* b_lin  = p; p += BL*16;
  float* a_lin  = p; p += BL*16;
  float* g_lin  = p; p += BL*512;
  float* q_conv = p; p += BL*256;
  float* k_conv = p; p += BL*256;
  float* v_conv = p; p += BL*512;
  float* qe     = p; p += BL*1024;
  float* ke     = p; p += BL*1024;
  float* w_buf  = p; p += BL*16;
  float* bt_buf = p; p += BL*16;
  float* g_buf  = p; p += BL*16;
  float* Mc     = p; p += (size_t)B_*HE_*NC_*64*64;
  float* Bc     = p; p += (size_t)B_*HE_*NC_*64*128;
  float* SSb    = p; p += (size_t)B_*HE_*NC_*64*128;
  float* Qt     = p; p += (size_t)B_*HE_*NC_*64*64;
  float* o_r    = p; p += BL*16*128;
  float* o_fin  = p; p += BL*512;

  #define GEMM_(Ap,lda,Bp,ldb,Cp,ldc,M,N,K) \
    gemm_f32<<<dim3(((N)+63)/64,(M)/64), dim3(256), 0, stream>>>(Ap,lda,Bp,ldb,Cp,ldc,M,N,K)

  GEMM_(x,1024, Wq,1024, q_lin,256, 4096,256,1024);
  GEMM_(x,1024, Wk,1024, k_lin,256, 4096,256,1024);
  GEMM_(x,1024, Wv,1024, v_lin,512, 4096,512,1024);
  GEMM_(x,1024, Wb,1024, b_lin,16,  4096,16,1024);
  GEMM_(x,1024, Wa,1024, a_lin,16,  4096,16,1024);
  GEMM_(x,1024, Wg,1024, g_lin,512, 4096,512,1024);

  { int tot = B_*L_*256; conv_silu<<<dim3((tot+255)/256), dim3(256), 0, stream>>>(q_lin, conv_q, q_conv, 256, tot); }
  { int tot = B_*L_*256; conv_silu<<<dim3((tot+255)/256), dim3(256), 0, stream>>>(k_lin, conv_k, k_conv, 256, tot); }
  { int tot = B_*L_*512; conv_silu<<<dim3((tot+255)/256), dim3(256), 0, stream>>>(v_lin, conv_v, v_conv, 512, tot); }

  routing<<<dim3(64), dim3(256), 0, stream>>>(q_conv, b_lin, a_lin, W_gate, A_log, dt_bias,
                                              w_buf, bt_buf, g_buf);

  for (int h = 0; h < 4; h++) {
    GEMM_(q_conv + h*64, 256, Wq_exp + (size_t)h*256*64, 64, qe + h*256, 1024, 4096, 256, 64);
    GEMM_(k_conv + h*64, 256, Wk_exp + (size_t)h*256*64, 64, ke + h*256, 1024, 4096, 256, 64);
  }
  l2norm_rows<<<dim3(16384), dim3(256), 0, stream>>>(qe, 0.125f);  // DK^-0.5
  l2norm_rows<<<dim3(16384), dim3(256), 0, stream>>>(ke, 1.0f);

  scan_chunk<<<dim3(NC_, HE_, B_), dim3(192), 0, stream>>>(ke, qe, v_conv, bt_buf, g_buf,
                                                           o_r, Qt, Mc, Bc);
  compose<<<dim3(B_*HE_), dim3(1024), 0, stream>>>(Mc, Bc, SSb);
  correct<<<dim3(NC_, B_*HE_), dim3(256), 0, stream>>>(SSb, Qt, o_r);
  combine<<<dim3(B_*L_*H_), dim3(128), 0, stream>>>(o_r, w_buf, g_lin, norm_w, o_fin);

  GEMM_(o_fin,512, Wo,512, out,1024, 4096,1024,512);
  #undef GEMM_
}

// Round 2
// 919.757 us; speedup vs baseline: 1.1929x; 1.1929x over previous
//
#include <hip/hip_runtime.h>
#include <hip/hip_bf16.h>
#include <math.h>

#define B_    2
#define L_    2048
#define HID_  1024
#define H_    4
#define DK_   64
#define RATIO_ 4
#define HE_   16
#define DV_   128
#define T_    64
#define NC_   32   // L_/T_

typedef __attribute__((ext_vector_type(8))) short short8;
typedef __attribute__((ext_vector_type(4))) float f32x4;

__device__ __forceinline__ float sigmoidf_(float x){ return 1.f/(1.f+expf(-x)); }
__device__ __forceinline__ ushort f2bf(float x){
  __hip_bfloat16 h = __float2bfloat16(x);
  return *reinterpret_cast<ushort*>(&h);
}

// ---------------- f32 -> bf16 cast ----------------
__global__ __launch_bounds__(256) void cast_bf16(const float* __restrict__ in,
                                                 ushort* __restrict__ out, int n)
{
  int i = blockIdx.x*256 + threadIdx.x;
  if (i < n) out[i] = f2bf(in[i]);
}

// ---------------- bf16 MFMA GEMM: C(MxN) f32 = A(MxK)bf16 * B(NxK)bf16^T ----------------
// 128x128 tile, 4 waves, BK=32, global_load_lds staging (m97 pattern).
// Requires M%128==0, N%128==0, K%32==0.
__global__ __launch_bounds__(256) void gemm_bf16(
    const ushort* __restrict__ A, int lda,
    const ushort* __restrict__ Bm, int ldb,
    float* __restrict__ C, int ldc, int M, int N, int K)
{
  __shared__ ushort As[128*32];
  __shared__ ushort Bs[128*32];
  const int tid  = threadIdx.x;
  const int wave = tid >> 6, lane = tid & 63;
  const int row0 = blockIdx.y*128, col0 = blockIdx.x*128;
  const int wr = (wave >> 1) * 64, wc = (wave & 1) * 64;
  const int frow = lane & 15;
  const int fko  = (lane >> 4) << 3;

  f32x4 acc[4][4];
  #pragma unroll
  for (int i=0;i<4;i++)
    #pragma unroll
    for (int j=0;j<4;j++) acc[i][j] = (f32x4){0.f,0.f,0.f,0.f};

  for (int k0 = 0; k0 < K; k0 += 32) {
    #pragma unroll
    for (int cc = 0; cc < 2; cc++) {
      int c  = wave*128 + cc*64 + lane;     // chunk 0..511
      int r  = c >> 2;                      // row in tile
      int ko = (c & 3) << 3;                // k octet
      __builtin_amdgcn_global_load_lds(
        (const __attribute__((address_space(1))) void*)(A + (size_t)(row0+r)*lda + k0 + ko),
        (__attribute__((address_space(3))) void*)(As + (size_t)(wave*128 + cc*64)*8),
        16, 0, 0);
      __builtin_amdgcn_global_load_lds(
        (const __attribute__((address_space(1))) void*)(Bm + (size_t)(col0+r)*ldb + k0 + ko),
        (__attribute__((address_space(3))) void*)(Bs + (size_t)(wave*128 + cc*64)*8),
        16, 0, 0);
    }
    __syncthreads();
    short8 af[4], bfv[4];
    #pragma unroll
    for (int mi=0;mi<4;mi++)
      af[mi] = *reinterpret_cast<const short8*>(&As[(wr + mi*16 + frow)*32 + fko]);
    #pragma unroll
    for (int ni=0;ni<4;ni++)
      bfv[ni] = *reinterpret_cast<const short8*>(&Bs[(wc + ni*16 + frow)*32 + fko]);
    #pragma unroll
    for (int mi=0;mi<4;mi++)
      #pragma unroll
      for (int ni=0;ni<4;ni++)
        acc[mi][ni] = __builtin_amdgcn_mfma_f32_16x16x32_bf16(af[mi], bfv[ni], acc[mi][ni], 0, 0, 0);
    __syncthreads();
  }
  const int ocol = lane & 15;
  const int orow = (lane >> 4) << 2;
  #pragma unroll
  for (int mi=0;mi<4;mi++)
    #pragma unroll
    for (int ni=0;ni<4;ni++) {
      size_t base = (size_t)(row0 + wr + mi*16 + orow)*ldc + (col0 + wc + ni*16 + ocol);
      #pragma unroll
      for (int q=0;q<4;q++) C[base + (size_t)q*ldc] = acc[mi][ni][q];
    }
}

// ---------------- generic f32 GEMM: C(MxN) = A(MxK) * B(NxK)^T ----------------
__global__ __launch_bounds__(256) void gemm_f32(const float* __restrict__ A, int lda,
    const float* __restrict__ Bm, int ldb, float* __restrict__ C, int ldc,
    int M, int N, int K)
{
  __shared__ float As[32][64];
  __shared__ float Bs[32][64];
  const int tid = threadIdx.x;
  const int row0 = blockIdx.y * 64;
  const int col0 = blockIdx.x * 64;
  const int tx = tid & 15, ty = tid >> 4;
  float acc[4][4] = {};
  for (int k0 = 0; k0 < K; k0 += 32) {
    #pragma unroll
    for (int ld = 0; ld < 2; ld++) {
      int id = tid + ld*256;
      int r  = id >> 3;          // 0..63
      int k4 = (id & 7) << 2;    // 0,4,...,28
      float4 av = *reinterpret_cast<const float4*>(&A[(size_t)(row0+r)*lda + k0 + k4]);
      As[k4+0][r] = av.x; As[k4+1][r] = av.y; As[k4+2][r] = av.z; As[k4+3][r] = av.w;
      float4 bv = make_float4(0.f,0.f,0.f,0.f);
      if (col0 + r < N) bv = *reinterpret_cast<const float4*>(&Bm[(size_t)(col0+r)*ldb + k0 + k4]);
      Bs[k4+0][r] = bv.x; Bs[k4+1][r] = bv.y; Bs[k4+2][r] = bv.z; Bs[k4+3][r] = bv.w;
    }
    __syncthreads();
    #pragma unroll
    for (int kk = 0; kk < 32; kk++) {
      float4 a4 = *reinterpret_cast<const float4*>(&As[kk][ty*4]);
      float4 b4 = *reinterpret_cast<const float4*>(&Bs[kk][tx*4]);
      float a[4] = {a4.x,a4.y,a4.z,a4.w};
      float b[4] = {b4.x,b4.y,b4.z,b4.w};
      #pragma unroll
      for (int i=0;i<4;i++)
        #pragma unroll
        for (int j=0;j<4;j++) acc[i][j] += a[i]*b[j];
    }
    __syncthreads();
  }
  #pragma unroll
  for (int i=0;i<4;i++) {
    int r = row0 + ty*4 + i;
    #pragma unroll
    for (int j=0;j<4;j++) {
      int cc = col0 + tx*4 + j;
      if (cc < N) C[(size_t)r*ldc + cc] = acc[i][j];
    }
  }
}

// ---------------- causal depthwise conv (KS=4) + SiLU ----------------
__global__ __launch_bounds__(256) void conv_silu(const float* __restrict__ in,
    const float* __restrict__ w, float* __restrict__ out, int C, int total)
{
  int n = blockIdx.x*256 + threadIdx.x;
  if (n >= total) return;
  int c = n % C;
  int t = (n / C) % L_;
  int b = n / (C*L_);
  size_t base = (size_t)b*L_*C + c;
  float acc = 0.f;
  #pragma unroll
  for (int s = 0; s < 4; s++) {
    int tt = t - 3 + s;
    if (tt >= 0) acc += in[base + (size_t)tt*C] * w[c*4+s];
  }
  out[n] = acc * sigmoidf_(acc);
}

// ---------------- routing (softmax over 3, top-2, tie->lower idx) + beta + g ----------------
__global__ __launch_bounds__(256) void routing(const float* __restrict__ qc,
    const float* __restrict__ b_lin, const float* __restrict__ a_lin,
    const float* __restrict__ Wg3, const float* __restrict__ A_log,
    const float* __restrict__ dt_bias, float* __restrict__ w_buf,
    float* __restrict__ bt_buf, float* __restrict__ g_buf)
{
  int n = blockIdx.x*256 + threadIdx.x;   // (b*L+l)*H + h, exactly 16384 threads
  int h  = n & 3;
  int bl = n >> 2;
  const float* q = qc + (size_t)bl*256 + h*64;
  float l0=0.f, l1=0.f, l2=0.f;
  for (int d=0; d<64; d++) {
    float qd = q[d];
    l0 += qd*Wg3[d]; l1 += qd*Wg3[64+d]; l2 += qd*Wg3[128+d];
  }
  float mx = fmaxf(l0, fmaxf(l1, l2));
  float e0 = expf(l0-mx), e1 = expf(l1-mx), e2 = expf(l2-mx);
  float inv_s = 1.f/(e0+e1+e2);
  float p0 = e0*inv_s, p1 = e1*inv_s, p2 = e2*inv_s;
  int m1 = 0; float pm1 = p0;
  if (p1 > pm1) { m1 = 1; pm1 = p1; }
  if (p2 > pm1) { m1 = 2; pm1 = p2; }
  int ia = (m1==0) ? 1 : 0;
  int ib = (m1==2) ? 1 : 2;
  float pa = (m1==0) ? p1 : p0;
  float pb = (m1==2) ? p1 : p2;
  int   m2  = (pb > pa) ? ib : ia;
  float pm2 = (pb > pa) ? pb : pa;
  float inv_w = 1.f/(pm1 + pm2);
  float w1 = 0.5f*pm1*inv_w;
  float w2 = 0.5f*pm2*inv_w;
  #pragma unroll
  for (int r = 0; r < 4; r++) {
    float wr = (r==0) ? 0.5f : (((r-1)==m1) ? w1 : (((r-1)==m2) ? w2 : 0.f));
    int he = h*4 + r;
    size_t gi = (size_t)bl*16 + he;
    w_buf[gi] = wr;
    float mask = (wr > 0.f) ? 1.f : 0.f;
    bt_buf[gi] = mask * sigmoidf_(b_lin[gi]);
    float av = a_lin[gi] + dt_bias[he];
    float sp = fmaxf(av, 0.f) + log1pf(expf(-fabsf(av)));
    g_buf[gi] = -expf(A_log[he]) * sp * mask;
  }
}

// ---------------- l2norm over rows of 64 (one wave per row) ----------------
__global__ __launch_bounds__(256) void l2norm_rows(float* __restrict__ v, float scale)
{
  int row  = blockIdx.x*4 + (threadIdx.x >> 6);
  int lane = threadIdx.x & 63;
  size_t idx = (size_t)row*64 + lane;
  float x = v[idx];
  float ss = x*x;
  #pragma unroll
  for (int off = 32; off > 0; off >>= 1) ss += __shfl_xor(ss, off);
  v[idx] = x * rsqrtf(ss + 1e-6f) * scale;
}

// ---------------- pass A: per-chunk recurrence from zero + transition matrix ----------------
__global__ __launch_bounds__(192) void scan_chunk(
    const float* __restrict__ ke, const float* __restrict__ qe,
    const float* __restrict__ vc, const float* __restrict__ bt_buf,
    const float* __restrict__ g_buf, float* __restrict__ o_r,
    float* __restrict__ Qt, float* __restrict__ Mc, float* __restrict__ Bc)
{
  const int c  = blockIdx.x;
  const int he = blockIdx.y;
  const int b  = blockIdx.z;
  const int bhe = b*HE_ + he;
  const int h = he >> 2;
  __shared__ float Kl[T_*64];
  __shared__ float Ql[T_*64];
  __shared__ float EG[T_];
  __shared__ float BT[T_];
  const int tid = threadIdx.x;
  const size_t l0 = (size_t)b*L_ + (size_t)c*T_;
  for (int id = tid; id < T_*16; id += 192) {
    int t = id >> 4, d4 = (id & 15) << 2;
    size_t gi = ((l0 + t)*HE_ + he)*64 + d4;
    *reinterpret_cast<float4*>(&Kl[t*64 + d4]) = *reinterpret_cast<const float4*>(&ke[gi]);
    *reinterpret_cast<float4*>(&Ql[t*64 + d4]) = *reinterpret_cast<const float4*>(&qe[gi]);
  }
  if (tid < T_) {
    size_t gi = (l0 + tid)*HE_ + he;
    EG[tid] = expf(g_buf[gi]);
    BT[tid] = bt_buf[gi];
  }
  __syncthreads();
  const float4* K4 = reinterpret_cast<const float4*>(Kl);
  const float4* Q4 = reinterpret_cast<const float4*>(Ql);
  const bool isB = tid < 128;
  const int mcol = tid - 128;
  float S[64];
  #pragma unroll
  for (int i=0;i<64;i++) S[i] = (!isB && i==mcol) ? 1.f : 0.f;

  if (isB) {
    const int j = tid;
    for (int t = 0; t < T_; t++) {
      float eg = EG[t], bt = BT[t];
      float vj = vc[(l0 + t)*(H_*DV_) + h*DV_ + j];
      float4 kf[16];
      #pragma unroll
      for (int i=0;i<16;i++) kf[i] = K4[t*16+i];
      float d0=0,d1=0,d2=0,d3=0;
      #pragma unroll
      for (int i=0;i<16;i++){
        d0 += kf[i].x*S[4*i+0]; d1 += kf[i].y*S[4*i+1];
        d2 += kf[i].z*S[4*i+2]; d3 += kf[i].w*S[4*i+3];
      }
      float u = (vj - eg*((d0+d1)+(d2+d3))) * bt;
      #pragma unroll
      for (int i=0;i<16;i++){
        S[4*i+0] = S[4*i+0]*eg + kf[i].x*u;
        S[4*i+1] = S[4*i+1]*eg + kf[i].y*u;
        S[4*i+2] = S[4*i+2]*eg + kf[i].z*u;
        S[4*i+3] = S[4*i+3]*eg + kf[i].w*u;
      }
      float o0=0,o1=0,o2=0,o3=0;
      #pragma unroll
      for (int i=0;i<16;i++){
        float4 qq = Q4[t*16+i];
        o0 += qq.x*S[4*i+0]; o1 += qq.y*S[4*i+1];
        o2 += qq.z*S[4*i+2]; o3 += qq.w*S[4*i+3];
      }
      o_r[((l0 + t)*HE_ + he)*DV_ + j] = (o0+o1)+(o2+o3);
    }
    size_t bb = ((size_t)bhe*NC_ + c)*64*128;
    #pragma unroll
    for (int i=0;i<64;i++) Bc[bb + (size_t)i*128 + tid] = S[i];
  } else {
    for (int t = 0; t < T_; t++) {
      float eg = EG[t], bt = BT[t];
      float4 kf[16];
      #pragma unroll
      for (int i=0;i<16;i++) kf[i] = K4[t*16+i];
      float d0=0,d1=0,d2=0,d3=0;
      #pragma unroll
      for (int i=0;i<16;i++){
        d0 += kf[i].x*S[4*i+0]; d1 += kf[i].y*S[4*i+1];
        d2 += kf[i].z*S[4*i+2]; d3 += kf[i].w*S[4*i+3];
      }
      float f = -eg*bt*((d0+d1)+(d2+d3));
      #pragma unroll
      for (int i=0;i<16;i++){
        S[4*i+0] = S[4*i+0]*eg + kf[i].x*f;
        S[4*i+1] = S[4*i+1]*eg + kf[i].y*f;
        S[4*i+2] = S[4*i+2]*eg + kf[i].z*f;
        S[4*i+3] = S[4*i+3]*eg + kf[i].w*f;
      }
      float o0=0,o1=0,o2=0,o3=0;
      #pragma unroll
      for (int i=0;i<16;i++){
        float4 qq = Q4[t*16+i];
        o0 += qq.x*S[4*i+0]; o1 += qq.y*S[4*i+1];
        o2 += qq.z*S[4*i+2]; o3 += qq.w*S[4*i+3];
      }
      Qt[(((size_t)bhe*NC_ + c)*T_ + t)*64 + mcol] = (o0+o1)+(o2+o3);
    }
    size_t mb = ((size_t)bhe*NC_ + c)*64*64;
    #pragma unroll
    for (int i=0;i<64;i++) Mc[mb + (size_t)mcol*64 + i] = S[i];
  }
}

// ---------------- pass B: sequential compose of chunk-start states ----------------
__global__ __launch_bounds__(1024) void compose(const float* __restrict__ Mc,
    const float* __restrict__ Bc, float* __restrict__ SSb)
{
  __shared__ float SS[8192];   // [m][j], 64x128
  __shared__ float Ml[4096];   // [m][i], 64x64
  const int bhe = blockIdx.x;
  const int tid = threadIdx.x;
  const int j  = tid & 127;
  const int ih = tid >> 7;
  for (int id = tid; id < 8192; id += 1024) SS[id] = 0.f;
  __syncthreads();
  for (int c = 0; c < NC_; c++) {
    size_t ob = ((size_t)bhe*NC_ + c)*8192;
    for (int id = tid; id < 8192; id += 1024) SSb[ob + id] = SS[id];
    if (c == NC_-1) break;
    size_t mb = ((size_t)bhe*NC_ + c)*4096;
    for (int id = tid; id < 4096; id += 1024) Ml[id] = Mc[mb + id];
    float acc[8];
    #pragma unroll
    for (int i = 0; i < 8; i++) acc[i] = Bc[ob + (size_t)(ih*8+i)*128 + j];
    __syncthreads();
    #pragma unroll 8
    for (int m = 0; m < 64; m++) {
      float ssm = SS[m*128 + j];
      #pragma unroll
      for (int i = 0; i < 8; i++) acc[i] += Ml[m*64 + ih*8 + i] * ssm;
    }
    __syncthreads();
    #pragma unroll
    for (int i = 0; i < 8; i++) SS[(ih*8+i)*128 + j] = acc[i];
    __syncthreads();
  }
}

// ---------------- pass C: o += q~^T * SS ----------------
__global__ __launch_bounds__(256) void correct(const float* __restrict__ SSb,
    const float* __restrict__ Qt, float* __restrict__ o_r)
{
  const int c = blockIdx.x;
  const int bhe = blockIdx.y;
  const int b = bhe >> 4, he = bhe & 15;
  __shared__ float SS[8192];
  __shared__ float Qs[4096];
  const int tid = threadIdx.x;
  size_t sb = ((size_t)bhe*NC_ + c)*8192;
  for (int id = tid; id < 8192; id += 256) SS[id] = SSb[sb + id];
  size_t qb = ((size_t)bhe*NC_ + c)*4096;
  for (int id = tid; id < 4096; id += 256) Qs[id] = Qt[qb + id];
  __syncthreads();
  const int j = tid & 127, th = tid >> 7;
  for (int tt = th*32; tt < th*32 + 32; tt++) {
    float a0=0,a1=0,a2=0,a3=0;
    #pragma unroll
    for (int m = 0; m < 64; m += 4) {
      a0 += Qs[tt*64+m+0]*SS[(m+0)*128+j];
      a1 += Qs[tt*64+m+1]*SS[(m+1)*128+j];
      a2 += Qs[tt*64+m+2]*SS[(m+2)*128+j];
      a3 += Qs[tt*64+m+3]*SS[(m+3)*128+j];
    }
    size_t oi = (((size_t)b*L_ + c*T_ + tt)*HE_ + he)*DV_ + j;
    o_r[oi] += (a0+a1)+(a2+a3);
  }
}

// ---------------- expert combine + RMSNorm*SiLU(gate) -> bf16 ----------------
__global__ __launch_bounds__(128) void combine(const float* __restrict__ o_r,
    const float* __restrict__ w_buf, const float* __restrict__ g_lin,
    const float* __restrict__ norm_w, ushort* __restrict__ o_fin)
{
  int n  = blockIdx.x;   // (b*L+l)*H + h
  int h  = n & 3;
  int bl = n >> 2;
  int j  = threadIdx.x;
  size_t wb = (size_t)bl*16 + h*4;
  size_t ob = wb*128 + j;
  float oc = 0.f;
  #pragma unroll
  for (int r = 0; r < 4; r++) oc += w_buf[wb+r] * o_r[ob + (size_t)r*128];
  float ss = oc*oc;
  #pragma unroll
  for (int off = 32; off > 0; off >>= 1) ss += __shfl_xor(ss, off);
  __shared__ float red[2];
  if ((threadIdx.x & 63) == 0) red[threadIdx.x >> 6] = ss;
  __syncthreads();
  float mean = (red[0] + red[1]) * (1.f/128.f);
  float sc = rsqrtf(mean + 1e-5f);
  float gv = g_lin[(size_t)bl*512 + h*128 + j];
  o_fin[(size_t)bl*512 + h*128 + j] = f2bf(oc * sc * norm_w[j] * (gv * sigmoidf_(gv)));
}

extern "C" void kernel_launch(void* const* d_in, const int* in_sizes, int n_in,
                              void* d_out, int out_size, void* d_ws, size_t ws_size,
                              hipStream_t stream)
{
  (void)in_sizes; (void)n_in; (void)out_size; (void)ws_size;
  const float* x       = (const float*)d_in[0];
  const float* Wq      = (const float*)d_in[1];
  const float* Wk      = (const float*)d_in[2];
  const float* Wv      = (const float*)d_in[3];
  const float* Wb      = (const float*)d_in[4];
  const float* Wa      = (const float*)d_in[5];
  const float* Wg      = (const float*)d_in[6];
  const float* Wo      = (const float*)d_in[7];
  const float* conv_q  = (const float*)d_in[8];
  const float* conv_k  = (const float*)d_in[9];
  const float* conv_v  = (const float*)d_in[10];
  const float* Wq_exp  = (const float*)d_in[11];
  const float* Wk_exp  = (const float*)d_in[12];
  const float* W_gate  = (const float*)d_in[13];
  const float* A_log   = (const float*)d_in[14];
  const float* dt_bias = (const float*)d_in[15];
  const float* norm_w  = (const float*)d_in[16];
  float* out = (float*)d_out;

  const size_t BL = (size_t)B_*L_;   // 4096
  float* p = (float*)d_ws;
  float* q_lin  = p; p += BL*256;
  float* k_lin  = p; p += BL*256;
  float* v_lin  = p; p += BL*512;
  float* b_lin  = p; p += BL*16;
  float* a_lin  = p; p += BL*16;
  float* g_lin  = p; p += BL*512;
  float* q_conv = p; p += BL*256;
  float* k_conv = p; p += BL*256;
  float* v_conv = p; p += BL*512;
  float* qe     = p; p += BL*1024;
  float* ke     = p; p += BL*1024;
  float* w_buf  = p; p += BL*16;
  float* bt_buf = p; p += BL*16;
  float* g_buf  = p; p += BL*16;
  float* Mc     = p; p += (size_t)B_*HE_*NC_*64*64;
  float* Bc     = p; p += (size_t)B_*HE_*NC_*64*128;
  float* SSb    = p; p += (size_t)B_*HE_*NC_*64*128;
  float* Qt     = p; p += (size_t)B_*HE_*NC_*64*64;
  float* o_r    = p; p += BL*16*128;
  ushort* xb    = (ushort*)p; p += BL*512;   // BL*1024 bf16
  ushort* Wvb   = (ushort*)p; p += 262144;   // 512*1024 bf16
  ushort* Wgb   = (ushort*)p; p += 262144;   // 512*1024 bf16
  ushort* Wob   = (ushort*)p; p += 262144;   // 1024*512 bf16
  ushort* o_finb= (ushort*)p; p += BL*256;   // BL*512 bf16

  #define GEMM_(Ap,lda,Bp,ldb,Cp,ldc,M,N,K) \
    gemm_f32<<<dim3(((N)+63)/64,(M)/64), dim3(256), 0, stream>>>(Ap,lda,Bp,ldb,Cp,ldc,M,N,K)
  #define GEMMB_(Ap,lda,Bp,ldb,Cp,ldc,M,N,K) \
    gemm_bf16<<<dim3((N)/128,(M)/128), dim3(256), 0, stream>>>(Ap,lda,Bp,ldb,Cp,ldc,M,N,K)

  // casts
  { int n = (int)(BL*1024); cast_bf16<<<dim3((n+255)/256), dim3(256), 0, stream>>>(x,  xb,  n); }
  { int n = 512*1024;       cast_bf16<<<dim3((n+255)/256), dim3(256), 0, stream>>>(Wv, Wvb, n); }
  { int n = 512*1024;       cast_bf16<<<dim3((n+255)/256), dim3(256), 0, stream>>>(Wg, Wgb, n); }
  { int n = 1024*512;       cast_bf16<<<dim3((n+255)/256), dim3(256), 0, stream>>>(Wo, Wob, n); }

  // projections: q,k,b,a stay f32 (q feeds discrete routing; k quadratic in recurrence)
  GEMM_(x,1024, Wq,1024, q_lin,256, 4096,256,1024);
  GEMM_(x,1024, Wk,1024, k_lin,256, 4096,256,1024);
  GEMM_(x,1024, Wb,1024, b_lin,16,  4096,16,1024);
  GEMM_(x,1024, Wa,1024, a_lin,16,  4096,16,1024);
  GEMMB_(xb,1024, Wvb,1024, v_lin,512, 4096,512,1024);
  GEMMB_(xb,1024, Wgb,1024, g_lin,512, 4096,512,1024);

  { int tot = B_*L_*256; conv_silu<<<dim3((tot+255)/256), dim3(256), 0, stream>>>(q_lin, conv_q, q_conv, 256, tot); }
  { int tot = B_*L_*256; conv_silu<<<dim3((tot+255)/256), dim3(256), 0, stream>>>(k_lin, conv_k, k_conv, 256, tot); }
  { int tot = B_*L_*512; conv_silu<<<dim3((tot+255)/256), dim3(256), 0, stream>>>(v_lin, conv_v, v_conv, 512, tot); }

  routing<<<dim3(64), dim3(256), 0, stream>>>(q_conv, b_lin, a_lin, W_gate, A_log, dt_bias,
                                              w_buf, bt_buf, g_buf);

  for (int h = 0; h < 4; h++) {
    GEMM_(q_conv + h*64, 256, Wq_exp + (size_t)h*256*64, 64, qe + h*256, 1024, 4096, 256, 64);
    GEMM_(k_conv + h*64, 256, Wk_exp + (size_t)h*256*64, 64, ke + h*256, 1024, 4096, 256, 64);
  }
  l2norm_rows<<<dim3(16384), dim3(256), 0, stream>>>(qe, 0.125f);  // DK^-0.5
  l2norm_rows<<<dim3(16384), dim3(256), 0, stream>>>(ke, 1.0f);

  scan_chunk<<<dim3(NC_, HE_, B_), dim3(192), 0, stream>>>(ke, qe, v_conv, bt_buf, g_buf,
                                                           o_r, Qt, Mc, Bc);
  compose<<<dim3(B_*HE_), dim3(1024), 0, stream>>>(Mc, Bc, SSb);
  correct<<<dim3(NC_, B_*HE_), dim3(256), 0, stream>>>(SSb, Qt, o_r);
  combine<<<dim3(B_*L_*H_), dim3(128), 0, stream>>>(o_r, w_buf, g_lin, norm_w, o_finb);

  GEMMB_(o_finb,512, Wob,512, out,1024, 4096,1024,512);
  #undef GEMM_
  #undef GEMMB_
}

// Round 3
// 772.219 us; speedup vs baseline: 1.4208x; 1.1911x over previous
//
#include <hip/hip_runtime.h>
#include <hip/hip_bf16.h>
#include <math.h>

#define B_    2
#define L_    2048
#define HID_  1024
#define H_    4
#define DK_   64
#define RATIO_ 4
#define HE_   16
#define DV_   128
#define T_    64
#define NC_   32   // L_/T_
#define SPITCH 72  // bf16 LDS row pitch (breaks bank conflicts on b128 frag reads)
#define APITCH 68  // f32 A-matrix LDS pitch

typedef __attribute__((ext_vector_type(8))) short short8;
typedef __attribute__((ext_vector_type(4))) float f32x4;

__device__ __forceinline__ float sigmoidf_(float x){ return 1.f/(1.f+expf(-x)); }
__device__ __forceinline__ ushort f2bf(float x){
  __hip_bfloat16 h = __float2bfloat16(x);
  return *reinterpret_cast<ushort*>(&h);
}
__device__ __forceinline__ float bf2f(ushort u){
  union { uint32_t i; float f; } v; v.i = ((uint32_t)u) << 16; return v.f;
}

// ---------------- f32 -> bf16 cast ----------------
__global__ __launch_bounds__(256) void cast_bf16(const float* __restrict__ in,
                                                 ushort* __restrict__ out, int n)
{
  int i = blockIdx.x*256 + threadIdx.x;
  if (i < n) out[i] = f2bf(in[i]);
}

// ---------------- bf16 MFMA GEMM: C(MxN) f32 = A(MxK)bf16 * B(NxK)bf16^T ----------------
__global__ __launch_bounds__(256) void gemm_bf16(
    const ushort* __restrict__ A, int lda,
    const ushort* __restrict__ Bm, int ldb,
    float* __restrict__ C, int ldc, int M, int N, int K)
{
  __shared__ ushort As[128*32];
  __shared__ ushort Bs[128*32];
  const int tid  = threadIdx.x;
  const int wave = tid >> 6, lane = tid & 63;
  const int row0 = blockIdx.y*128, col0 = blockIdx.x*128;
  const int wr = (wave >> 1) * 64, wc = (wave & 1) * 64;
  const int frow = lane & 15;
  const int fko  = (lane >> 4) << 3;

  f32x4 acc[4][4];
  #pragma unroll
  for (int i=0;i<4;i++)
    #pragma unroll
    for (int j=0;j<4;j++) acc[i][j] = (f32x4){0.f,0.f,0.f,0.f};

  for (int k0 = 0; k0 < K; k0 += 32) {
    #pragma unroll
    for (int cc = 0; cc < 2; cc++) {
      int c  = wave*128 + cc*64 + lane;
      int r  = c >> 2;
      int ko = (c & 3) << 3;
      __builtin_amdgcn_global_load_lds(
        (const __attribute__((address_space(1))) void*)(A + (size_t)(row0+r)*lda + k0 + ko),
        (__attribute__((address_space(3))) void*)(As + (size_t)(wave*128 + cc*64)*8),
        16, 0, 0);
      __builtin_amdgcn_global_load_lds(
        (const __attribute__((address_space(1))) void*)(Bm + (size_t)(col0+r)*ldb + k0 + ko),
        (__attribute__((address_space(3))) void*)(Bs + (size_t)(wave*128 + cc*64)*8),
        16, 0, 0);
    }
    __syncthreads();
    short8 af[4], bfv[4];
    #pragma unroll
    for (int mi=0;mi<4;mi++)
      af[mi] = *reinterpret_cast<const short8*>(&As[(wr + mi*16 + frow)*32 + fko]);
    #pragma unroll
    for (int ni=0;ni<4;ni++)
      bfv[ni] = *reinterpret_cast<const short8*>(&Bs[(wc + ni*16 + frow)*32 + fko]);
    #pragma unroll
    for (int mi=0;mi<4;mi++)
      #pragma unroll
      for (int ni=0;ni<4;ni++)
        acc[mi][ni] = __builtin_amdgcn_mfma_f32_16x16x32_bf16(af[mi], bfv[ni], acc[mi][ni], 0, 0, 0);
    __syncthreads();
  }
  const int ocol = lane & 15;
  const int orow = (lane >> 4) << 2;
  #pragma unroll
  for (int mi=0;mi<4;mi++)
    #pragma unroll
    for (int ni=0;ni<4;ni++) {
      size_t base = (size_t)(row0 + wr + mi*16 + orow)*ldc + (col0 + wc + ni*16 + ocol);
      #pragma unroll
      for (int q=0;q<4;q++) C[base + (size_t)q*ldc] = acc[mi][ni][q];
    }
}

// ---------------- generic f32 GEMM: C(MxN) = A(MxK) * B(NxK)^T ----------------
__global__ __launch_bounds__(256) void gemm_f32(const float* __restrict__ A, int lda,
    const float* __restrict__ Bm, int ldb, float* __restrict__ C, int ldc,
    int M, int N, int K)
{
  __shared__ float As[32][64];
  __shared__ float Bs[32][64];
  const int tid = threadIdx.x;
  const int row0 = blockIdx.y * 64;
  const int col0 = blockIdx.x * 64;
  const int tx = tid & 15, ty = tid >> 4;
  float acc[4][4] = {};
  for (int k0 = 0; k0 < K; k0 += 32) {
    #pragma unroll
    for (int ld = 0; ld < 2; ld++) {
      int id = tid + ld*256;
      int r  = id >> 3;
      int k4 = (id & 7) << 2;
      float4 av = *reinterpret_cast<const float4*>(&A[(size_t)(row0+r)*lda + k0 + k4]);
      As[k4+0][r] = av.x; As[k4+1][r] = av.y; As[k4+2][r] = av.z; As[k4+3][r] = av.w;
      float4 bv = make_float4(0.f,0.f,0.f,0.f);
      if (col0 + r < N) bv = *reinterpret_cast<const float4*>(&Bm[(size_t)(col0+r)*ldb + k0 + k4]);
      Bs[k4+0][r] = bv.x; Bs[k4+1][r] = bv.y; Bs[k4+2][r] = bv.z; Bs[k4+3][r] = bv.w;
    }
    __syncthreads();
    #pragma unroll
    for (int kk = 0; kk < 32; kk++) {
      float4 a4 = *reinterpret_cast<const float4*>(&As[kk][ty*4]);
      float4 b4 = *reinterpret_cast<const float4*>(&Bs[kk][tx*4]);
      float a[4] = {a4.x,a4.y,a4.z,a4.w};
      float b[4] = {b4.x,b4.y,b4.z,b4.w};
      #pragma unroll
      for (int i=0;i<4;i++)
        #pragma unroll
        for (int j=0;j<4;j++) acc[i][j] += a[i]*b[j];
    }
    __syncthreads();
  }
  #pragma unroll
  for (int i=0;i<4;i++) {
    int r = row0 + ty*4 + i;
    #pragma unroll
    for (int j=0;j<4;j++) {
      int cc = col0 + tx*4 + j;
      if (cc < N) C[(size_t)r*ldc + cc] = acc[i][j];
    }
  }
}

// ---------------- batched per-head expansion GEMMs (8 in one launch) ----------------
// z = qk*4+h; C(4096x256) = A(4096x64, strided) * Wexp(256x64)^T
__global__ __launch_bounds__(256) void gemm_expand(
    const float* __restrict__ q_conv, const float* __restrict__ k_conv,
    const float* __restrict__ Wq_exp, const float* __restrict__ Wk_exp,
    float* __restrict__ qe, float* __restrict__ ke)
{
  const int z = blockIdx.z;
  const int hh = z & 3;
  const float* A  = (z < 4 ? q_conv : k_conv) + hh*64;
  const float* Bm = (z < 4 ? Wq_exp : Wk_exp) + (size_t)hh*16384;
  float* C        = (z < 4 ? qe : ke) + hh*256;
  __shared__ float As[32][64];
  __shared__ float Bs[32][64];
  const int tid = threadIdx.x;
  const int row0 = blockIdx.y * 64;
  const int col0 = blockIdx.x * 64;
  const int tx = tid & 15, ty = tid >> 4;
  float acc[4][4] = {};
  for (int k0 = 0; k0 < 64; k0 += 32) {
    #pragma unroll
    for (int ld = 0; ld < 2; ld++) {
      int id = tid + ld*256;
      int r  = id >> 3;
      int k4 = (id & 7) << 2;
      float4 av = *reinterpret_cast<const float4*>(&A[(size_t)(row0+r)*256 + k0 + k4]);
      As[k4+0][r] = av.x; As[k4+1][r] = av.y; As[k4+2][r] = av.z; As[k4+3][r] = av.w;
      float4 bv = *reinterpret_cast<const float4*>(&Bm[(size_t)(col0+r)*64 + k0 + k4]);
      Bs[k4+0][r] = bv.x; Bs[k4+1][r] = bv.y; Bs[k4+2][r] = bv.z; Bs[k4+3][r] = bv.w;
    }
    __syncthreads();
    #pragma unroll
    for (int kk = 0; kk < 32; kk++) {
      float4 a4 = *reinterpret_cast<const float4*>(&As[kk][ty*4]);
      float4 b4 = *reinterpret_cast<const float4*>(&Bs[kk][tx*4]);
      float a[4] = {a4.x,a4.y,a4.z,a4.w};
      float b[4] = {b4.x,b4.y,b4.z,b4.w};
      #pragma unroll
      for (int i=0;i<4;i++)
        #pragma unroll
        for (int j=0;j<4;j++) acc[i][j] += a[i]*b[j];
    }
    __syncthreads();
  }
  #pragma unroll
  for (int i=0;i<4;i++)
    #pragma unroll
    for (int j=0;j<4;j++)
      C[(size_t)(row0 + ty*4 + i)*1024 + col0 + tx*4 + j] = acc[i][j];
}

// ---------------- causal depthwise conv (KS=4) + SiLU ----------------
__global__ __launch_bounds__(256) void conv_silu(const float* __restrict__ in,
    const float* __restrict__ w, float* __restrict__ out, int C, int total)
{
  int n = blockIdx.x*256 + threadIdx.x;
  if (n >= total) return;
  int c = n % C;
  int t = (n / C) % L_;
  int b = n / (C*L_);
  size_t base = (size_t)b*L_*C + c;
  float acc = 0.f;
  #pragma unroll
  for (int s = 0; s < 4; s++) {
    int tt = t - 3 + s;
    if (tt >= 0) acc += in[base + (size_t)tt*C] * w[c*4+s];
  }
  out[n] = acc * sigmoidf_(acc);
}

// ---------------- routing + beta + g ----------------
__global__ __launch_bounds__(256) void routing(const float* __restrict__ qc,
    const float* __restrict__ ba_lin, const float* __restrict__ Wg3,
    const float* __restrict__ A_log, const float* __restrict__ dt_bias,
    float* __restrict__ w_buf, float* __restrict__ bt_buf, float* __restrict__ g_buf)
{
  int n = blockIdx.x*256 + threadIdx.x;
  int h  = n & 3;
  int bl = n >> 2;
  const float* q = qc + (size_t)bl*256 + h*64;
  float l0=0.f, l1=0.f, l2=0.f;
  for (int d=0; d<64; d++) {
    float qd = q[d];
    l0 += qd*Wg3[d]; l1 += qd*Wg3[64+d]; l2 += qd*Wg3[128+d];
  }
  float mx = fmaxf(l0, fmaxf(l1, l2));
  float e0 = expf(l0-mx), e1 = expf(l1-mx), e2 = expf(l2-mx);
  float inv_s = 1.f/(e0+e1+e2);
  float p0 = e0*inv_s, p1 = e1*inv_s, p2 = e2*inv_s;
  int m1 = 0; float pm1 = p0;
  if (p1 > pm1) { m1 = 1; pm1 = p1; }
  if (p2 > pm1) { m1 = 2; pm1 = p2; }
  int ia = (m1==0) ? 1 : 0;
  int ib = (m1==2) ? 1 : 2;
  float pa = (m1==0) ? p1 : p0;
  float pb = (m1==2) ? p1 : p2;
  int   m2  = (pb > pa) ? ib : ia;
  float pm2 = (pb > pa) ? pb : pa;
  float inv_w = 1.f/(pm1 + pm2);
  float w1 = 0.5f*pm1*inv_w;
  float w2 = 0.5f*pm2*inv_w;
  #pragma unroll
  for (int r = 0; r < 4; r++) {
    float wr = (r==0) ? 0.5f : (((r-1)==m1) ? w1 : (((r-1)==m2) ? w2 : 0.f));
    int he = h*4 + r;
    size_t gi = (size_t)bl*16 + he;
    w_buf[gi] = wr;
    float mask = (wr > 0.f) ? 1.f : 0.f;
    bt_buf[gi] = mask * sigmoidf_(ba_lin[(size_t)bl*32 + he]);
    float av = ba_lin[(size_t)bl*32 + 16 + he] + dt_bias[he];
    float sp = fmaxf(av, 0.f) + log1pf(expf(-fabsf(av)));
    g_buf[gi] = -expf(A_log[he]) * sp * mask;
  }
}

// ---------------- l2norm over rows of 64 ----------------
__global__ __launch_bounds__(256) void l2norm_rows(float* __restrict__ v, float scale)
{
  int row  = blockIdx.x*4 + (threadIdx.x >> 6);
  int lane = threadIdx.x & 63;
  size_t idx = (size_t)row*64 + lane;
  float x = v[idx];
  float ss = x*x;
  #pragma unroll
  for (int off = 32; off > 0; off >>= 1) ss += __shfl_xor(ss, off);
  v[idx] = x * rsqrtf(ss + 1e-6f) * scale;
}

// ---------------- MFMA tile helper: C16x16 = A[r0..+16] . B[c0..+16]^T over 64 ----------------
__device__ __forceinline__ f32x4 tile64(const ushort* Am, int r0,
                                        const ushort* Bm, int c0, int lane)
{
  f32x4 acc = {0.f,0.f,0.f,0.f};
  const int fr = lane & 15, fo = (lane >> 4) << 3;
  #pragma unroll
  for (int kk = 0; kk < 2; ++kk) {
    short8 a = *reinterpret_cast<const short8*>(&Am[(r0+fr)*SPITCH + fo + kk*32]);
    short8 b = *reinterpret_cast<const short8*>(&Bm[(c0+fr)*SPITCH + fo + kk*32]);
    acc = __builtin_amdgcn_mfma_f32_16x16x32_bf16(a, b, acc, 0, 0, 0);
  }
  return acc;
}

// ---------------- pass A via WY/UT transform + MFMA ----------------
// Per block: one (batch, head-expert, chunk). Produces o_r (zero-state outputs),
// Qt (q~ = Gamma*Q - P*uK), Mc (chunk transition), Bc (chunk state from zero).
__global__ __launch_bounds__(256,2) void scan_chunk_mfma(
    const float* __restrict__ ke, const float* __restrict__ qe,
    const float* __restrict__ vc, const float* __restrict__ bt_buf,
    const float* __restrict__ g_buf, float* __restrict__ o_r,
    float* __restrict__ Qt, float* __restrict__ Mc, float* __restrict__ Bc)
{
  __shared__ float smem[18496];                       // 73984 B
  ushort* Kbf = (ushort*)smem;                        // [64][72] bf16
  ushort* Qbf = (ushort*)(smem + 2304);               // [64][72] bf16
  ushort* KTD = (ushort*)(smem + 4608);               // [64][72] bf16 (K^T, D-scaled)
  float*  Af  = smem + 6912;                          // [64][68] f32 (A matrix)
  ushort* Pf  = (ushort*)(smem + 6912);               // overlay after substitution
  ushort* UV  = (ushort*)(smem + 11264);              // Vbf [64][128] then Ut [192][72]
  float*  cgs = smem + 18176;
  float*  bts = cgs + 64;
  float*  bGs = bts + 64;
  float*  Ds  = bGs + 64;
  float*  gams= Ds + 64;

  const int c  = blockIdx.x;
  const int he = blockIdx.y;
  const int b  = blockIdx.z;
  const int bhe = b*HE_ + he;
  const int h = he >> 2;
  const int tid = threadIdx.x;
  const int wave = tid >> 6, lane = tid & 63;
  const size_t l0 = (size_t)b*L_ + (size_t)c*T_;

  // ---- ph0a: global loads to regs + g-scan (wave 0) ----
  const int tr = tid >> 2;      // row 0..63
  const int sg = tid & 3;       // quarter
  float4 kreg[4], qreg[4], vreg[8];
  {
    const float4* kp = (const float4*)&ke[((l0+tr)*HE_ + he)*64 + sg*16];
    const float4* qp = (const float4*)&qe[((l0+tr)*HE_ + he)*64 + sg*16];
    #pragma unroll
    for (int i=0;i<4;i++){ kreg[i] = kp[i]; qreg[i] = qp[i]; }
    const float4* vp = (const float4*)&vc[(l0+tr)*(H_*DV_) + h*DV_ + sg*32];
    #pragma unroll
    for (int i=0;i<8;i++) vreg[i] = vp[i];
  }
  if (tid < 64) {
    float g  = g_buf[(l0+tid)*HE_ + he];
    float bt = bt_buf[(l0+tid)*HE_ + he];
    float cg = g;
    #pragma unroll
    for (int off = 1; off < 64; off <<= 1) {
      float o = __shfl_up(cg, off);
      if (tid >= off) cg += o;
    }
    float cg63 = __shfl(cg, 63);
    cgs[tid] = cg; bts[tid] = bt;
    float gm = expf(cg);
    gams[tid] = gm; bGs[tid] = bt*gm; Ds[tid] = expf(cg63 - cg);
  }
  __syncthreads();
  // ---- ph0b: cvt + LDS stores ----
  {
    float Dt = Ds[tr];
    ushort* Vb = UV;
    #pragma unroll
    for (int i=0;i<4;i++){
      float kv[4] = {kreg[i].x,kreg[i].y,kreg[i].z,kreg[i].w};
      float qv[4] = {qreg[i].x,qreg[i].y,qreg[i].z,qreg[i].w};
      #pragma unroll
      for (int j=0;j<4;j++){
        int d = sg*16 + i*4 + j;
        Kbf[tr*SPITCH + d] = f2bf(kv[j]);
        Qbf[tr*SPITCH + d] = f2bf(qv[j]);
        KTD[d*SPITCH + tr] = f2bf(kv[j]*Dt);
      }
    }
    #pragma unroll
    for (int i=0;i<8;i++){
      float vv[4] = {vreg[i].x,vreg[i].y,vreg[i].z,vreg[i].w};
      #pragma unroll
      for (int j=0;j<4;j++)
        Vb[tr*128 + sg*32 + i*4 + j] = f2bf(vv[j]);
    }
  }
  __syncthreads();
  // ---- ph1: CK = K.K^T -> A (scaled, strictly lower, zero elsewhere) ----
  {
    const int r0 = wave*16;
    #pragma unroll
    for (int ct=0; ct<4; ++ct) {
      f32x4 acc = tile64(Kbf, r0, Kbf, ct*16, lane);
      int t = r0 + ((lane>>4)<<2);
      int s = ct*16 + (lane&15);
      #pragma unroll
      for (int q=0;q<4;q++){
        int tq = t + q;
        Af[tq*APITCH + s] = (s < tq) ? bts[tq]*expf(cgs[tq]-cgs[s])*acc[q] : 0.f;
      }
    }
  }
  __syncthreads();
  // ---- ph2: forward substitution u = (I+A)^-1 [beta*V | betaGamma*K], per column ----
  float u[64];
  if (tid < 192) {
    if (tid < 128) {
      const ushort* Vb = UV;
      #pragma unroll
      for (int s=0;s<64;++s) u[s] = bts[s]*bf2f(Vb[s*128 + tid]);
    } else {
      #pragma unroll
      for (int s=0;s<64;++s) u[s] = bGs[s]*bf2f(Kbf[s*SPITCH + (tid-128)]);
    }
  }
  __syncthreads();   // all Vbf reads complete before Ut overwrites the region
  if (tid < 192) {
    #pragma unroll
    for (int t=1;t<64;++t) {
      const float4* Ar = (const float4*)(Af + t*APITCH);
      float p0=0.f,p1=0.f,p2=0.f,p3=0.f;
      #pragma unroll
      for (int s4=0; s4*4<t; ++s4) {   // A upper zero-padded -> safe overshoot
        float4 a = Ar[s4];
        p0 += a.x*u[s4*4+0]; p1 += a.y*u[s4*4+1];
        p2 += a.z*u[s4*4+2]; p3 += a.w*u[s4*4+3];
      }
      u[t] -= (p0+p1)+(p2+p3);
    }
    ushort* Ut = UV;
    uint4* dst = (uint4*)&Ut[tid*SPITCH];
    #pragma unroll
    for (int i=0;i<8;++i) {
      uint32_t w0 = ((uint32_t)f2bf(u[8*i+1])<<16) | f2bf(u[8*i+0]);
      uint32_t w1 = ((uint32_t)f2bf(u[8*i+3])<<16) | f2bf(u[8*i+2]);
      uint32_t w2 = ((uint32_t)f2bf(u[8*i+5])<<16) | f2bf(u[8*i+4]);
      uint32_t w3 = ((uint32_t)f2bf(u[8*i+7])<<16) | f2bf(u[8*i+6]);
      dst[i] = make_uint4(w0,w1,w2,w3);
    }
  }
  __syncthreads();
  // ---- ph3: CQ = Q.K^T -> P (scaled, lower incl diag), overlays A ----
  {
    const int r0 = wave*16;
    f32x4 accs[4];
    #pragma unroll
    for (int ct=0; ct<4; ++ct) accs[ct] = tile64(Qbf, r0, Kbf, ct*16, lane);
    __syncthreads();   // all A reads done (none remain) before P overwrite; cheap safety
    #pragma unroll
    for (int ct=0; ct<4; ++ct) {
      int t = r0 + ((lane>>4)<<2);
      int s = ct*16 + (lane&15);
      #pragma unroll
      for (int q=0;q<4;q++){
        int tq = t + q;
        float val = (s <= tq) ? expf(cgs[tq]-cgs[s])*accs[ct][q] : 0.f;
        Pf[tq*SPITCH + s] = f2bf(val);
      }
    }
  }
  __syncthreads();
  // ---- ph4: output GEMMs ----
  {
    const int r0 = wave*16;
    const float gend = expf(cgs[63]);
    const ushort* Ut = UV;
    const ushort* UtK = UV + 128*SPITCH;
    const size_t bb = ((size_t)bhe*NC_ + c)*(size_t)(64*128);
    const size_t mb = ((size_t)bhe*NC_ + c)*(size_t)(64*64);
    // G3: O0 = P * uV^T  -> o_r
    #pragma unroll
    for (int jt=0; jt<8; ++jt) {
      f32x4 acc = tile64(Pf, r0, Ut, jt*16, lane);
      int t = r0 + ((lane>>4)<<2);
      int j = jt*16 + (lane&15);
      #pragma unroll
      for (int q=0;q<4;q++)
        o_r[((l0 + t + q)*HE_ + he)*DV_ + j] = acc[q];
    }
    // G4: Bc = KTD * uV^T
    #pragma unroll
    for (int jt=0; jt<8; ++jt) {
      f32x4 acc = tile64(KTD, r0, Ut, jt*16, lane);
      int i = r0 + ((lane>>4)<<2);
      int j = jt*16 + (lane&15);
      #pragma unroll
      for (int q=0;q<4;q++)
        Bc[bb + (size_t)(i+q)*128 + j] = acc[q];
    }
    // G5: Mc[m][i] = gend*delta - (KTD * uK^T)[i][m]
    #pragma unroll
    for (int ct=0; ct<4; ++ct) {
      f32x4 acc = tile64(KTD, r0, UtK, ct*16, lane);
      int i = r0 + ((lane>>4)<<2);
      int m = ct*16 + (lane&15);
      #pragma unroll
      for (int q=0;q<4;q++){
        float val = -acc[q];
        if (i + q == m) val += gend;
        Mc[mb + (size_t)m*64 + (i+q)] = val;
      }
    }
    // G6: Qt[t][m] = gam_t*Q[t][m] - (P * uK^T)[t][m]
    #pragma unroll
    for (int ct=0; ct<4; ++ct) {
      f32x4 acc = tile64(Pf, r0, UtK, ct*16, lane);
      int t = r0 + ((lane>>4)<<2);
      int m = ct*16 + (lane&15);
      #pragma unroll
      for (int q=0;q<4;q++)
        Qt[mb + (size_t)(t+q)*64 + m] = gams[t+q]*bf2f(Qbf[(t+q)*SPITCH + m]) - acc[q];
    }
  }
}

// ---------------- pass B: sequential compose of chunk-start states ----------------
__global__ __launch_bounds__(1024) void compose(const float* __restrict__ Mc,
    const float* __restrict__ Bc, float* __restrict__ SSb)
{
  __shared__ float SS[8192];
  __shared__ float Ml[4096];
  const int bhe = blockIdx.x;
  const int tid = threadIdx.x;
  const int j  = tid & 127;
  const int ih = tid >> 7;
  for (int id = tid; id < 8192; id += 1024) SS[id] = 0.f;
  __syncthreads();
  for (int c = 0; c < NC_; c++) {
    size_t ob = ((size_t)bhe*NC_ + c)*8192;
    for (int id = tid; id < 8192; id += 1024) SSb[ob + id] = SS[id];
    if (c == NC_-1) break;
    size_t mb = ((size_t)bhe*NC_ + c)*4096;
    for (int id = tid; id < 4096; id += 1024) Ml[id] = Mc[mb + id];
    float acc[8];
    #pragma unroll
    for (int i = 0; i < 8; i++) acc[i] = Bc[ob + (size_t)(ih*8+i)*128 + j];
    __syncthreads();
    #pragma unroll 8
    for (int m = 0; m < 64; m++) {
      float ssm = SS[m*128 + j];
      #pragma unroll
      for (int i = 0; i < 8; i++) acc[i] += Ml[m*64 + ih*8 + i] * ssm;
    }
    __syncthreads();
    #pragma unroll
    for (int i = 0; i < 8; i++) SS[(ih*8+i)*128 + j] = acc[i];
    __syncthreads();
  }
}

// ---------------- pass C: o += q~^T * SS ----------------
__global__ __launch_bounds__(256) void correct(const float* __restrict__ SSb,
    const float* __restrict__ Qt, float* __restrict__ o_r)
{
  const int c = blockIdx.x;
  const int bhe = blockIdx.y;
  const int b = bhe >> 4, he = bhe & 15;
  __shared__ float SS[8192];
  __shared__ float Qs[4096];
  const int tid = threadIdx.x;
  size_t sb = ((size_t)bhe*NC_ + c)*8192;
  for (int id = tid; id < 8192; id += 256) SS[id] = SSb[sb + id];
  size_t qb = ((size_t)bhe*NC_ + c)*4096;
  for (int id = tid; id < 4096; id += 256) Qs[id] = Qt[qb + id];
  __syncthreads();
  const int j = tid & 127, th = tid >> 7;
  for (int tt = th*32; tt < th*32 + 32; tt++) {
    float a0=0,a1=0,a2=0,a3=0;
    #pragma unroll
    for (int m = 0; m < 64; m += 4) {
      a0 += Qs[tt*64+m+0]*SS[(m+0)*128+j];
      a1 += Qs[tt*64+m+1]*SS[(m+1)*128+j];
      a2 += Qs[tt*64+m+2]*SS[(m+2)*128+j];
      a3 += Qs[tt*64+m+3]*SS[(m+3)*128+j];
    }
    size_t oi = (((size_t)b*L_ + c*T_ + tt)*HE_ + he)*DV_ + j;
    o_r[oi] += (a0+a1)+(a2+a3);
  }
}

// ---------------- expert combine + RMSNorm*SiLU(gate) -> bf16 ----------------
__global__ __launch_bounds__(128) void combine(const float* __restrict__ o_r,
    const float* __restrict__ w_buf, const float* __restrict__ g_lin,
    const float* __restrict__ norm_w, ushort* __restrict__ o_fin)
{
  int n  = blockIdx.x;
  int h  = n & 3;
  int bl = n >> 2;
  int j  = threadIdx.x;
  size_t wb = (size_t)bl*16 + h*4;
  size_t ob = wb*128 + j;
  float oc = 0.f;
  #pragma unroll
  for (int r = 0; r < 4; r++) oc += w_buf[wb+r] * o_r[ob + (size_t)r*128];
  float ss = oc*oc;
  #pragma unroll
  for (int off = 32; off > 0; off >>= 1) ss += __shfl_xor(ss, off);
  __shared__ float red[2];
  if ((threadIdx.x & 63) == 0) red[threadIdx.x >> 6] = ss;
  __syncthreads();
  float mean = (red[0] + red[1]) * (1.f/128.f);
  float sc = rsqrtf(mean + 1e-5f);
  float gv = g_lin[(size_t)bl*512 + h*128 + j];
  o_fin[(size_t)bl*512 + h*128 + j] = f2bf(oc * sc * norm_w[j] * (gv * sigmoidf_(gv)));
}

extern "C" void kernel_launch(void* const* d_in, const int* in_sizes, int n_in,
                              void* d_out, int out_size, void* d_ws, size_t ws_size,
                              hipStream_t stream)
{
  (void)in_sizes; (void)n_in; (void)out_size; (void)ws_size;
  const float* x       = (const float*)d_in[0];
  const float* Wq      = (const float*)d_in[1];
  const float* Wk      = (const float*)d_in[2];
  const float* Wv      = (const float*)d_in[3];
  const float* Wb      = (const float*)d_in[4];
  const float* Wa      = (const float*)d_in[5];
  const float* Wg      = (const float*)d_in[6];
  const float* Wo      = (const float*)d_in[7];
  const float* conv_q  = (const float*)d_in[8];
  const float* conv_k  = (const float*)d_in[9];
  const float* conv_v  = (const float*)d_in[10];
  const float* Wq_exp  = (const float*)d_in[11];
  const float* Wk_exp  = (const float*)d_in[12];
  const float* W_gate  = (const float*)d_in[13];
  const float* A_log   = (const float*)d_in[14];
  const float* dt_bias = (const float*)d_in[15];
  const float* norm_w  = (const float*)d_in[16];
  float* out = (float*)d_out;

  const size_t BL = (size_t)B_*L_;   // 4096
  float* p = (float*)d_ws;
  float* q_lin  = p; p += BL*256;
  float* k_lin  = p; p += BL*256;
  float* v_lin  = p; p += BL*512;
  float* ba_lin = p; p += BL*32;
  float* g_lin  = p; p += BL*512;
  float* q_conv = p; p += BL*256;
  float* k_conv = p; p += BL*256;
  float* v_conv = p; p += BL*512;
  float* qe     = p; p += BL*1024;
  float* ke     = p; p += BL*1024;
  float* w_buf  = p; p += BL*16;
  float* bt_buf = p; p += BL*16;
  float* g_buf  = p; p += BL*16;
  float* Wba    = p; p += 32*1024;
  float* Mc     = p; p += (size_t)B_*HE_*NC_*64*64;
  float* Bc     = p; p += (size_t)B_*HE_*NC_*64*128;
  float* SSb    = p; p += (size_t)B_*HE_*NC_*64*128;
  float* Qt     = p; p += (size_t)B_*HE_*NC_*64*64;
  float* o_r    = p; p += BL*16*128;
  ushort* xb    = (ushort*)p; p += BL*512;
  ushort* Wvb   = (ushort*)p; p += 262144;
  ushort* Wgb   = (ushort*)p; p += 262144;
  ushort* Wob   = (ushort*)p; p += 262144;
  ushort* o_finb= (ushort*)p; p += BL*256;

  #define GEMM_(Ap,lda,Bp,ldb,Cp,ldc,M,N,K) \
    gemm_f32<<<dim3(((N)+63)/64,(M)/64), dim3(256), 0, stream>>>(Ap,lda,Bp,ldb,Cp,ldc,M,N,K)
  #define GEMMB_(Ap,lda,Bp,ldb,Cp,ldc,M,N,K) \
    gemm_bf16<<<dim3((N)/128,(M)/128), dim3(256), 0, stream>>>(Ap,lda,Bp,ldb,Cp,ldc,M,N,K)

  // weight concat for fused b/a projection
  hipMemcpyAsync(Wba, Wb, 16*1024*sizeof(float), hipMemcpyDeviceToDevice, stream);
  hipMemcpyAsync(Wba + 16*1024, Wa, 16*1024*sizeof(float), hipMemcpyDeviceToDevice, stream);

  // casts
  { int n = (int)(BL*1024); cast_bf16<<<dim3((n+255)/256), dim3(256), 0, stream>>>(x,  xb,  n); }
  { int n = 512*1024;       cast_bf16<<<dim3((n+255)/256), dim3(256), 0, stream>>>(Wv, Wvb, n); }
  { int n = 512*1024;       cast_bf16<<<dim3((n+255)/256), dim3(256), 0, stream>>>(Wg, Wgb, n); }
  { int n = 1024*512;       cast_bf16<<<dim3((n+255)/256), dim3(256), 0, stream>>>(Wo, Wob, n); }

  GEMM_(x,1024, Wq,1024, q_lin,256, 4096,256,1024);
  GEMM_(x,1024, Wk,1024, k_lin,256, 4096,256,1024);
  GEMM_(x,1024, Wba,1024, ba_lin,32, 4096,32,1024);
  GEMMB_(xb,1024, Wvb,1024, v_lin,512, 4096,512,1024);
  GEMMB_(xb,1024, Wgb,1024, g_lin,512, 4096,512,1024);

  { int tot = B_*L_*256; conv_silu<<<dim3((tot+255)/256), dim3(256), 0, stream>>>(q_lin, conv_q, q_conv, 256, tot); }
  { int tot = B_*L_*256; conv_silu<<<dim3((tot+255)/256), dim3(256), 0, stream>>>(k_lin, conv_k, k_conv, 256, tot); }
  { int tot = B_*L_*512; conv_silu<<<dim3((tot+255)/256), dim3(256), 0, stream>>>(v_lin, conv_v, v_conv, 512, tot); }

  routing<<<dim3(64), dim3(256), 0, stream>>>(q_conv, ba_lin, W_gate, A_log, dt_bias,
                                              w_buf, bt_buf, g_buf);

  gemm_expand<<<dim3(4, 64, 8), dim3(256), 0, stream>>>(q_conv, k_conv, Wq_exp, Wk_exp, qe, ke);

  l2norm_rows<<<dim3(16384), dim3(256), 0, stream>>>(qe, 0.125f);
  l2norm_rows<<<dim3(16384), dim3(256), 0, stream>>>(ke, 1.0f);

  scan_chunk_mfma<<<dim3(NC_, HE_, B_), dim3(256), 0, stream>>>(ke, qe, v_conv, bt_buf, g_buf,
                                                                o_r, Qt, Mc, Bc);
  compose<<<dim3(B_*HE_), dim3(1024), 0, stream>>>(Mc, Bc, SSb);
  correct<<<dim3(NC_, B_*HE_), dim3(256), 0, stream>>>(SSb, Qt, o_r);
  combine<<<dim3(B_*L_*H_), dim3(128), 0, stream>>>(o_r, w_buf, g_lin, norm_w, o_finb);

  GEMMB_(o_finb,512, Wob,512, out,1024, 4096,1024,512);
  #undef GEMM_
  #undef GEMMB_
}

// Round 5
// 501.655 us; speedup vs baseline: 2.1871x; 1.5393x over previous
//
#include <hip/hip_runtime.h>
#include <hip/hip_bf16.h>
#include <math.h>

#define B_    2
#define L_    2048
#define HID_  1024
#define H_    4
#define DK_   64
#define RATIO_ 4
#define HE_   16
#define DV_   128
#define T_    64
#define NC_   32   // L_/T_
#define SPITCH 72  // bf16 LDS row pitch
#define APITCH 68  // f32 A-matrix LDS pitch
#define NCAT  1408 // concat projection width: k256 v512 g512 b16 a16 pad96

typedef __attribute__((ext_vector_type(8))) short short8;
typedef __attribute__((ext_vector_type(4))) float f32x4;

__device__ __forceinline__ float sigmoidf_(float x){ return 1.f/(1.f+expf(-x)); }
__device__ __forceinline__ ushort f2bf(float x){
  __hip_bfloat16 h = __float2bfloat16(x);
  return *reinterpret_cast<ushort*>(&h);
}
__device__ __forceinline__ float bf2f(ushort u){
  union { uint32_t i; float f; } v; v.i = ((uint32_t)u) << 16; return v.f;
}

// ---------------- f32 -> bf16 cast ----------------
__global__ __launch_bounds__(256) void cast_bf16(const float* __restrict__ in,
                                                 ushort* __restrict__ out, int n)
{
  int i = blockIdx.x*256 + threadIdx.x;
  if (i < n) out[i] = f2bf(in[i]);
}

// ---------------- concat weights [k|v|g|b|a|pad] -> bf16 [1408][1024] ----------------
__global__ __launch_bounds__(256) void concat_wcat(const float* __restrict__ Wk,
    const float* __restrict__ Wv, const float* __restrict__ Wg,
    const float* __restrict__ Wb, const float* __restrict__ Wa,
    ushort* __restrict__ Wcat)
{
  int idx = blockIdx.x*256 + threadIdx.x;
  if (idx >= NCAT*1024) return;
  int r = idx >> 10, cc = idx & 1023;
  float v = 0.f;
  if      (r < 256)  v = Wk[(size_t)r*1024 + cc];
  else if (r < 768)  v = Wv[(size_t)(r-256)*1024 + cc];
  else if (r < 1280) v = Wg[(size_t)(r-768)*1024 + cc];
  else if (r < 1296) v = Wb[(size_t)(r-1280)*1024 + cc];
  else if (r < 1312) v = Wa[(size_t)(r-1296)*1024 + cc];
  Wcat[idx] = f2bf(v);
}

// ---------------- bf16 MFMA GEMM (f32 out): C = A(MxK) * B(NxK)^T ----------------
__global__ __launch_bounds__(256) void gemm_bf16(
    const ushort* __restrict__ A, int lda,
    const ushort* __restrict__ Bm, int ldb,
    float* __restrict__ C, int ldc, int K)
{
  __shared__ ushort As[128*32];
  __shared__ ushort Bs[128*32];
  const int tid  = threadIdx.x;
  const int wave = tid >> 6, lane = tid & 63;
  const int row0 = blockIdx.y*128, col0 = blockIdx.x*128;
  const int wr = (wave >> 1) * 64, wc = (wave & 1) * 64;
  const int frow = lane & 15;
  const int fko  = (lane >> 4) << 3;
  f32x4 acc[4][4];
  #pragma unroll
  for (int i=0;i<4;i++)
    #pragma unroll
    for (int j=0;j<4;j++) acc[i][j] = (f32x4){0.f,0.f,0.f,0.f};
  for (int k0 = 0; k0 < K; k0 += 32) {
    #pragma unroll
    for (int cc = 0; cc < 2; cc++) {
      int c  = wave*128 + cc*64 + lane;
      int r  = c >> 2;
      int ko = (c & 3) << 3;
      __builtin_amdgcn_global_load_lds(
        (const __attribute__((address_space(1))) void*)(A + (size_t)(row0+r)*lda + k0 + ko),
        (__attribute__((address_space(3))) void*)(As + (size_t)(wave*128 + cc*64)*8),
        16, 0, 0);
      __builtin_amdgcn_global_load_lds(
        (const __attribute__((address_space(1))) void*)(Bm + (size_t)(col0+r)*ldb + k0 + ko),
        (__attribute__((address_space(3))) void*)(Bs + (size_t)(wave*128 + cc*64)*8),
        16, 0, 0);
    }
    __syncthreads();
    short8 af[4], bfv[4];
    #pragma unroll
    for (int mi=0;mi<4;mi++)
      af[mi] = *reinterpret_cast<const short8*>(&As[(wr + mi*16 + frow)*32 + fko]);
    #pragma unroll
    for (int ni=0;ni<4;ni++)
      bfv[ni] = *reinterpret_cast<const short8*>(&Bs[(wc + ni*16 + frow)*32 + fko]);
    #pragma unroll
    for (int mi=0;mi<4;mi++)
      #pragma unroll
      for (int ni=0;ni<4;ni++)
        acc[mi][ni] = __builtin_amdgcn_mfma_f32_16x16x32_bf16(af[mi], bfv[ni], acc[mi][ni], 0, 0, 0);
    __syncthreads();
  }
  const int ocol = lane & 15;
  const int orow = (lane >> 4) << 2;
  #pragma unroll
  for (int mi=0;mi<4;mi++)
    #pragma unroll
    for (int ni=0;ni<4;ni++) {
      size_t base = (size_t)(row0 + wr + mi*16 + orow)*ldc + (col0 + wc + ni*16 + ocol);
      #pragma unroll
      for (int q=0;q<4;q++) C[base + (size_t)q*ldc] = acc[mi][ni][q];
    }
}

// ---------------- batched bf16 expansion GEMM (bf16 out), z = (q/k)*4 + h ----------------
__global__ __launch_bounds__(256) void gemm_expand_bf16(
    const ushort* __restrict__ qc_bf, const ushort* __restrict__ kc_bf,
    const ushort* __restrict__ Wqeb, const ushort* __restrict__ Wkeb,
    ushort* __restrict__ qeb, ushort* __restrict__ keb)
{
  const int z = blockIdx.z;
  const int hh = z & 3;
  const ushort* A  = (z < 4 ? qc_bf : kc_bf) + hh*64;      // lda 256
  const ushort* Bm = (z < 4 ? Wqeb  : Wkeb ) + (size_t)hh*16384; // ldb 64
  ushort* C        = (z < 4 ? qeb   : keb  ) + hh*256;     // ldc 1024
  const int lda = 256, ldb = 64, ldc = 1024, K = 64;
  __shared__ ushort As[128*32];
  __shared__ ushort Bs[128*32];
  const int tid  = threadIdx.x;
  const int wave = tid >> 6, lane = tid & 63;
  const int row0 = blockIdx.y*128, col0 = blockIdx.x*128;
  const int wr = (wave >> 1) * 64, wc = (wave & 1) * 64;
  const int frow = lane & 15;
  const int fko  = (lane >> 4) << 3;
  f32x4 acc[4][4];
  #pragma unroll
  for (int i=0;i<4;i++)
    #pragma unroll
    for (int j=0;j<4;j++) acc[i][j] = (f32x4){0.f,0.f,0.f,0.f};
  for (int k0 = 0; k0 < K; k0 += 32) {
    #pragma unroll
    for (int cc = 0; cc < 2; cc++) {
      int c  = wave*128 + cc*64 + lane;
      int r  = c >> 2;
      int ko = (c & 3) << 3;
      __builtin_amdgcn_global_load_lds(
        (const __attribute__((address_space(1))) void*)(A + (size_t)(row0+r)*lda + k0 + ko),
        (__attribute__((address_space(3))) void*)(As + (size_t)(wave*128 + cc*64)*8),
        16, 0, 0);
      __builtin_amdgcn_global_load_lds(
        (const __attribute__((address_space(1))) void*)(Bm + (size_t)(col0+r)*ldb + k0 + ko),
        (__attribute__((address_space(3))) void*)(Bs + (size_t)(wave*128 + cc*64)*8),
        16, 0, 0);
    }
    __syncthreads();
    short8 af[4], bfv[4];
    #pragma unroll
    for (int mi=0;mi<4;mi++)
      af[mi] = *reinterpret_cast<const short8*>(&As[(wr + mi*16 + frow)*32 + fko]);
    #pragma unroll
    for (int ni=0;ni<4;ni++)
      bfv[ni] = *reinterpret_cast<const short8*>(&Bs[(wc + ni*16 + frow)*32 + fko]);
    #pragma unroll
    for (int mi=0;mi<4;mi++)
      #pragma unroll
      for (int ni=0;ni<4;ni++)
        acc[mi][ni] = __builtin_amdgcn_mfma_f32_16x16x32_bf16(af[mi], bfv[ni], acc[mi][ni], 0, 0, 0);
    __syncthreads();
  }
  const int ocol = lane & 15;
  const int orow = (lane >> 4) << 2;
  #pragma unroll
  for (int mi=0;mi<4;mi++)
    #pragma unroll
    for (int ni=0;ni<4;ni++) {
      size_t base = (size_t)(row0 + wr + mi*16 + orow)*ldc + (col0 + wc + ni*16 + ocol);
      #pragma unroll
      for (int q=0;q<4;q++) C[base + (size_t)q*ldc] = f2bf(acc[mi][ni][q]);
    }
}

// ---------------- generic f32 GEMM (Wq only): C = A(MxK) * B(NxK)^T ----------------
__global__ __launch_bounds__(256) void gemm_f32(const float* __restrict__ A, int lda,
    const float* __restrict__ Bm, int ldb, float* __restrict__ C, int ldc,
    int M, int N, int K)
{
  __shared__ float As[32][64];
  __shared__ float Bs[32][64];
  const int tid = threadIdx.x;
  const int row0 = blockIdx.y * 64;
  const int col0 = blockIdx.x * 64;
  const int tx = tid & 15, ty = tid >> 4;
  float acc[4][4] = {};
  for (int k0 = 0; k0 < K; k0 += 32) {
    #pragma unroll
    for (int ld = 0; ld < 2; ld++) {
      int id = tid + ld*256;
      int r  = id >> 3;
      int k4 = (id & 7) << 2;
      float4 av = *reinterpret_cast<const float4*>(&A[(size_t)(row0+r)*lda + k0 + k4]);
      As[k4+0][r] = av.x; As[k4+1][r] = av.y; As[k4+2][r] = av.z; As[k4+3][r] = av.w;
      float4 bv = make_float4(0.f,0.f,0.f,0.f);
      if (col0 + r < N) bv = *reinterpret_cast<const float4*>(&Bm[(size_t)(col0+r)*ldb + k0 + k4]);
      Bs[k4+0][r] = bv.x; Bs[k4+1][r] = bv.y; Bs[k4+2][r] = bv.z; Bs[k4+3][r] = bv.w;
    }
    __syncthreads();
    #pragma unroll
    for (int kk = 0; kk < 32; kk++) {
      float4 a4 = *reinterpret_cast<const float4*>(&As[kk][ty*4]);
      float4 b4 = *reinterpret_cast<const float4*>(&Bs[kk][tx*4]);
      float a[4] = {a4.x,a4.y,a4.z,a4.w};
      float b[4] = {b4.x,b4.y,b4.z,b4.w};
      #pragma unroll
      for (int i=0;i<4;i++)
        #pragma unroll
        for (int j=0;j<4;j++) acc[i][j] += a[i]*b[j];
    }
    __syncthreads();
  }
  #pragma unroll
  for (int i=0;i<4;i++) {
    int r = row0 + ty*4 + i;
    #pragma unroll
    for (int j=0;j<4;j++) {
      int cc = col0 + tx*4 + j;
      if (cc < N) C[(size_t)r*ldc + cc] = acc[i][j];
    }
  }
}

// ---------------- causal depthwise conv (KS=4) + SiLU, optional f32/bf16 outs ----------------
__global__ __launch_bounds__(256) void conv_silu(const float* __restrict__ in, int ild,
    const float* __restrict__ w, float* __restrict__ outf, ushort* __restrict__ outb,
    int C, int total)
{
  int n = blockIdx.x*256 + threadIdx.x;
  if (n >= total) return;
  int c = n % C;
  int t = (n / C) % L_;
  int b = n / (C*L_);
  float acc = 0.f;
  #pragma unroll
  for (int s = 0; s < 4; s++) {
    int tt = t - 3 + s;
    if (tt >= 0) acc += in[((size_t)b*L_ + tt)*ild + c] * w[c*4+s];
  }
  float y = acc * sigmoidf_(acc);
  if (outf) outf[n] = y;
  if (outb) outb[n] = f2bf(y);
}

// ---------------- routing + beta + g ----------------
__global__ __launch_bounds__(256) void routing(const float* __restrict__ qc,
    const float* __restrict__ kvgba, const float* __restrict__ Wg3,
    const float* __restrict__ A_log, const float* __restrict__ dt_bias,
    float* __restrict__ w_buf, float* __restrict__ bt_buf, float* __restrict__ g_buf)
{
  int n = blockIdx.x*256 + threadIdx.x;
  int h  = n & 3;
  int bl = n >> 2;
  const float* q = qc + (size_t)bl*256 + h*64;
  float l0=0.f, l1=0.f, l2=0.f;
  for (int d=0; d<64; d++) {
    float qd = q[d];
    l0 += qd*Wg3[d]; l1 += qd*Wg3[64+d]; l2 += qd*Wg3[128+d];
  }
  float mx = fmaxf(l0, fmaxf(l1, l2));
  float e0 = expf(l0-mx), e1 = expf(l1-mx), e2 = expf(l2-mx);
  float inv_s = 1.f/(e0+e1+e2);
  float p0 = e0*inv_s, p1 = e1*inv_s, p2 = e2*inv_s;
  int m1 = 0; float pm1 = p0;
  if (p1 > pm1) { m1 = 1; pm1 = p1; }
  if (p2 > pm1) { m1 = 2; pm1 = p2; }
  int ia = (m1==0) ? 1 : 0;
  int ib = (m1==2) ? 1 : 2;
  float pa = (m1==0) ? p1 : p0;
  float pb = (m1==2) ? p1 : p2;
  int   m2  = (pb > pa) ? ib : ia;
  float pm2 = (pb > pa) ? pb : pa;
  float inv_w = 1.f/(pm1 + pm2);
  float w1 = 0.5f*pm1*inv_w;
  float w2 = 0.5f*pm2*inv_w;
  #pragma unroll
  for (int r = 0; r < 4; r++) {
    float wr = (r==0) ? 0.5f : (((r-1)==m1) ? w1 : (((r-1)==m2) ? w2 : 0.f));
    int he = h*4 + r;
    size_t gi = (size_t)bl*16 + he;
    w_buf[gi] = wr;
    float mask = (wr > 0.f) ? 1.f : 0.f;
    bt_buf[gi] = mask * sigmoidf_(kvgba[(size_t)bl*NCAT + 1280 + he]);
    float av = kvgba[(size_t)bl*NCAT + 1296 + he] + dt_bias[he];
    float sp = fmaxf(av, 0.f) + log1pf(expf(-fabsf(av)));
    g_buf[gi] = -expf(A_log[he]) * sp * mask;
  }
}

// ---------------- l2norm over rows of 64 (bf16 in/out) ----------------
__global__ __launch_bounds__(256) void l2norm_rows_bf(ushort* __restrict__ v, float scale)
{
  int row  = blockIdx.x*4 + (threadIdx.x >> 6);
  int lane = threadIdx.x & 63;
  size_t idx = (size_t)row*64 + lane;
  float x = bf2f(v[idx]);
  float ss = x*x;
  #pragma unroll
  for (int off = 32; off > 0; off >>= 1) ss += __shfl_xor(ss, off);
  v[idx] = f2bf(x * rsqrtf(ss + 1e-6f) * scale);
}

// ---------------- MFMA tile helper ----------------
__device__ __forceinline__ f32x4 tile64(const ushort* Am, int r0,
                                        const ushort* Bm, int c0, int lane)
{
  f32x4 acc = {0.f,0.f,0.f,0.f};
  const int fr = lane & 15, fo = (lane >> 4) << 3;
  #pragma unroll
  for (int kk = 0; kk < 2; ++kk) {
    short8 a = *reinterpret_cast<const short8*>(&Am[(r0+fr)*SPITCH + fo + kk*32]);
    short8 b = *reinterpret_cast<const short8*>(&Bm[(c0+fr)*SPITCH + fo + kk*32]);
    acc = __builtin_amdgcn_mfma_f32_16x16x32_bf16(a, b, acc, 0, 0, 0);
  }
  return acc;
}

// ---------------- pass A via WY/UT transform + MFMA ----------------
__global__ __launch_bounds__(256,2) void scan_chunk_mfma(
    const ushort* __restrict__ keb, const ushort* __restrict__ qeb,
    const float* __restrict__ vc, const float* __restrict__ bt_buf,
    const float* __restrict__ g_buf, float* __restrict__ o_r,
    float* __restrict__ Qt, float* __restrict__ Mc, float* __restrict__ Bc)
{
  __shared__ float smem[18496];                       // 73984 B
  ushort* Kbf = (ushort*)smem;                        // [64][72] bf16
  ushort* Qbf = (ushort*)(smem + 2304);               // [64][72] bf16
  ushort* KTD = (ushort*)(smem + 4608);               // [64][72] bf16 (K^T, D-scaled)
  float*  Af  = smem + 6912;                          // [64][68] f32 (A matrix)
  ushort* Pf  = (ushort*)(smem + 6912);               // overlay after substitution
  ushort* UV  = (ushort*)(smem + 11264);              // Vbf [64][128] then Ut [192][72]
  float*  cgs = smem + 18176;
  float*  bts = cgs + 64;
  float*  bGs = bts + 64;
  float*  Ds  = bGs + 64;
  float*  gams= Ds + 64;

  const int c  = blockIdx.x;
  const int he = blockIdx.y;
  const int b  = blockIdx.z;
  const int bhe = b*HE_ + he;
  const int h = he >> 2;
  const int tid = threadIdx.x;
  const int wave = tid >> 6, lane = tid & 63;
  const size_t l0 = (size_t)b*L_ + (size_t)c*T_;

  // ---- ph0a: global loads to regs + g-scan (wave 0) ----
  const int tr = tid >> 2;      // row 0..63
  const int sg = tid & 3;       // quarter
  uint32_t kwv[8], qwv[8];
  float4 vreg[8];
  {
    const uint4* kp = (const uint4*)(keb + (l0+tr)*1024 + he*64 + sg*16);
    const uint4* qp = (const uint4*)(qeb + (l0+tr)*1024 + he*64 + sg*16);
    uint4 k0 = kp[0], k1 = kp[1], q0 = qp[0], q1 = qp[1];
    kwv[0]=k0.x; kwv[1]=k0.y; kwv[2]=k0.z; kwv[3]=k0.w;
    kwv[4]=k1.x; kwv[5]=k1.y; kwv[6]=k1.z; kwv[7]=k1.w;
    qwv[0]=q0.x; qwv[1]=q0.y; qwv[2]=q0.z; qwv[3]=q0.w;
    qwv[4]=q1.x; qwv[5]=q1.y; qwv[6]=q1.z; qwv[7]=q1.w;
    const float4* vp = (const float4*)&vc[(l0+tr)*(H_*DV_) + h*DV_ + sg*32];
    #pragma unroll
    for (int i=0;i<8;i++) vreg[i] = vp[i];
  }
  if (tid < 64) {
    float g  = g_buf[(l0+tid)*HE_ + he];
    float bt = bt_buf[(l0+tid)*HE_ + he];
    float cg = g;
    #pragma unroll
    for (int off = 1; off < 64; off <<= 1) {
      float o = __shfl_up(cg, off);
      if (tid >= off) cg += o;
    }
    float cg63 = __shfl(cg, 63);
    cgs[tid] = cg; bts[tid] = bt;
    float gm = expf(cg);
    gams[tid] = gm; bGs[tid] = bt*gm; Ds[tid] = expf(cg63 - cg);
  }
  __syncthreads();
  // ---- ph0b: LDS stores ----
  {
    float Dt = Ds[tr];
    uint2* kdst = (uint2*)(Kbf + tr*SPITCH + sg*16);
    uint2* qdst = (uint2*)(Qbf + tr*SPITCH + sg*16);
    #pragma unroll
    for (int i=0;i<4;i++){
      kdst[i] = make_uint2(kwv[2*i], kwv[2*i+1]);
      qdst[i] = make_uint2(qwv[2*i], qwv[2*i+1]);
    }
    #pragma unroll
    for (int i=0;i<8;i++){
      ushort lo = (ushort)(kwv[i] & 0xffff), hi = (ushort)(kwv[i] >> 16);
      int d = sg*16 + 2*i;
      KTD[(d+0)*SPITCH + tr] = f2bf(bf2f(lo)*Dt);
      KTD[(d+1)*SPITCH + tr] = f2bf(bf2f(hi)*Dt);
    }
    ushort* Vb = UV;
    #pragma unroll
    for (int i=0;i<8;i++){
      float vv[4] = {vreg[i].x,vreg[i].y,vreg[i].z,vreg[i].w};
      #pragma unroll
      for (int j=0;j<4;j++)
        Vb[tr*128 + sg*32 + i*4 + j] = f2bf(vv[j]);
    }
  }
  __syncthreads();
  // ---- ph1: CK = K.K^T -> A (scaled, strictly lower, zero elsewhere) ----
  {
    const int r0 = wave*16;
    #pragma unroll
    for (int ct=0; ct<4; ++ct) {
      f32x4 acc = tile64(Kbf, r0, Kbf, ct*16, lane);
      int t = r0 + ((lane>>4)<<2);
      int s = ct*16 + (lane&15);
      #pragma unroll
      for (int q=0;q<4;q++){
        int tq = t + q;
        Af[tq*APITCH + s] = (s < tq) ? bts[tq]*expf(cgs[tq]-cgs[s])*acc[q] : 0.f;
      }
    }
  }
  __syncthreads();
  // ---- ph2: forward substitution u = (I+A)^-1 [beta*V | betaGamma*K] ----
  float u[64];
  if (tid < 192) {
    if (tid < 128) {
      const ushort* Vb = UV;
      #pragma unroll
      for (int s=0;s<64;++s) u[s] = bts[s]*bf2f(Vb[s*128 + tid]);
    } else {
      #pragma unroll
      for (int s=0;s<64;++s) u[s] = bGs[s]*bf2f(Kbf[s*SPITCH + (tid-128)]);
    }
  }
  __syncthreads();
  if (tid < 192) {
    #pragma unroll
    for (int t=1;t<64;++t) {
      const float4* Ar = (const float4*)(Af + t*APITCH);
      float p0=0.f,p1=0.f,p2=0.f,p3=0.f;
      #pragma unroll
      for (int s4=0; s4*4<t; ++s4) {
        float4 a = Ar[s4];
        p0 += a.x*u[s4*4+0]; p1 += a.y*u[s4*4+1];
        p2 += a.z*u[s4*4+2]; p3 += a.w*u[s4*4+3];
      }
      u[t] -= (p0+p1)+(p2+p3);
    }
    ushort* Ut = UV;
    uint4* dst = (uint4*)&Ut[tid*SPITCH];
    #pragma unroll
    for (int i=0;i<8;++i) {
      uint32_t w0 = ((uint32_t)f2bf(u[8*i+1])<<16) | f2bf(u[8*i+0]);
      uint32_t w1 = ((uint32_t)f2bf(u[8*i+3])<<16) | f2bf(u[8*i+2]);
      uint32_t w2 = ((uint32_t)f2bf(u[8*i+5])<<16) | f2bf(u[8*i+4]);
      uint32_t w3 = ((uint32_t)f2bf(u[8*i+7])<<16) | f2bf(u[8*i+6]);
      dst[i] = make_uint4(w0,w1,w2,w3);
    }
  }
  __syncthreads();
  // ---- ph3: CQ = Q.K^T -> P (scaled, lower incl diag), overlays A ----
  {
    const int r0 = wave*16;
    f32x4 accs[4];
    #pragma unroll
    for (int ct=0; ct<4; ++ct) accs[ct] = tile64(Qbf, r0, Kbf, ct*16, lane);
    __syncthreads();
    #pragma unroll
    for (int ct=0; ct<4; ++ct) {
      int t = r0 + ((lane>>4)<<2);
      int s = ct*16 + (lane&15);
      #pragma unroll
      for (int q=0;q<4;q++){
        int tq = t + q;
        float val = (s <= tq) ? expf(cgs[tq]-cgs[s])*accs[ct][q] : 0.f;
        Pf[tq*SPITCH + s] = f2bf(val);
      }
    }
  }
  __syncthreads();
  // ---- ph4: output GEMMs ----
  {
    const int r0 = wave*16;
    const float gend = expf(cgs[63]);
    const ushort* Ut = UV;
    const ushort* UtK = UV + 128*SPITCH;
    const size_t bb = ((size_t)bhe*NC_ + c)*(size_t)(64*128);
    const size_t mb = ((size_t)bhe*NC_ + c)*(size_t)(64*64);
    #pragma unroll
    for (int jt=0; jt<8; ++jt) {
      f32x4 acc = tile64(Pf, r0, Ut, jt*16, lane);
      int t = r0 + ((lane>>4)<<2);
      int j = jt*16 + (lane&15);
      #pragma unroll
      for (int q=0;q<4;q++)
        o_r[((l0 + t + q)*HE_ + he)*DV_ + j] = acc[q];
    }
    #pragma unroll
    for (int jt=0; jt<8; ++jt) {
      f32x4 acc = tile64(KTD, r0, Ut, jt*16, lane);
      int i = r0 + ((lane>>4)<<2);
      int j = jt*16 + (lane&15);
      #pragma unroll
      for (int q=0;q<4;q++)
        Bc[bb + (size_t)(i+q)*128 + j] = acc[q];
    }
    #pragma unroll
    for (int ct=0; ct<4; ++ct) {
      f32x4 acc = tile64(KTD, r0, UtK, ct*16, lane);
      int i = r0 + ((lane>>4)<<2);
      int m = ct*16 + (lane&15);
      #pragma unroll
      for (int q=0;q<4;q++){
        float val = -acc[q];
        if (i + q == m) val += gend;
        Mc[mb + (size_t)m*64 + (i+q)] = val;
      }
    }
    #pragma unroll
    for (int ct=0; ct<4; ++ct) {
      f32x4 acc = tile64(Pf, r0, UtK, ct*16, lane);
      int t = r0 + ((lane>>4)<<2);
      int m = ct*16 + (lane&15);
      #pragma unroll
      for (int q=0;q<4;q++)
        Qt[mb + (size_t)(t+q)*64 + m] = gams[t+q]*bf2f(Qbf[(t+q)*SPITCH + m]) - acc[q];
    }
  }
}

// ---------------- pass B: column-sliced sequential compose (256 blocks) ----------------
__global__ __launch_bounds__(256) void compose_slice(const float* __restrict__ Mc,
    const float* __restrict__ Bc, float* __restrict__ SSb)
{
  __shared__ float Ml[4096];    // [m][i]
  __shared__ float SSl[1024];   // [i][j], 64 x 16
  const int bhe = blockIdx.x >> 3;
  const int j0  = (blockIdx.x & 7) * 16;
  const int tid = threadIdx.x;
  const int j  = tid & 15;
  const int ig = tid >> 4;      // 0..15 -> rows ig*4..ig*4+3
  for (int id = tid; id < 1024; id += 256) SSl[id] = 0.f;
  __syncthreads();
  for (int c = 0; c < NC_; c++) {
    size_t ob = ((size_t)bhe*NC_ + c)*8192;
    #pragma unroll
    for (int r = 0; r < 4; r++)
      SSb[ob + (size_t)(ig*4+r)*128 + j0 + j] = SSl[(ig*4+r)*16 + j];
    if (c == NC_-1) break;
    size_t mb = ((size_t)bhe*NC_ + c)*4096;
    float bacc0 = Bc[ob + (size_t)(ig*4+0)*128 + j0 + j];
    float bacc1 = Bc[ob + (size_t)(ig*4+1)*128 + j0 + j];
    float bacc2 = Bc[ob + (size_t)(ig*4+2)*128 + j0 + j];
    float bacc3 = Bc[ob + (size_t)(ig*4+3)*128 + j0 + j];
    for (int id = tid; id < 1024; id += 256)
      *(float4*)&Ml[id*4] = *(const float4*)&Mc[mb + (size_t)id*4];
    __syncthreads();
    #pragma unroll 8
    for (int m = 0; m < 64; m++) {
      float ssm = SSl[m*16 + j];
      float4 mv = *(const float4*)&Ml[m*64 + ig*4];
      bacc0 += mv.x*ssm; bacc1 += mv.y*ssm; bacc2 += mv.z*ssm; bacc3 += mv.w*ssm;
    }
    __syncthreads();
    SSl[(ig*4+0)*16 + j] = bacc0;
    SSl[(ig*4+1)*16 + j] = bacc1;
    SSl[(ig*4+2)*16 + j] = bacc2;
    SSl[(ig*4+3)*16 + j] = bacc3;
    __syncthreads();
  }
}

// ---------------- pass C: o += q~^T * SS ----------------
__global__ __launch_bounds__(256) void correct(const float* __restrict__ SSb,
    const float* __restrict__ Qt, float* __restrict__ o_r)
{
  const int c = blockIdx.x;
  const int bhe = blockIdx.y;
  const int b = bhe >> 4, he = bhe & 15;
  __shared__ float SS[8192];
  __shared__ float Qs[4096];
  const int tid = threadIdx.x;
  size_t sb = ((size_t)bhe*NC_ + c)*8192;
  for (int id = tid; id < 8192; id += 256) SS[id] = SSb[sb + id];
  size_t qb = ((size_t)bhe*NC_ + c)*4096;
  for (int id = tid; id < 4096; id += 256) Qs[id] = Qt[qb + id];
  __syncthreads();
  const int j = tid & 127, th = tid >> 7;
  for (int tt = th*32; tt < th*32 + 32; tt++) {
    float a0=0,a1=0,a2=0,a3=0;
    #pragma unroll
    for (int m = 0; m < 64; m += 4) {
      a0 += Qs[tt*64+m+0]*SS[(m+0)*128+j];
      a1 += Qs[tt*64+m+1]*SS[(m+1)*128+j];
      a2 += Qs[tt*64+m+2]*SS[(m+2)*128+j];
      a3 += Qs[tt*64+m+3]*SS[(m+3)*128+j];
    }
    size_t oi = (((size_t)b*L_ + c*T_ + tt)*HE_ + he)*DV_ + j;
    o_r[oi] += (a0+a1)+(a2+a3);
  }
}

// ---------------- expert combine + RMSNorm*SiLU(gate) -> bf16 ----------------
__global__ __launch_bounds__(128) void combine(const float* __restrict__ o_r,
    const float* __restrict__ w_buf, const float* __restrict__ kvgba,
    const float* __restrict__ norm_w, ushort* __restrict__ o_fin)
{
  int n  = blockIdx.x;
  int h  = n & 3;
  int bl = n >> 2;
  int j  = threadIdx.x;
  size_t wb = (size_t)bl*16 + h*4;
  size_t ob = wb*128 + j;
  float oc = 0.f;
  #pragma unroll
  for (int r = 0; r < 4; r++) oc += w_buf[wb+r] * o_r[ob + (size_t)r*128];
  float ss = oc*oc;
  #pragma unroll
  for (int off = 32; off > 0; off >>= 1) ss += __shfl_xor(ss, off);
  __shared__ float red[2];
  if ((threadIdx.x & 63) == 0) red[threadIdx.x >> 6] = ss;
  __syncthreads();
  float mean = (red[0] + red[1]) * (1.f/128.f);
  float sc = rsqrtf(mean + 1e-5f);
  float gv = kvgba[(size_t)bl*NCAT + 768 + h*128 + j];
  o_fin[(size_t)bl*512 + h*128 + j] = f2bf(oc * sc * norm_w[j] * (gv * sigmoidf_(gv)));
}

extern "C" void kernel_launch(void* const* d_in, const int* in_sizes, int n_in,
                              void* d_out, int out_size, void* d_ws, size_t ws_size,
                              hipStream_t stream)
{
  (void)in_sizes; (void)n_in; (void)out_size; (void)ws_size;
  const float* x       = (const float*)d_in[0];
  const float* Wq      = (const float*)d_in[1];
  const float* Wk      = (const float*)d_in[2];
  const float* Wv      = (const float*)d_in[3];
  const float* Wb      = (const float*)d_in[4];
  const float* Wa      = (const float*)d_in[5];
  const float* Wg      = (const float*)d_in[6];
  const float* Wo      = (const float*)d_in[7];
  const float* conv_q  = (const float*)d_in[8];
  const float* conv_k  = (const float*)d_in[9];
  const float* conv_v  = (const float*)d_in[10];
  const float* Wq_exp  = (const float*)d_in[11];
  const float* Wk_exp  = (const float*)d_in[12];
  const float* W_gate  = (const float*)d_in[13];
  const float* A_log   = (const float*)d_in[14];
  const float* dt_bias = (const float*)d_in[15];
  const float* norm_w  = (const float*)d_in[16];
  float* out = (float*)d_out;

  const size_t BL = (size_t)B_*L_;   // 4096
  float* p = (float*)d_ws;
  float* q_lin  = p; p += BL*256;
  float* kvgba  = p; p += BL*NCAT;
  float* q_conv = p; p += BL*256;
  float* v_conv = p; p += BL*512;
  float* w_buf  = p; p += BL*16;
  float* bt_buf = p; p += BL*16;
  float* g_buf  = p; p += BL*16;
  float* Mc     = p; p += (size_t)B_*HE_*NC_*64*64;
  float* Bc     = p; p += (size_t)B_*HE_*NC_*64*128;
  float* SSb    = p; p += (size_t)B_*HE_*NC_*64*128;
  float* Qt     = p; p += (size_t)B_*HE_*NC_*64*64;
  float* o_r    = p; p += BL*16*128;
  ushort* xb    = (ushort*)p; p += BL*512;        // x bf16
  ushort* Wcat  = (ushort*)p; p += (NCAT*1024)/2; // concat weights bf16
  ushort* qc_bf = (ushort*)p; p += BL*128;        // q_conv bf16
  ushort* kc_bf = (ushort*)p; p += BL*128;        // k_conv bf16
  ushort* qeb   = (ushort*)p; p += BL*512;        // qe bf16 [4096][1024]
  ushort* keb   = (ushort*)p; p += BL*512;        // ke bf16
  ushort* Wqeb  = (ushort*)p; p += 32768;         // 4*256*64 bf16
  ushort* Wkeb  = (ushort*)p; p += 32768;
  ushort* Wob   = (ushort*)p; p += 262144;        // 1024*512 bf16
  ushort* o_finb= (ushort*)p; p += BL*256;        // bf16 [4096][512]

  // weight prep
  concat_wcat<<<dim3((NCAT*1024+255)/256), dim3(256), 0, stream>>>(Wk, Wv, Wg, Wb, Wa, Wcat);
  { int n = (int)(BL*1024); cast_bf16<<<dim3((n+255)/256), dim3(256), 0, stream>>>(x, xb, n); }
  { int n = 65536;  cast_bf16<<<dim3((n+255)/256), dim3(256), 0, stream>>>(Wq_exp, Wqeb, n); }
  { int n = 65536;  cast_bf16<<<dim3((n+255)/256), dim3(256), 0, stream>>>(Wk_exp, Wkeb, n); }
  { int n = 524288; cast_bf16<<<dim3((n+255)/256), dim3(256), 0, stream>>>(Wo, Wob, n); }

  // projections
  gemm_f32<<<dim3(4, 64), dim3(256), 0, stream>>>(x, 1024, Wq, 1024, q_lin, 256, 4096, 256, 1024);
  gemm_bf16<<<dim3(NCAT/128, 32), dim3(256), 0, stream>>>(xb, 1024, Wcat, 1024, kvgba, NCAT, 1024);

  // convs (+SiLU)
  { int tot = B_*L_*256; conv_silu<<<dim3((tot+255)/256), dim3(256), 0, stream>>>(q_lin, 256, conv_q, q_conv, qc_bf, 256, tot); }
  { int tot = B_*L_*256; conv_silu<<<dim3((tot+255)/256), dim3(256), 0, stream>>>(kvgba, NCAT, conv_k, (float*)nullptr, kc_bf, 256, tot); }
  { int tot = B_*L_*512; conv_silu<<<dim3((tot+255)/256), dim3(256), 0, stream>>>(kvgba + 256, NCAT, conv_v, v_conv, (ushort*)nullptr, 512, tot); }

  routing<<<dim3(64), dim3(256), 0, stream>>>(q_conv, kvgba, W_gate, A_log, dt_bias,
                                              w_buf, bt_buf, g_buf);

  gemm_expand_bf16<<<dim3(2, 32, 8), dim3(256), 0, stream>>>(qc_bf, kc_bf, Wqeb, Wkeb, qeb, keb);

  // 65536 rows of 64, 4 rows/block -> 16384 blocks (was 4096: the round-4 NaN bug)
  l2norm_rows_bf<<<dim3(16384), dim3(256), 0, stream>>>(qeb, 0.125f);
  l2norm_rows_bf<<<dim3(16384), dim3(256), 0, stream>>>(keb, 1.0f);

  scan_chunk_mfma<<<dim3(NC_, HE_, B_), dim3(256), 0, stream>>>(keb, qeb, v_conv, bt_buf, g_buf,
                                                                o_r, Qt, Mc, Bc);
  compose_slice<<<dim3(B_*HE_*8), dim3(256), 0, stream>>>(Mc, Bc, SSb);
  correct<<<dim3(NC_, B_*HE_), dim3(256), 0, stream>>>(SSb, Qt, o_r);
  combine<<<dim3(B_*L_*H_), dim3(128), 0, stream>>>(o_r, w_buf, kvgba, norm_w, o_finb);

  gemm_bf16<<<dim3(8, 32), dim3(256), 0, stream>>>(o_finb, 512, Wob, 512, out, 1024, 512);
}

// Round 6
// 400.339 us; speedup vs baseline: 2.7406x; 1.2531x over previous
//
#include <hip/hip_runtime.h>
#include <hip/hip_bf16.h>
#include <math.h>

#define B_    2
#define L_    2048
#define HID_  1024
#define H_    4
#define DK_   64
#define RATIO_ 4
#define HE_   16
#define DV_   128
#define T_    64
#define NC_   32   // L_/T_
#define SPITCH 72  // bf16 LDS row pitch
#define APITCH 68  // f32 A-matrix LDS pitch
#define NCAT  1408 // concat projection width: k256 v512 g512 b16 a16 pad96
#define QMP   65   // Qt/Mc global row pitch (f32) -> LDS banks (row+col)%32, conflict-free
#define QMSZ  4160 // 64*65 per chunk

typedef __attribute__((ext_vector_type(8))) short short8;
typedef __attribute__((ext_vector_type(4))) float f32x4;

__device__ __forceinline__ float sigmoidf_(float x){ return 1.f/(1.f+expf(-x)); }
__device__ __forceinline__ ushort f2bf(float x){
  __hip_bfloat16 h = __float2bfloat16(x);
  return *reinterpret_cast<ushort*>(&h);
}
__device__ __forceinline__ float bf2f(ushort u){
  union { uint32_t i; float f; } v; v.i = ((uint32_t)u) << 16; return v.f;
}

// ---------------- f32 -> bf16 cast ----------------
__global__ __launch_bounds__(256) void cast_bf16(const float* __restrict__ in,
                                                 ushort* __restrict__ out, int n)
{
  int i = blockIdx.x*256 + threadIdx.x;
  if (i < n) out[i] = f2bf(in[i]);
}

// ---------------- concat weights [k|v|g|b|a|pad] -> bf16 [1408][1024] ----------------
__global__ __launch_bounds__(256) void concat_wcat(const float* __restrict__ Wk,
    const float* __restrict__ Wv, const float* __restrict__ Wg,
    const float* __restrict__ Wb, const float* __restrict__ Wa,
    ushort* __restrict__ Wcat)
{
  int idx = blockIdx.x*256 + threadIdx.x;
  if (idx >= NCAT*1024) return;
  int r = idx >> 10, cc = idx & 1023;
  float v = 0.f;
  if      (r < 256)  v = Wk[(size_t)r*1024 + cc];
  else if (r < 768)  v = Wv[(size_t)(r-256)*1024 + cc];
  else if (r < 1280) v = Wg[(size_t)(r-768)*1024 + cc];
  else if (r < 1296) v = Wb[(size_t)(r-1280)*1024 + cc];
  else if (r < 1312) v = Wa[(size_t)(r-1296)*1024 + cc];
  Wcat[idx] = f2bf(v);
}

// ---------------- bf16 MFMA GEMM (f32 out): C = A(MxK) * B(NxK)^T ----------------
__global__ __launch_bounds__(256) void gemm_bf16(
    const ushort* __restrict__ A, int lda,
    const ushort* __restrict__ Bm, int ldb,
    float* __restrict__ C, int ldc, int K)
{
  __shared__ ushort As[128*32];
  __shared__ ushort Bs[128*32];
  const int tid  = threadIdx.x;
  const int wave = tid >> 6, lane = tid & 63;
  const int row0 = blockIdx.y*128, col0 = blockIdx.x*128;
  const int wr = (wave >> 1) * 64, wc = (wave & 1) * 64;
  const int frow = lane & 15;
  const int fko  = (lane >> 4) << 3;
  f32x4 acc[4][4];
  #pragma unroll
  for (int i=0;i<4;i++)
    #pragma unroll
    for (int j=0;j<4;j++) acc[i][j] = (f32x4){0.f,0.f,0.f,0.f};
  for (int k0 = 0; k0 < K; k0 += 32) {
    #pragma unroll
    for (int cc = 0; cc < 2; cc++) {
      int c  = wave*128 + cc*64 + lane;
      int r  = c >> 2;
      int ko = (c & 3) << 3;
      __builtin_amdgcn_global_load_lds(
        (const __attribute__((address_space(1))) void*)(A + (size_t)(row0+r)*lda + k0 + ko),
        (__attribute__((address_space(3))) void*)(As + (size_t)(wave*128 + cc*64)*8),
        16, 0, 0);
      __builtin_amdgcn_global_load_lds(
        (const __attribute__((address_space(1))) void*)(Bm + (size_t)(col0+r)*ldb + k0 + ko),
        (__attribute__((address_space(3))) void*)(Bs + (size_t)(wave*128 + cc*64)*8),
        16, 0, 0);
    }
    __syncthreads();
    short8 af[4], bfv[4];
    #pragma unroll
    for (int mi=0;mi<4;mi++)
      af[mi] = *reinterpret_cast<const short8*>(&As[(wr + mi*16 + frow)*32 + fko]);
    #pragma unroll
    for (int ni=0;ni<4;ni++)
      bfv[ni] = *reinterpret_cast<const short8*>(&Bs[(wc + ni*16 + frow)*32 + fko]);
    #pragma unroll
    for (int mi=0;mi<4;mi++)
      #pragma unroll
      for (int ni=0;ni<4;ni++)
        acc[mi][ni] = __builtin_amdgcn_mfma_f32_16x16x32_bf16(af[mi], bfv[ni], acc[mi][ni], 0, 0, 0);
    __syncthreads();
  }
  const int ocol = lane & 15;
  const int orow = (lane >> 4) << 2;
  #pragma unroll
  for (int mi=0;mi<4;mi++)
    #pragma unroll
    for (int ni=0;ni<4;ni++) {
      size_t base = (size_t)(row0 + wr + mi*16 + orow)*ldc + (col0 + wc + ni*16 + ocol);
      #pragma unroll
      for (int q=0;q<4;q++) C[base + (size_t)q*ldc] = acc[mi][ni][q];
    }
}

// ---------------- batched bf16 expansion GEMM (bf16 out), z = (q/k)*4 + h ----------------
__global__ __launch_bounds__(256) void gemm_expand_bf16(
    const ushort* __restrict__ qc_bf, const ushort* __restrict__ kc_bf,
    const ushort* __restrict__ Wqeb, const ushort* __restrict__ Wkeb,
    ushort* __restrict__ qeb, ushort* __restrict__ keb)
{
  const int z = blockIdx.z;
  const int hh = z & 3;
  const ushort* A  = (z < 4 ? qc_bf : kc_bf) + hh*64;      // lda 256
  const ushort* Bm = (z < 4 ? Wqeb  : Wkeb ) + (size_t)hh*16384; // ldb 64
  ushort* C        = (z < 4 ? qeb   : keb  ) + hh*256;     // ldc 1024
  const int lda = 256, ldb = 64, ldc = 1024, K = 64;
  __shared__ ushort As[128*32];
  __shared__ ushort Bs[128*32];
  const int tid  = threadIdx.x;
  const int wave = tid >> 6, lane = tid & 63;
  const int row0 = blockIdx.y*128, col0 = blockIdx.x*128;
  const int wr = (wave >> 1) * 64, wc = (wave & 1) * 64;
  const int frow = lane & 15;
  const int fko  = (lane >> 4) << 3;
  f32x4 acc[4][4];
  #pragma unroll
  for (int i=0;i<4;i++)
    #pragma unroll
    for (int j=0;j<4;j++) acc[i][j] = (f32x4){0.f,0.f,0.f,0.f};
  for (int k0 = 0; k0 < K; k0 += 32) {
    #pragma unroll
    for (int cc = 0; cc < 2; cc++) {
      int c  = wave*128 + cc*64 + lane;
      int r  = c >> 2;
      int ko = (c & 3) << 3;
      __builtin_amdgcn_global_load_lds(
        (const __attribute__((address_space(1))) void*)(A + (size_t)(row0+r)*lda + k0 + ko),
        (__attribute__((address_space(3))) void*)(As + (size_t)(wave*128 + cc*64)*8),
        16, 0, 0);
      __builtin_amdgcn_global_load_lds(
        (const __attribute__((address_space(1))) void*)(Bm + (size_t)(col0+r)*ldb + k0 + ko),
        (__attribute__((address_space(3))) void*)(Bs + (size_t)(wave*128 + cc*64)*8),
        16, 0, 0);
    }
    __syncthreads();
    short8 af[4], bfv[4];
    #pragma unroll
    for (int mi=0;mi<4;mi++)
      af[mi] = *reinterpret_cast<const short8*>(&As[(wr + mi*16 + frow)*32 + fko]);
    #pragma unroll
    for (int ni=0;ni<4;ni++)
      bfv[ni] = *reinterpret_cast<const short8*>(&Bs[(wc + ni*16 + frow)*32 + fko]);
    #pragma unroll
    for (int mi=0;mi<4;mi++)
      #pragma unroll
      for (int ni=0;ni<4;ni++)
        acc[mi][ni] = __builtin_amdgcn_mfma_f32_16x16x32_bf16(af[mi], bfv[ni], acc[mi][ni], 0, 0, 0);
    __syncthreads();
  }
  const int ocol = lane & 15;
  const int orow = (lane >> 4) << 2;
  #pragma unroll
  for (int mi=0;mi<4;mi++)
    #pragma unroll
    for (int ni=0;ni<4;ni++) {
      size_t base = (size_t)(row0 + wr + mi*16 + orow)*ldc + (col0 + wc + ni*16 + ocol);
      #pragma unroll
      for (int q=0;q<4;q++) C[base + (size_t)q*ldc] = f2bf(acc[mi][ni][q]);
    }
}

// ---------------- f32 GEMM with double-buffered LDS (Wq): C = A*B^T ----------------
__global__ __launch_bounds__(256) void gemm_f32_db(const float* __restrict__ A, int lda,
    const float* __restrict__ Bm, int ldb, float* __restrict__ C, int ldc,
    int M, int N, int K)
{
  __shared__ float As[2][32][64];
  __shared__ float Bs[2][32][64];
  const int tid = threadIdx.x;
  const int row0 = blockIdx.y * 64;
  const int col0 = blockIdx.x * 64;
  const int tx = tid & 15, ty = tid >> 4;
  const int r0s = tid >> 3;          // staging row (0..31), second chunk +32
  const int k4s = (tid & 7) << 2;    // staging k quad
  float4 av0, av1, bv0, bv1;

  // load K-tile 0
  av0 = *(const float4*)&A[(size_t)(row0 + r0s)*lda + k4s];
  av1 = *(const float4*)&A[(size_t)(row0 + r0s + 32)*lda + k4s];
  bv0 = (col0 + r0s < N) ? *(const float4*)&Bm[(size_t)(col0 + r0s)*ldb + k4s] : make_float4(0,0,0,0);
  bv1 = (col0 + r0s + 32 < N) ? *(const float4*)&Bm[(size_t)(col0 + r0s + 32)*ldb + k4s] : make_float4(0,0,0,0);
  As[0][k4s+0][r0s] = av0.x; As[0][k4s+1][r0s] = av0.y; As[0][k4s+2][r0s] = av0.z; As[0][k4s+3][r0s] = av0.w;
  As[0][k4s+0][r0s+32] = av1.x; As[0][k4s+1][r0s+32] = av1.y; As[0][k4s+2][r0s+32] = av1.z; As[0][k4s+3][r0s+32] = av1.w;
  Bs[0][k4s+0][r0s] = bv0.x; Bs[0][k4s+1][r0s] = bv0.y; Bs[0][k4s+2][r0s] = bv0.z; Bs[0][k4s+3][r0s] = bv0.w;
  Bs[0][k4s+0][r0s+32] = bv1.x; Bs[0][k4s+1][r0s+32] = bv1.y; Bs[0][k4s+2][r0s+32] = bv1.z; Bs[0][k4s+3][r0s+32] = bv1.w;
  __syncthreads();

  float acc[4][4] = {};
  const int nt = K >> 5;
  for (int kt = 0; kt < nt; ++kt) {
    const int p = kt & 1;
    if (kt + 1 < nt) {   // issue next tile loads early (overlap with compute)
      int k0 = (kt+1) << 5;
      av0 = *(const float4*)&A[(size_t)(row0 + r0s)*lda + k0 + k4s];
      av1 = *(const float4*)&A[(size_t)(row0 + r0s + 32)*lda + k0 + k4s];
      bv0 = (col0 + r0s < N) ? *(const float4*)&Bm[(size_t)(col0 + r0s)*ldb + k0 + k4s] : make_float4(0,0,0,0);
      bv1 = (col0 + r0s + 32 < N) ? *(const float4*)&Bm[(size_t)(col0 + r0s + 32)*ldb + k0 + k4s] : make_float4(0,0,0,0);
    }
    #pragma unroll
    for (int kk = 0; kk < 32; kk++) {
      float4 a4 = *(const float4*)&As[p][kk][ty*4];
      float4 b4 = *(const float4*)&Bs[p][kk][tx*4];
      float a[4] = {a4.x,a4.y,a4.z,a4.w};
      float b[4] = {b4.x,b4.y,b4.z,b4.w};
      #pragma unroll
      for (int i=0;i<4;i++)
        #pragma unroll
        for (int j=0;j<4;j++) acc[i][j] += a[i]*b[j];
    }
    if (kt + 1 < nt) {   // commit to the other buffer (read last at kt-1, safe)
      const int q = p ^ 1;
      As[q][k4s+0][r0s] = av0.x; As[q][k4s+1][r0s] = av0.y; As[q][k4s+2][r0s] = av0.z; As[q][k4s+3][r0s] = av0.w;
      As[q][k4s+0][r0s+32] = av1.x; As[q][k4s+1][r0s+32] = av1.y; As[q][k4s+2][r0s+32] = av1.z; As[q][k4s+3][r0s+32] = av1.w;
      Bs[q][k4s+0][r0s] = bv0.x; Bs[q][k4s+1][r0s] = bv0.y; Bs[q][k4s+2][r0s] = bv0.z; Bs[q][k4s+3][r0s] = bv0.w;
      Bs[q][k4s+0][r0s+32] = bv1.x; Bs[q][k4s+1][r0s+32] = bv1.y; Bs[q][k4s+2][r0s+32] = bv1.z; Bs[q][k4s+3][r0s+32] = bv1.w;
    }
    __syncthreads();
  }
  #pragma unroll
  for (int i=0;i<4;i++) {
    int r = row0 + ty*4 + i;
    #pragma unroll
    for (int j=0;j<4;j++) {
      int cc = col0 + tx*4 + j;
      if (cc < N) C[(size_t)r*ldc + cc] = acc[i][j];
    }
  }
}

// ---------------- causal depthwise conv (KS=4) + SiLU, optional f32/bf16 outs ----------------
__global__ __launch_bounds__(256) void conv_silu(const float* __restrict__ in, int ild,
    const float* __restrict__ w, float* __restrict__ outf, ushort* __restrict__ outb,
    int C, int total)
{
  int n = blockIdx.x*256 + threadIdx.x;
  if (n >= total) return;
  int c = n % C;
  int t = (n / C) % L_;
  int b = n / (C*L_);
  float acc = 0.f;
  #pragma unroll
  for (int s = 0; s < 4; s++) {
    int tt = t - 3 + s;
    if (tt >= 0) acc += in[((size_t)b*L_ + tt)*ild + c] * w[c*4+s];
  }
  float y = acc * sigmoidf_(acc);
  if (outf) outf[n] = y;
  if (outb) outb[n] = f2bf(y);
}

// ---------------- routing + beta + g ----------------
__global__ __launch_bounds__(256) void routing(const float* __restrict__ qc,
    const float* __restrict__ kvgba, const float* __restrict__ Wg3,
    const float* __restrict__ A_log, const float* __restrict__ dt_bias,
    float* __restrict__ w_buf, float* __restrict__ bt_buf, float* __restrict__ g_buf)
{
  int n = blockIdx.x*256 + threadIdx.x;
  int h  = n & 3;
  int bl = n >> 2;
  const float* q = qc + (size_t)bl*256 + h*64;
  float l0=0.f, l1=0.f, l2=0.f;
  for (int d=0; d<64; d++) {
    float qd = q[d];
    l0 += qd*Wg3[d]; l1 += qd*Wg3[64+d]; l2 += qd*Wg3[128+d];
  }
  float mx = fmaxf(l0, fmaxf(l1, l2));
  float e0 = expf(l0-mx), e1 = expf(l1-mx), e2 = expf(l2-mx);
  float inv_s = 1.f/(e0+e1+e2);
  float p0 = e0*inv_s, p1 = e1*inv_s, p2 = e2*inv_s;
  int m1 = 0; float pm1 = p0;
  if (p1 > pm1) { m1 = 1; pm1 = p1; }
  if (p2 > pm1) { m1 = 2; pm1 = p2; }
  int ia = (m1==0) ? 1 : 0;
  int ib = (m1==2) ? 1 : 2;
  float pa = (m1==0) ? p1 : p0;
  float pb = (m1==2) ? p1 : p2;
  int   m2  = (pb > pa) ? ib : ia;
  float pm2 = (pb > pa) ? pb : pa;
  float inv_w = 1.f/(pm1 + pm2);
  float w1 = 0.5f*pm1*inv_w;
  float w2 = 0.5f*pm2*inv_w;
  #pragma unroll
  for (int r = 0; r < 4; r++) {
    float wr = (r==0) ? 0.5f : (((r-1)==m1) ? w1 : (((r-1)==m2) ? w2 : 0.f));
    int he = h*4 + r;
    size_t gi = (size_t)bl*16 + he;
    w_buf[gi] = wr;
    float mask = (wr > 0.f) ? 1.f : 0.f;
    bt_buf[gi] = mask * sigmoidf_(kvgba[(size_t)bl*NCAT + 1280 + he]);
    float av = kvgba[(size_t)bl*NCAT + 1296 + he] + dt_bias[he];
    float sp = fmaxf(av, 0.f) + log1pf(expf(-fabsf(av)));
    g_buf[gi] = -expf(A_log[he]) * sp * mask;
  }
}

// ---------------- l2norm over rows of 64 (bf16 in/out) ----------------
__global__ __launch_bounds__(256) void l2norm_rows_bf(ushort* __restrict__ v, float scale)
{
  int row  = blockIdx.x*4 + (threadIdx.x >> 6);
  int lane = threadIdx.x & 63;
  size_t idx = (size_t)row*64 + lane;
  float x = bf2f(v[idx]);
  float ss = x*x;
  #pragma unroll
  for (int off = 32; off > 0; off >>= 1) ss += __shfl_xor(ss, off);
  v[idx] = f2bf(x * rsqrtf(ss + 1e-6f) * scale);
}

// ---------------- MFMA tile helper ----------------
__device__ __forceinline__ f32x4 tile64(const ushort* Am, int r0,
                                        const ushort* Bm, int c0, int lane)
{
  f32x4 acc = {0.f,0.f,0.f,0.f};
  const int fr = lane & 15, fo = (lane >> 4) << 3;
  #pragma unroll
  for (int kk = 0; kk < 2; ++kk) {
    short8 a = *reinterpret_cast<const short8*>(&Am[(r0+fr)*SPITCH + fo + kk*32]);
    short8 b = *reinterpret_cast<const short8*>(&Bm[(c0+fr)*SPITCH + fo + kk*32]);
    acc = __builtin_amdgcn_mfma_f32_16x16x32_bf16(a, b, acc, 0, 0, 0);
  }
  return acc;
}

// ---------------- pass A via WY/UT transform + MFMA ----------------
__global__ __launch_bounds__(256,2) void scan_chunk_mfma(
    const ushort* __restrict__ keb, const ushort* __restrict__ qeb,
    const float* __restrict__ vc, const float* __restrict__ bt_buf,
    const float* __restrict__ g_buf, float* __restrict__ o_r,
    float* __restrict__ Qt, float* __restrict__ Mc, float* __restrict__ Bc)
{
  __shared__ float smem[18496];                       // 73984 B
  ushort* Kbf = (ushort*)smem;                        // [64][72] bf16
  ushort* Qbf = (ushort*)(smem + 2304);               // [64][72] bf16
  ushort* KTD = (ushort*)(smem + 4608);               // [64][72] bf16 (K^T, D-scaled)
  float*  Af  = smem + 6912;                          // [64][68] f32 (A matrix)
  ushort* Pf  = (ushort*)(smem + 6912);               // overlay after substitution
  ushort* UV  = (ushort*)(smem + 11264);              // Vbf [64][128] then Ut [192][72]
  float*  cgs = smem + 18176;
  float*  bts = cgs + 64;
  float*  bGs = bts + 64;
  float*  Ds  = bGs + 64;
  float*  gams= Ds + 64;

  const int c  = blockIdx.x;
  const int he = blockIdx.y;
  const int b  = blockIdx.z;
  const int bhe = b*HE_ + he;
  const int h = he >> 2;
  const int tid = threadIdx.x;
  const int wave = tid >> 6, lane = tid & 63;
  const size_t l0 = (size_t)b*L_ + (size_t)c*T_;

  // ---- ph0a: global loads to regs + g-scan (wave 0) ----
  const int tr = tid >> 2;      // row 0..63
  const int sg = tid & 3;       // quarter
  uint32_t kwv[8], qwv[8];
  float4 vreg[8];
  {
    const uint4* kp = (const uint4*)(keb + (l0+tr)*1024 + he*64 + sg*16);
    const uint4* qp = (const uint4*)(qeb + (l0+tr)*1024 + he*64 + sg*16);
    uint4 k0 = kp[0], k1 = kp[1], q0 = qp[0], q1 = qp[1];
    kwv[0]=k0.x; kwv[1]=k0.y; kwv[2]=k0.z; kwv[3]=k0.w;
    kwv[4]=k1.x; kwv[5]=k1.y; kwv[6]=k1.z; kwv[7]=k1.w;
    qwv[0]=q0.x; qwv[1]=q0.y; qwv[2]=q0.z; qwv[3]=q0.w;
    qwv[4]=q1.x; qwv[5]=q1.y; qwv[6]=q1.z; qwv[7]=q1.w;
    const float4* vp = (const float4*)&vc[(l0+tr)*(H_*DV_) + h*DV_ + sg*32];
    #pragma unroll
    for (int i=0;i<8;i++) vreg[i] = vp[i];
  }
  if (tid < 64) {
    float g  = g_buf[(l0+tid)*HE_ + he];
    float bt = bt_buf[(l0+tid)*HE_ + he];
    float cg = g;
    #pragma unroll
    for (int off = 1; off < 64; off <<= 1) {
      float o = __shfl_up(cg, off);
      if (tid >= off) cg += o;
    }
    float cg63 = __shfl(cg, 63);
    cgs[tid] = cg; bts[tid] = bt;
    float gm = expf(cg);
    gams[tid] = gm; bGs[tid] = bt*gm; Ds[tid] = expf(cg63 - cg);
  }
  __syncthreads();
  // ---- ph0b: LDS stores ----
  {
    float Dt = Ds[tr];
    uint2* kdst = (uint2*)(Kbf + tr*SPITCH + sg*16);
    uint2* qdst = (uint2*)(Qbf + tr*SPITCH + sg*16);
    #pragma unroll
    for (int i=0;i<4;i++){
      kdst[i] = make_uint2(kwv[2*i], kwv[2*i+1]);
      qdst[i] = make_uint2(qwv[2*i], qwv[2*i+1]);
    }
    #pragma unroll
    for (int i=0;i<8;i++){
      ushort lo = (ushort)(kwv[i] & 0xffff), hi = (ushort)(kwv[i] >> 16);
      int d = sg*16 + 2*i;
      KTD[(d+0)*SPITCH + tr] = f2bf(bf2f(lo)*Dt);
      KTD[(d+1)*SPITCH + tr] = f2bf(bf2f(hi)*Dt);
    }
    ushort* Vb = UV;
    #pragma unroll
    for (int i=0;i<8;i++){
      float vv[4] = {vreg[i].x,vreg[i].y,vreg[i].z,vreg[i].w};
      #pragma unroll
      for (int j=0;j<4;j++)
        Vb[tr*128 + sg*32 + i*4 + j] = f2bf(vv[j]);
    }
  }
  __syncthreads();
  // ---- ph1: CK = K.K^T -> A (scaled, strictly lower, zero elsewhere) ----
  {
    const int r0 = wave*16;
    #pragma unroll
    for (int ct=0; ct<4; ++ct) {
      f32x4 acc = tile64(Kbf, r0, Kbf, ct*16, lane);
      int t = r0 + ((lane>>4)<<2);
      int s = ct*16 + (lane&15);
      #pragma unroll
      for (int q=0;q<4;q++){
        int tq = t + q;
        Af[tq*APITCH + s] = (s < tq) ? bts[tq]*expf(cgs[tq]-cgs[s])*acc[q] : 0.f;
      }
    }
  }
  __syncthreads();
  // ---- ph2: forward substitution u = (I+A)^-1 [beta*V | betaGamma*K] ----
  float u[64];
  if (tid < 192) {
    if (tid < 128) {
      const ushort* Vb = UV;
      #pragma unroll
      for (int s=0;s<64;++s) u[s] = bts[s]*bf2f(Vb[s*128 + tid]);
    } else {
      #pragma unroll
      for (int s=0;s<64;++s) u[s] = bGs[s]*bf2f(Kbf[s*SPITCH + (tid-128)]);
    }
  }
  __syncthreads();
  if (tid < 192) {
    #pragma unroll
    for (int t=1;t<64;++t) {
      const float4* Ar = (const float4*)(Af + t*APITCH);
      float p0=0.f,p1=0.f,p2=0.f,p3=0.f;
      #pragma unroll
      for (int s4=0; s4*4<t; ++s4) {
        float4 a = Ar[s4];
        p0 += a.x*u[s4*4+0]; p1 += a.y*u[s4*4+1];
        p2 += a.z*u[s4*4+2]; p3 += a.w*u[s4*4+3];
      }
      u[t] -= (p0+p1)+(p2+p3);
    }
    ushort* Ut = UV;
    uint4* dst = (uint4*)&Ut[tid*SPITCH];
    #pragma unroll
    for (int i=0;i<8;++i) {
      uint32_t w0 = ((uint32_t)f2bf(u[8*i+1])<<16) | f2bf(u[8*i+0]);
      uint32_t w1 = ((uint32_t)f2bf(u[8*i+3])<<16) | f2bf(u[8*i+2]);
      uint32_t w2 = ((uint32_t)f2bf(u[8*i+5])<<16) | f2bf(u[8*i+4]);
      uint32_t w3 = ((uint32_t)f2bf(u[8*i+7])<<16) | f2bf(u[8*i+6]);
      dst[i] = make_uint4(w0,w1,w2,w3);
    }
  }
  __syncthreads();
  // ---- ph3: CQ = Q.K^T -> P (scaled, lower incl diag), overlays A ----
  {
    const int r0 = wave*16;
    f32x4 accs[4];
    #pragma unroll
    for (int ct=0; ct<4; ++ct) accs[ct] = tile64(Qbf, r0, Kbf, ct*16, lane);
    __syncthreads();
    #pragma unroll
    for (int ct=0; ct<4; ++ct) {
      int t = r0 + ((lane>>4)<<2);
      int s = ct*16 + (lane&15);
      #pragma unroll
      for (int q=0;q<4;q++){
        int tq = t + q;
        float val = (s <= tq) ? expf(cgs[tq]-cgs[s])*accs[ct][q] : 0.f;
        Pf[tq*SPITCH + s] = f2bf(val);
      }
    }
  }
  __syncthreads();
  // ---- ph4: output GEMMs ----
  {
    const int r0 = wave*16;
    const float gend = expf(cgs[63]);
    const ushort* Ut = UV;
    const ushort* UtK = UV + 128*SPITCH;
    const size_t bb = ((size_t)bhe*NC_ + c)*(size_t)(64*128);
    const size_t pb = ((size_t)bhe*NC_ + c)*(size_t)QMSZ;
    #pragma unroll
    for (int jt=0; jt<8; ++jt) {
      f32x4 acc = tile64(Pf, r0, Ut, jt*16, lane);
      int t = r0 + ((lane>>4)<<2);
      int j = jt*16 + (lane&15);
      #pragma unroll
      for (int q=0;q<4;q++)
        o_r[((l0 + t + q)*HE_ + he)*DV_ + j] = acc[q];
    }
    #pragma unroll
    for (int jt=0; jt<8; ++jt) {
      f32x4 acc = tile64(KTD, r0, Ut, jt*16, lane);
      int i = r0 + ((lane>>4)<<2);
      int j = jt*16 + (lane&15);
      #pragma unroll
      for (int q=0;q<4;q++)
        Bc[bb + (size_t)(i+q)*128 + j] = acc[q];
    }
    #pragma unroll
    for (int ct=0; ct<4; ++ct) {
      f32x4 acc = tile64(KTD, r0, UtK, ct*16, lane);
      int i = r0 + ((lane>>4)<<2);
      int m = ct*16 + (lane&15);
      #pragma unroll
      for (int q=0;q<4;q++){
        float val = -acc[q];
        if (i + q == m) val += gend;
        Mc[pb + (size_t)m*QMP + (i+q)] = val;      // pitch-65 rows
      }
    }
    #pragma unroll
    for (int ct=0; ct<4; ++ct) {
      f32x4 acc = tile64(Pf, r0, UtK, ct*16, lane);
      int t = r0 + ((lane>>4)<<2);
      int m = ct*16 + (lane&15);
      #pragma unroll
      for (int q=0;q<4;q++)
        Qt[pb + (size_t)(t+q)*QMP + m] = gams[t+q]*bf2f(Qbf[(t+q)*SPITCH + m]) - acc[q];  // pitch-65
    }
  }
}

// ---------------- fused pass B+C: sequential compose + output correction ----------------
// grid (32 bhe, 8 slices): linear id = bhe + 32*slice -> id%8 = bhe%8 ->
// all 8 slices of one bhe land on the SAME XCD (L2-local Mc/Qt reuse).
__global__ __launch_bounds__(256) void compose_correct(
    const float* __restrict__ Mc, const float* __restrict__ Bc,
    const float* __restrict__ Qt, float* __restrict__ o_r)
{
  __shared__ float Ql[2][4352];   // staged Qt chunk (valid 4160) + slack
  __shared__ float Ml[2][4352];   // staged Mc chunk
  __shared__ float SSl[1024];     // running state slice [64][16]
  const int bhe = blockIdx.x;
  const int j0  = blockIdx.y * 16;
  const int b = bhe >> 4, he = bhe & 15;
  const int tid = threadIdx.x;
  const int wave = tid >> 6, lane = tid & 63;
  const int rw = tid >> 2;        // row 0..63
  const int jg = tid & 3;         // j quad within slice

  for (int id = tid; id < 1024; id += 256) SSl[id] = 0.f;

  // prologue: stage M_0, load B_0
  {
    const float* src = Mc + (size_t)(bhe*NC_)*QMSZ;
    #pragma unroll
    for (int pass = 0; pass < 4; ++pass){
      int cb = pass*256 + wave*64;
      __builtin_amdgcn_global_load_lds(
        (const __attribute__((address_space(1))) void*)(src + (size_t)(cb+lane)*4),
        (__attribute__((address_space(3))) void*)(Ml[0] + cb*4), 16, 0, 0);
    }
    if (wave == 0)
      __builtin_amdgcn_global_load_lds(
        (const __attribute__((address_space(1))) void*)(src + (size_t)(1024+lane)*4),
        (__attribute__((address_space(3))) void*)(Ml[0] + 4096), 16, 0, 0);
  }
  float4 bcur = *(const float4*)&Bc[(size_t)(bhe*NC_)*8192 + rw*128 + j0 + jg*4];
  __syncthreads();

  int p = 0;
  for (int c = 0; c < NC_; ++c){
    float4 bnext = make_float4(0.f,0.f,0.f,0.f);
    if (c+1 < NC_){
      // stage Qt_{c+1}
      const float* qsrc = Qt + (size_t)(bhe*NC_ + c + 1)*QMSZ;
      #pragma unroll
      for (int pass = 0; pass < 4; ++pass){
        int cb = pass*256 + wave*64;
        __builtin_amdgcn_global_load_lds(
          (const __attribute__((address_space(1))) void*)(qsrc + (size_t)(cb+lane)*4),
          (__attribute__((address_space(3))) void*)(Ql[p^1] + cb*4), 16, 0, 0);
      }
      if (wave == 0)
        __builtin_amdgcn_global_load_lds(
          (const __attribute__((address_space(1))) void*)(qsrc + (size_t)(1024+lane)*4),
          (__attribute__((address_space(3))) void*)(Ql[p^1] + 4096), 16, 0, 0);
      if (c+1 < NC_-1){
        // stage Mc_{c+1}
        const float* msrc = Mc + (size_t)(bhe*NC_ + c + 1)*QMSZ;
        #pragma unroll
        for (int pass = 0; pass < 4; ++pass){
          int cb = pass*256 + wave*64;
          __builtin_amdgcn_global_load_lds(
            (const __attribute__((address_space(1))) void*)(msrc + (size_t)(cb+lane)*4),
            (__attribute__((address_space(3))) void*)(Ml[p^1] + cb*4), 16, 0, 0);
        }
        if (wave == 0)
          __builtin_amdgcn_global_load_lds(
            (const __attribute__((address_space(1))) void*)(msrc + (size_t)(1024+lane)*4),
            (__attribute__((address_space(3))) void*)(Ml[p^1] + 4096), 16, 0, 0);
        bnext = *(const float4*)&Bc[(size_t)(bhe*NC_ + c + 1)*8192 + rw*128 + j0 + jg*4];
      }
    }
    const float4* SS4 = (const float4*)SSl;
    // correction: o_r[c] += Qt_c^T-contracted state (skip c=0, SS=0)
    if (c > 0){
      float4 oa = make_float4(0.f,0.f,0.f,0.f);
      const float* Qr = Ql[p] + rw*QMP;
      #pragma unroll 8
      for (int m = 0; m < 64; ++m){
        float qv = Qr[m];
        float4 s = SS4[m*4 + jg];
        oa.x += qv*s.x; oa.y += qv*s.y; oa.z += qv*s.z; oa.w += qv*s.w;
      }
      size_t oi = (((size_t)b*L_ + c*T_ + rw)*HE_ + he)*DV_ + j0 + jg*4;
      float4 o = *(float4*)&o_r[oi];
      o.x += oa.x; o.y += oa.y; o.z += oa.z; o.w += oa.w;
      *(float4*)&o_r[oi] = o;
    }
    // update: SS <- Mc_c . SS + B_c (skip at last chunk)
    float4 ns = bcur;
    if (c < NC_-1){
      const float* Mlp = Ml[p];
      #pragma unroll 8
      for (int m = 0; m < 64; ++m){
        float mv = Mlp[m*QMP + rw];
        float4 s = SS4[m*4 + jg];
        ns.x += mv*s.x; ns.y += mv*s.y; ns.z += mv*s.z; ns.w += mv*s.w;
      }
    }
    __syncthreads();
    if (c < NC_-1) *(float4*)&SSl[rw*16 + jg*4] = ns;
    __syncthreads();     // SS visible + staged c+1 drained (vmcnt before barrier)
    p ^= 1;
    bcur = bnext;
  }
}

// ---------------- expert combine + RMSNorm*SiLU(gate) -> bf16 ----------------
__global__ __launch_bounds__(128) void combine(const float* __restrict__ o_r,
    const float* __restrict__ w_buf, const float* __restrict__ kvgba,
    const float* __restrict__ norm_w, ushort* __restrict__ o_fin)
{
  int n  = blockIdx.x;
  int h  = n & 3;
  int bl = n >> 2;
  int j  = threadIdx.x;
  size_t wb = (size_t)bl*16 + h*4;
  size_t ob = wb*128 + j;
  float oc = 0.f;
  #pragma unroll
  for (int r = 0; r < 4; r++) oc += w_buf[wb+r] * o_r[ob + (size_t)r*128];
  float ss = oc*oc;
  #pragma unroll
  for (int off = 32; off > 0; off >>= 1) ss += __shfl_xor(ss, off);
  __shared__ float red[2];
  if ((threadIdx.x & 63) == 0) red[threadIdx.x >> 6] = ss;
  __syncthreads();
  float mean = (red[0] + red[1]) * (1.f/128.f);
  float sc = rsqrtf(mean + 1e-5f);
  float gv = kvgba[(size_t)bl*NCAT + 768 + h*128 + j];
  o_fin[(size_t)bl*512 + h*128 + j] = f2bf(oc * sc * norm_w[j] * (gv * sigmoidf_(gv)));
}

extern "C" void kernel_launch(void* const* d_in, const int* in_sizes, int n_in,
                              void* d_out, int out_size, void* d_ws, size_t ws_size,
                              hipStream_t stream)
{
  (void)in_sizes; (void)n_in; (void)out_size; (void)ws_size;
  const float* x       = (const float*)d_in[0];
  const float* Wq      = (const float*)d_in[1];
  const float* Wk      = (const float*)d_in[2];
  const float* Wv      = (const float*)d_in[3];
  const float* Wb      = (const float*)d_in[4];
  const float* Wa      = (const float*)d_in[5];
  const float* Wg      = (const float*)d_in[6];
  const float* Wo      = (const float*)d_in[7];
  const float* conv_q  = (const float*)d_in[8];
  const float* conv_k  = (const float*)d_in[9];
  const float* conv_v  = (const float*)d_in[10];
  const float* Wq_exp  = (const float*)d_in[11];
  const float* Wk_exp  = (const float*)d_in[12];
  const float* W_gate  = (const float*)d_in[13];
  const float* A_log   = (const float*)d_in[14];
  const float* dt_bias = (const float*)d_in[15];
  const float* norm_w  = (const float*)d_in[16];
  float* out = (float*)d_out;

  const size_t BL = (size_t)B_*L_;   // 4096
  float* p = (float*)d_ws;
  float* q_lin  = p; p += BL*256;
  float* kvgba  = p; p += BL*NCAT;
  float* q_conv = p; p += BL*256;
  float* v_conv = p; p += BL*512;
  float* w_buf  = p; p += BL*16;
  float* bt_buf = p; p += BL*16;
  float* g_buf  = p; p += BL*16;
  float* Mc     = p; p += (size_t)B_*HE_*NC_*QMSZ + 1024;   // pitch-65 rows + stage slack
  float* Bc     = p; p += (size_t)B_*HE_*NC_*64*128;
  float* Qt     = p; p += (size_t)B_*HE_*NC_*QMSZ + 1024;
  float* o_r    = p; p += BL*16*128;
  ushort* xb    = (ushort*)p; p += BL*512;        // x bf16
  ushort* Wcat  = (ushort*)p; p += (NCAT*1024)/2; // concat weights bf16
  ushort* qc_bf = (ushort*)p; p += BL*128;        // q_conv bf16
  ushort* kc_bf = (ushort*)p; p += BL*128;        // k_conv bf16
  ushort* qeb   = (ushort*)p; p += BL*512;        // qe bf16 [4096][1024]
  ushort* keb   = (ushort*)p; p += BL*512;        // ke bf16
  ushort* Wqeb  = (ushort*)p; p += 32768;
  ushort* Wkeb  = (ushort*)p; p += 32768;
  ushort* Wob   = (ushort*)p; p += 262144;        // 1024*512 bf16
  ushort* o_finb= (ushort*)p; p += BL*256;        // bf16 [4096][512]

  // weight prep
  concat_wcat<<<dim3((NCAT*1024+255)/256), dim3(256), 0, stream>>>(Wk, Wv, Wg, Wb, Wa, Wcat);
  { int n = (int)(BL*1024); cast_bf16<<<dim3((n+255)/256), dim3(256), 0, stream>>>(x, xb, n); }
  { int n = 65536;  cast_bf16<<<dim3((n+255)/256), dim3(256), 0, stream>>>(Wq_exp, Wqeb, n); }
  { int n = 65536;  cast_bf16<<<dim3((n+255)/256), dim3(256), 0, stream>>>(Wk_exp, Wkeb, n); }
  { int n = 524288; cast_bf16<<<dim3((n+255)/256), dim3(256), 0, stream>>>(Wo, Wob, n); }

  // projections
  gemm_f32_db<<<dim3(4, 64), dim3(256), 0, stream>>>(x, 1024, Wq, 1024, q_lin, 256, 4096, 256, 1024);
  gemm_bf16<<<dim3(NCAT/128, 32), dim3(256), 0, stream>>>(xb, 1024, Wcat, 1024, kvgba, NCAT, 1024);

  // convs (+SiLU)
  { int tot = B_*L_*256; conv_silu<<<dim3((tot+255)/256), dim3(256), 0, stream>>>(q_lin, 256, conv_q, q_conv, qc_bf, 256, tot); }
  { int tot = B_*L_*256; conv_silu<<<dim3((tot+255)/256), dim3(256), 0, stream>>>(kvgba, NCAT, conv_k, (float*)nullptr, kc_bf, 256, tot); }
  { int tot = B_*L_*512; conv_silu<<<dim3((tot+255)/256), dim3(256), 0, stream>>>(kvgba + 256, NCAT, conv_v, v_conv, (ushort*)nullptr, 512, tot); }

  routing<<<dim3(64), dim3(256), 0, stream>>>(q_conv, kvgba, W_gate, A_log, dt_bias,
                                              w_buf, bt_buf, g_buf);

  gemm_expand_bf16<<<dim3(2, 32, 8), dim3(256), 0, stream>>>(qc_bf, kc_bf, Wqeb, Wkeb, qeb, keb);

  l2norm_rows_bf<<<dim3(16384), dim3(256), 0, stream>>>(qeb, 0.125f);
  l2norm_rows_bf<<<dim3(16384), dim3(256), 0, stream>>>(keb, 1.0f);

  scan_chunk_mfma<<<dim3(NC_, HE_, B_), dim3(256), 0, stream>>>(keb, qeb, v_conv, bt_buf, g_buf,
                                                                o_r, Qt, Mc, Bc);
  compose_correct<<<dim3(32, 8), dim3(256), 0, stream>>>(Mc, Bc, Qt, o_r);
  combine<<<dim3(B_*L_*H_), dim3(128), 0, stream>>>(o_r, w_buf, kvgba, norm_w, o_finb);

  gemm_bf16<<<dim3(8, 32), dim3(256), 0, stream>>>(o_finb, 512, Wob, 512, out, 1024, 512);
}

// Round 7
// 371.967 us; speedup vs baseline: 2.9496x; 1.0763x over previous
//
#include <hip/hip_runtime.h>
#include <hip/hip_bf16.h>
#include <math.h>

#define B_    2
#define L_    2048
#define HID_  1024
#define H_    4
#define DK_   64
#define RATIO_ 4
#define HE_   16
#define DV_   128
#define T_    64
#define NC_   32   // L_/T_
#define SPITCH 72  // bf16 LDS row pitch
#define APITCH 68  // f32 A-matrix LDS pitch
#define NCAT  1408 // concat projection width: k256 v512 g512 b16 a16 pad96
#define QMP   68   // Qt/McT row pitch (f32): 16B-aligned rows, LDS banks (4*rw+m)%32 <=2-way
#define QMSZ  4352 // 64*68 per chunk

typedef __attribute__((ext_vector_type(8))) short short8;
typedef __attribute__((ext_vector_type(4))) float f32x4;

__device__ __forceinline__ float sigmoidf_(float x){ return 1.f/(1.f+expf(-x)); }
__device__ __forceinline__ ushort f2bf(float x){
  __hip_bfloat16 h = __float2bfloat16(x);
  return *reinterpret_cast<ushort*>(&h);
}
__device__ __forceinline__ float bf2f(ushort u){
  union { uint32_t i; float f; } v; v.i = ((uint32_t)u) << 16; return v.f;
}

// ---------------- f32 -> bf16 cast ----------------
__global__ __launch_bounds__(256) void cast_bf16(const float* __restrict__ in,
                                                 ushort* __restrict__ out, int n)
{
  int i = blockIdx.x*256 + threadIdx.x;
  if (i < n) out[i] = f2bf(in[i]);
}

// ---------------- concat weights [k|v|g|b|a|pad] -> bf16 [1408][1024] ----------------
__global__ __launch_bounds__(256) void concat_wcat(const float* __restrict__ Wk,
    const float* __restrict__ Wv, const float* __restrict__ Wg,
    const float* __restrict__ Wb, const float* __restrict__ Wa,
    ushort* __restrict__ Wcat)
{
  int idx = blockIdx.x*256 + threadIdx.x;
  if (idx >= NCAT*1024) return;
  int r = idx >> 10, cc = idx & 1023;
  float v = 0.f;
  if      (r < 256)  v = Wk[(size_t)r*1024 + cc];
  else if (r < 768)  v = Wv[(size_t)(r-256)*1024 + cc];
  else if (r < 1280) v = Wg[(size_t)(r-768)*1024 + cc];
  else if (r < 1296) v = Wb[(size_t)(r-1280)*1024 + cc];
  else if (r < 1312) v = Wa[(size_t)(r-1296)*1024 + cc];
  Wcat[idx] = f2bf(v);
}

// ---------------- bf16 MFMA GEMM (f32 out): C = A(MxK) * B(NxK)^T ----------------
__global__ __launch_bounds__(256) void gemm_bf16(
    const ushort* __restrict__ A, int lda,
    const ushort* __restrict__ Bm, int ldb,
    float* __restrict__ C, int ldc, int K)
{
  __shared__ ushort As[128*32];
  __shared__ ushort Bs[128*32];
  const int tid  = threadIdx.x;
  const int wave = tid >> 6, lane = tid & 63;
  const int row0 = blockIdx.y*128, col0 = blockIdx.x*128;
  const int wr = (wave >> 1) * 64, wc = (wave & 1) * 64;
  const int frow = lane & 15;
  const int fko  = (lane >> 4) << 3;
  f32x4 acc[4][4];
  #pragma unroll
  for (int i=0;i<4;i++)
    #pragma unroll
    for (int j=0;j<4;j++) acc[i][j] = (f32x4){0.f,0.f,0.f,0.f};
  for (int k0 = 0; k0 < K; k0 += 32) {
    #pragma unroll
    for (int cc = 0; cc < 2; cc++) {
      int c  = wave*128 + cc*64 + lane;
      int r  = c >> 2;
      int ko = (c & 3) << 3;
      __builtin_amdgcn_global_load_lds(
        (const __attribute__((address_space(1))) void*)(A + (size_t)(row0+r)*lda + k0 + ko),
        (__attribute__((address_space(3))) void*)(As + (size_t)(wave*128 + cc*64)*8),
        16, 0, 0);
      __builtin_amdgcn_global_load_lds(
        (const __attribute__((address_space(1))) void*)(Bm + (size_t)(col0+r)*ldb + k0 + ko),
        (__attribute__((address_space(3))) void*)(Bs + (size_t)(wave*128 + cc*64)*8),
        16, 0, 0);
    }
    __syncthreads();
    short8 af[4], bfv[4];
    #pragma unroll
    for (int mi=0;mi<4;mi++)
      af[mi] = *reinterpret_cast<const short8*>(&As[(wr + mi*16 + frow)*32 + fko]);
    #pragma unroll
    for (int ni=0;ni<4;ni++)
      bfv[ni] = *reinterpret_cast<const short8*>(&Bs[(wc + ni*16 + frow)*32 + fko]);
    #pragma unroll
    for (int mi=0;mi<4;mi++)
      #pragma unroll
      for (int ni=0;ni<4;ni++)
        acc[mi][ni] = __builtin_amdgcn_mfma_f32_16x16x32_bf16(af[mi], bfv[ni], acc[mi][ni], 0, 0, 0);
    __syncthreads();
  }
  const int ocol = lane & 15;
  const int orow = (lane >> 4) << 2;
  #pragma unroll
  for (int mi=0;mi<4;mi++)
    #pragma unroll
    for (int ni=0;ni<4;ni++) {
      size_t base = (size_t)(row0 + wr + mi*16 + orow)*ldc + (col0 + wc + ni*16 + ocol);
      #pragma unroll
      for (int q=0;q<4;q++) C[base + (size_t)q*ldc] = acc[mi][ni][q];
    }
}

// ---------------- batched bf16 expansion GEMM (bf16 out), z = (q/k)*4 + h ----------------
__global__ __launch_bounds__(256) void gemm_expand_bf16(
    const ushort* __restrict__ qc_bf, const ushort* __restrict__ kc_bf,
    const ushort* __restrict__ Wqeb, const ushort* __restrict__ Wkeb,
    ushort* __restrict__ qeb, ushort* __restrict__ keb)
{
  const int z = blockIdx.z;
  const int hh = z & 3;
  const ushort* A  = (z < 4 ? qc_bf : kc_bf) + hh*64;      // lda 256
  const ushort* Bm = (z < 4 ? Wqeb  : Wkeb ) + (size_t)hh*16384; // ldb 64
  ushort* C        = (z < 4 ? qeb   : keb  ) + hh*256;     // ldc 1024
  const int lda = 256, ldb = 64, ldc = 1024, K = 64;
  __shared__ ushort As[128*32];
  __shared__ ushort Bs[128*32];
  const int tid  = threadIdx.x;
  const int wave = tid >> 6, lane = tid & 63;
  const int row0 = blockIdx.y*128, col0 = blockIdx.x*128;
  const int wr = (wave >> 1) * 64, wc = (wave & 1) * 64;
  const int frow = lane & 15;
  const int fko  = (lane >> 4) << 3;
  f32x4 acc[4][4];
  #pragma unroll
  for (int i=0;i<4;i++)
    #pragma unroll
    for (int j=0;j<4;j++) acc[i][j] = (f32x4){0.f,0.f,0.f,0.f};
  for (int k0 = 0; k0 < K; k0 += 32) {
    #pragma unroll
    for (int cc = 0; cc < 2; cc++) {
      int c  = wave*128 + cc*64 + lane;
      int r  = c >> 2;
      int ko = (c & 3) << 3;
      __builtin_amdgcn_global_load_lds(
        (const __attribute__((address_space(1))) void*)(A + (size_t)(row0+r)*lda + k0 + ko),
        (__attribute__((address_space(3))) void*)(As + (size_t)(wave*128 + cc*64)*8),
        16, 0, 0);
      __builtin_amdgcn_global_load_lds(
        (const __attribute__((address_space(1))) void*)(Bm + (size_t)(col0+r)*ldb + k0 + ko),
        (__attribute__((address_space(3))) void*)(Bs + (size_t)(wave*128 + cc*64)*8),
        16, 0, 0);
    }
    __syncthreads();
    short8 af[4], bfv[4];
    #pragma unroll
    for (int mi=0;mi<4;mi++)
      af[mi] = *reinterpret_cast<const short8*>(&As[(wr + mi*16 + frow)*32 + fko]);
    #pragma unroll
    for (int ni=0;ni<4;ni++)
      bfv[ni] = *reinterpret_cast<const short8*>(&Bs[(wc + ni*16 + frow)*32 + fko]);
    #pragma unroll
    for (int mi=0;mi<4;mi++)
      #pragma unroll
      for (int ni=0;ni<4;ni++)
        acc[mi][ni] = __builtin_amdgcn_mfma_f32_16x16x32_bf16(af[mi], bfv[ni], acc[mi][ni], 0, 0, 0);
    __syncthreads();
  }
  const int ocol = lane & 15;
  const int orow = (lane >> 4) << 2;
  #pragma unroll
  for (int mi=0;mi<4;mi++)
    #pragma unroll
    for (int ni=0;ni<4;ni++) {
      size_t base = (size_t)(row0 + wr + mi*16 + orow)*ldc + (col0 + wc + ni*16 + ocol);
      #pragma unroll
      for (int q=0;q<4;q++) C[base + (size_t)q*ldc] = f2bf(acc[mi][ni][q]);
    }
}

// ---------------- f32 GEMM with double-buffered LDS (Wq): C = A*B^T ----------------
__global__ __launch_bounds__(256) void gemm_f32_db(const float* __restrict__ A, int lda,
    const float* __restrict__ Bm, int ldb, float* __restrict__ C, int ldc,
    int M, int N, int K)
{
  __shared__ float As[2][32][64];
  __shared__ float Bs[2][32][64];
  const int tid = threadIdx.x;
  const int row0 = blockIdx.y * 64;
  const int col0 = blockIdx.x * 64;
  const int tx = tid & 15, ty = tid >> 4;
  const int r0s = tid >> 3;
  const int k4s = (tid & 7) << 2;
  float4 av0, av1, bv0, bv1;

  av0 = *(const float4*)&A[(size_t)(row0 + r0s)*lda + k4s];
  av1 = *(const float4*)&A[(size_t)(row0 + r0s + 32)*lda + k4s];
  bv0 = (col0 + r0s < N) ? *(const float4*)&Bm[(size_t)(col0 + r0s)*ldb + k4s] : make_float4(0,0,0,0);
  bv1 = (col0 + r0s + 32 < N) ? *(const float4*)&Bm[(size_t)(col0 + r0s + 32)*ldb + k4s] : make_float4(0,0,0,0);
  As[0][k4s+0][r0s] = av0.x; As[0][k4s+1][r0s] = av0.y; As[0][k4s+2][r0s] = av0.z; As[0][k4s+3][r0s] = av0.w;
  As[0][k4s+0][r0s+32] = av1.x; As[0][k4s+1][r0s+32] = av1.y; As[0][k4s+2][r0s+32] = av1.z; As[0][k4s+3][r0s+32] = av1.w;
  Bs[0][k4s+0][r0s] = bv0.x; Bs[0][k4s+1][r0s] = bv0.y; Bs[0][k4s+2][r0s] = bv0.z; Bs[0][k4s+3][r0s] = bv0.w;
  Bs[0][k4s+0][r0s+32] = bv1.x; Bs[0][k4s+1][r0s+32] = bv1.y; Bs[0][k4s+2][r0s+32] = bv1.z; Bs[0][k4s+3][r0s+32] = bv1.w;
  __syncthreads();

  float acc[4][4] = {};
  const int nt = K >> 5;
  for (int kt = 0; kt < nt; ++kt) {
    const int p = kt & 1;
    if (kt + 1 < nt) {
      int k0 = (kt+1) << 5;
      av0 = *(const float4*)&A[(size_t)(row0 + r0s)*lda + k0 + k4s];
      av1 = *(const float4*)&A[(size_t)(row0 + r0s + 32)*lda + k0 + k4s];
      bv0 = (col0 + r0s < N) ? *(const float4*)&Bm[(size_t)(col0 + r0s)*ldb + k0 + k4s] : make_float4(0,0,0,0);
      bv1 = (col0 + r0s + 32 < N) ? *(const float4*)&Bm[(size_t)(col0 + r0s + 32)*ldb + k0 + k4s] : make_float4(0,0,0,0);
    }
    #pragma unroll
    for (int kk = 0; kk < 32; kk++) {
      float4 a4 = *(const float4*)&As[p][kk][ty*4];
      float4 b4 = *(const float4*)&Bs[p][kk][tx*4];
      float a[4] = {a4.x,a4.y,a4.z,a4.w};
      float b[4] = {b4.x,b4.y,b4.z,b4.w};
      #pragma unroll
      for (int i=0;i<4;i++)
        #pragma unroll
        for (int j=0;j<4;j++) acc[i][j] += a[i]*b[j];
    }
    if (kt + 1 < nt) {
      const int q = p ^ 1;
      As[q][k4s+0][r0s] = av0.x; As[q][k4s+1][r0s] = av0.y; As[q][k4s+2][r0s] = av0.z; As[q][k4s+3][r0s] = av0.w;
      As[q][k4s+0][r0s+32] = av1.x; As[q][k4s+1][r0s+32] = av1.y; As[q][k4s+2][r0s+32] = av1.z; As[q][k4s+3][r0s+32] = av1.w;
      Bs[q][k4s+0][r0s] = bv0.x; Bs[q][k4s+1][r0s] = bv0.y; Bs[q][k4s+2][r0s] = bv0.z; Bs[q][k4s+3][r0s] = bv0.w;
      Bs[q][k4s+0][r0s+32] = bv1.x; Bs[q][k4s+1][r0s+32] = bv1.y; Bs[q][k4s+2][r0s+32] = bv1.z; Bs[q][k4s+3][r0s+32] = bv1.w;
    }
    __syncthreads();
  }
  #pragma unroll
  for (int i=0;i<4;i++) {
    int r = row0 + ty*4 + i;
    #pragma unroll
    for (int j=0;j<4;j++) {
      int cc = col0 + tx*4 + j;
      if (cc < N) C[(size_t)r*ldc + cc] = acc[i][j];
    }
  }
}

// ---------------- causal depthwise conv (KS=4) + SiLU, optional f32/bf16 outs ----------------
__global__ __launch_bounds__(256) void conv_silu(const float* __restrict__ in, int ild,
    const float* __restrict__ w, float* __restrict__ outf, ushort* __restrict__ outb,
    int C, int total)
{
  int n = blockIdx.x*256 + threadIdx.x;
  if (n >= total) return;
  int c = n % C;
  int t = (n / C) % L_;
  int b = n / (C*L_);
  float acc = 0.f;
  #pragma unroll
  for (int s = 0; s < 4; s++) {
    int tt = t - 3 + s;
    if (tt >= 0) acc += in[((size_t)b*L_ + tt)*ild + c] * w[c*4+s];
  }
  float y = acc * sigmoidf_(acc);
  if (outf) outf[n] = y;
  if (outb) outb[n] = f2bf(y);
}

// ---------------- routing + beta + g ----------------
__global__ __launch_bounds__(256) void routing(const float* __restrict__ qc,
    const float* __restrict__ kvgba, const float* __restrict__ Wg3,
    const float* __restrict__ A_log, const float* __restrict__ dt_bias,
    float* __restrict__ w_buf, float* __restrict__ bt_buf, float* __restrict__ g_buf)
{
  int n = blockIdx.x*256 + threadIdx.x;
  int h  = n & 3;
  int bl = n >> 2;
  const float* q = qc + (size_t)bl*256 + h*64;
  float l0=0.f, l1=0.f, l2=0.f;
  for (int d=0; d<64; d++) {
    float qd = q[d];
    l0 += qd*Wg3[d]; l1 += qd*Wg3[64+d]; l2 += qd*Wg3[128+d];
  }
  float mx = fmaxf(l0, fmaxf(l1, l2));
  float e0 = expf(l0-mx), e1 = expf(l1-mx), e2 = expf(l2-mx);
  float inv_s = 1.f/(e0+e1+e2);
  float p0 = e0*inv_s, p1 = e1*inv_s, p2 = e2*inv_s;
  int m1 = 0; float pm1 = p0;
  if (p1 > pm1) { m1 = 1; pm1 = p1; }
  if (p2 > pm1) { m1 = 2; pm1 = p2; }
  int ia = (m1==0) ? 1 : 0;
  int ib = (m1==2) ? 1 : 2;
  float pa = (m1==0) ? p1 : p0;
  float pb = (m1==2) ? p1 : p2;
  int   m2  = (pb > pa) ? ib : ia;
  float pm2 = (pb > pa) ? pb : pa;
  float inv_w = 1.f/(pm1 + pm2);
  float w1 = 0.5f*pm1*inv_w;
  float w2 = 0.5f*pm2*inv_w;
  #pragma unroll
  for (int r = 0; r < 4; r++) {
    float wr = (r==0) ? 0.5f : (((r-1)==m1) ? w1 : (((r-1)==m2) ? w2 : 0.f));
    int he = h*4 + r;
    size_t gi = (size_t)bl*16 + he;
    w_buf[gi] = wr;
    float mask = (wr > 0.f) ? 1.f : 0.f;
    bt_buf[gi] = mask * sigmoidf_(kvgba[(size_t)bl*NCAT + 1280 + he]);
    float av = kvgba[(size_t)bl*NCAT + 1296 + he] + dt_bias[he];
    float sp = fmaxf(av, 0.f) + log1pf(expf(-fabsf(av)));
    g_buf[gi] = -expf(A_log[he]) * sp * mask;
  }
}

// ---------------- l2norm over rows of 64 (bf16 in/out) ----------------
__global__ __launch_bounds__(256) void l2norm_rows_bf(ushort* __restrict__ v, float scale)
{
  int row  = blockIdx.x*4 + (threadIdx.x >> 6);
  int lane = threadIdx.x & 63;
  size_t idx = (size_t)row*64 + lane;
  float x = bf2f(v[idx]);
  float ss = x*x;
  #pragma unroll
  for (int off = 32; off > 0; off >>= 1) ss += __shfl_xor(ss, off);
  v[idx] = f2bf(x * rsqrtf(ss + 1e-6f) * scale);
}

// ---------------- MFMA tile helper ----------------
__device__ __forceinline__ f32x4 tile64(const ushort* Am, int r0,
                                        const ushort* Bm, int c0, int lane)
{
  f32x4 acc = {0.f,0.f,0.f,0.f};
  const int fr = lane & 15, fo = (lane >> 4) << 3;
  #pragma unroll
  for (int kk = 0; kk < 2; ++kk) {
    short8 a = *reinterpret_cast<const short8*>(&Am[(r0+fr)*SPITCH + fo + kk*32]);
    short8 b = *reinterpret_cast<const short8*>(&Bm[(c0+fr)*SPITCH + fo + kk*32]);
    acc = __builtin_amdgcn_mfma_f32_16x16x32_bf16(a, b, acc, 0, 0, 0);
  }
  return acc;
}

// ---------------- pass A via WY/UT transform + MFMA ----------------
// 1D grid, id = c*32 + bhe -> id%8 = bhe%8: all chunks of a bhe on ONE XCD
// (matches compose_correct's block (bhe, slice) -> L2-local Mc/Qt/Bc).
__global__ __launch_bounds__(256,2) void scan_chunk_mfma(
    const ushort* __restrict__ keb, const ushort* __restrict__ qeb,
    const float* __restrict__ vc, const float* __restrict__ bt_buf,
    const float* __restrict__ g_buf, float* __restrict__ o_r,
    float* __restrict__ Qt, float* __restrict__ Mc, float* __restrict__ Bc)
{
  __shared__ float smem[18496];                       // 73984 B
  ushort* Kbf = (ushort*)smem;                        // [64][72] bf16
  ushort* Qbf = (ushort*)(smem + 2304);               // [64][72] bf16
  ushort* KTD = (ushort*)(smem + 4608);               // [64][72] bf16 (K^T, D-scaled)
  float*  Af  = smem + 6912;                          // [64][68] f32 (A matrix)
  ushort* Pf  = (ushort*)(smem + 6912);               // overlay after substitution
  ushort* UV  = (ushort*)(smem + 11264);              // Vbf [64][128] then Ut [192][72]
  float*  cgs = smem + 18176;
  float*  bts = cgs + 64;
  float*  bGs = bts + 64;
  float*  Ds  = bGs + 64;
  float*  gams= Ds + 64;

  const int id = blockIdx.x;
  const int c   = id >> 5;
  const int bhe = id & 31;
  const int b  = bhe >> 4;
  const int he = bhe & 15;
  const int h = he >> 2;
  const int tid = threadIdx.x;
  const int wave = tid >> 6, lane = tid & 63;
  const size_t l0 = (size_t)b*L_ + (size_t)c*T_;

  // ---- ph0a: global loads to regs + g-scan (wave 0) ----
  const int tr = tid >> 2;      // row 0..63
  const int sg = tid & 3;       // quarter
  uint32_t kwv[8], qwv[8];
  float4 vreg[8];
  {
    const uint4* kp = (const uint4*)(keb + (l0+tr)*1024 + he*64 + sg*16);
    const uint4* qp = (const uint4*)(qeb + (l0+tr)*1024 + he*64 + sg*16);
    uint4 k0 = kp[0], k1 = kp[1], q0 = qp[0], q1 = qp[1];
    kwv[0]=k0.x; kwv[1]=k0.y; kwv[2]=k0.z; kwv[3]=k0.w;
    kwv[4]=k1.x; kwv[5]=k1.y; kwv[6]=k1.z; kwv[7]=k1.w;
    qwv[0]=q0.x; qwv[1]=q0.y; qwv[2]=q0.z; qwv[3]=q0.w;
    qwv[4]=q1.x; qwv[5]=q1.y; qwv[6]=q1.z; qwv[7]=q1.w;
    const float4* vp = (const float4*)&vc[(l0+tr)*(H_*DV_) + h*DV_ + sg*32];
    #pragma unroll
    for (int i=0;i<8;i++) vreg[i] = vp[i];
  }
  if (tid < 64) {
    float g  = g_buf[(l0+tid)*HE_ + he];
    float bt = bt_buf[(l0+tid)*HE_ + he];
    float cg = g;
    #pragma unroll
    for (int off = 1; off < 64; off <<= 1) {
      float o = __shfl_up(cg, off);
      if (tid >= off) cg += o;
    }
    float cg63 = __shfl(cg, 63);
    cgs[tid] = cg; bts[tid] = bt;
    float gm = expf(cg);
    gams[tid] = gm; bGs[tid] = bt*gm; Ds[tid] = expf(cg63 - cg);
  }
  __syncthreads();
  // ---- ph0b: LDS stores ----
  {
    float Dt = Ds[tr];
    uint2* kdst = (uint2*)(Kbf + tr*SPITCH + sg*16);
    uint2* qdst = (uint2*)(Qbf + tr*SPITCH + sg*16);
    #pragma unroll
    for (int i=0;i<4;i++){
      kdst[i] = make_uint2(kwv[2*i], kwv[2*i+1]);
      qdst[i] = make_uint2(qwv[2*i], qwv[2*i+1]);
    }
    #pragma unroll
    for (int i=0;i<8;i++){
      ushort lo = (ushort)(kwv[i] & 0xffff), hi = (ushort)(kwv[i] >> 16);
      int d = sg*16 + 2*i;
      KTD[(d+0)*SPITCH + tr] = f2bf(bf2f(lo)*Dt);
      KTD[(d+1)*SPITCH + tr] = f2bf(bf2f(hi)*Dt);
    }
    ushort* Vb = UV;
    #pragma unroll
    for (int i=0;i<8;i++){
      float vv[4] = {vreg[i].x,vreg[i].y,vreg[i].z,vreg[i].w};
      #pragma unroll
      for (int j=0;j<4;j++)
        Vb[tr*128 + sg*32 + i*4 + j] = f2bf(vv[j]);
    }
  }
  __syncthreads();
  // ---- ph1: CK = K.K^T -> A (scaled, strictly lower, zero elsewhere) ----
  {
    const int r0 = wave*16;
    #pragma unroll
    for (int ct=0; ct<4; ++ct) {
      f32x4 acc = tile64(Kbf, r0, Kbf, ct*16, lane);
      int t = r0 + ((lane>>4)<<2);
      int s = ct*16 + (lane&15);
      #pragma unroll
      for (int q=0;q<4;q++){
        int tq = t + q;
        Af[tq*APITCH + s] = (s < tq) ? bts[tq]*expf(cgs[tq]-cgs[s])*acc[q] : 0.f;
      }
    }
  }
  __syncthreads();
  // ---- ph2: forward substitution u = (I+A)^-1 [beta*V | betaGamma*K] ----
  float u[64];
  if (tid < 192) {
    if (tid < 128) {
      const ushort* Vb = UV;
      #pragma unroll
      for (int s=0;s<64;++s) u[s] = bts[s]*bf2f(Vb[s*128 + tid]);
    } else {
      #pragma unroll
      for (int s=0;s<64;++s) u[s] = bGs[s]*bf2f(Kbf[s*SPITCH + (tid-128)]);
    }
  }
  __syncthreads();
  if (tid < 192) {
    #pragma unroll
    for (int t=1;t<64;++t) {
      const float4* Ar = (const float4*)(Af + t*APITCH);
      float p0=0.f,p1=0.f,p2=0.f,p3=0.f;
      #pragma unroll
      for (int s4=0; s4*4<t; ++s4) {
        float4 a = Ar[s4];
        p0 += a.x*u[s4*4+0]; p1 += a.y*u[s4*4+1];
        p2 += a.z*u[s4*4+2]; p3 += a.w*u[s4*4+3];
      }
      u[t] -= (p0+p1)+(p2+p3);
    }
    ushort* Ut = UV;
    uint4* dst = (uint4*)&Ut[tid*SPITCH];
    #pragma unroll
    for (int i=0;i<8;++i) {
      uint32_t w0 = ((uint32_t)f2bf(u[8*i+1])<<16) | f2bf(u[8*i+0]);
      uint32_t w1 = ((uint32_t)f2bf(u[8*i+3])<<16) | f2bf(u[8*i+2]);
      uint32_t w2 = ((uint32_t)f2bf(u[8*i+5])<<16) | f2bf(u[8*i+4]);
      uint32_t w3 = ((uint32_t)f2bf(u[8*i+7])<<16) | f2bf(u[8*i+6]);
      dst[i] = make_uint4(w0,w1,w2,w3);
    }
  }
  __syncthreads();
  // ---- ph3: CQ = Q.K^T -> P (scaled, lower incl diag), overlays A ----
  {
    const int r0 = wave*16;
    f32x4 accs[4];
    #pragma unroll
    for (int ct=0; ct<4; ++ct) accs[ct] = tile64(Qbf, r0, Kbf, ct*16, lane);
    __syncthreads();
    #pragma unroll
    for (int ct=0; ct<4; ++ct) {
      int t = r0 + ((lane>>4)<<2);
      int s = ct*16 + (lane&15);
      #pragma unroll
      for (int q=0;q<4;q++){
        int tq = t + q;
        float val = (s <= tq) ? expf(cgs[tq]-cgs[s])*accs[ct][q] : 0.f;
        Pf[tq*SPITCH + s] = f2bf(val);
      }
    }
  }
  __syncthreads();
  // ---- ph4: output GEMMs ----
  {
    const int r0 = wave*16;
    const float gend = expf(cgs[63]);
    const ushort* Ut = UV;
    const ushort* UtK = UV + 128*SPITCH;
    const size_t bb = ((size_t)bhe*NC_ + c)*(size_t)(64*128);
    const size_t pb = ((size_t)bhe*NC_ + c)*(size_t)QMSZ;
    #pragma unroll
    for (int jt=0; jt<8; ++jt) {
      f32x4 acc = tile64(Pf, r0, Ut, jt*16, lane);
      int t = r0 + ((lane>>4)<<2);
      int j = jt*16 + (lane&15);
      #pragma unroll
      for (int q=0;q<4;q++)
        o_r[((l0 + t + q)*HE_ + he)*DV_ + j] = acc[q];
    }
    #pragma unroll
    for (int jt=0; jt<8; ++jt) {
      f32x4 acc = tile64(KTD, r0, Ut, jt*16, lane);
      int i = r0 + ((lane>>4)<<2);
      int j = jt*16 + (lane&15);
      #pragma unroll
      for (int q=0;q<4;q++)
        Bc[bb + (size_t)(i+q)*128 + j] = acc[q];
    }
    // G5: M_old[m][i] = gend*delta - (KTD*uK^T)[i][m]; store TRANSPOSED MT[i][m]
    // (lane&15 = m consecutive -> 64B-coalesced stores; compose reads rows)
    #pragma unroll
    for (int ct=0; ct<4; ++ct) {
      f32x4 acc = tile64(KTD, r0, UtK, ct*16, lane);
      int i = r0 + ((lane>>4)<<2);
      int m = ct*16 + (lane&15);
      #pragma unroll
      for (int q=0;q<4;q++){
        float val = -acc[q];
        if (i + q == m) val += gend;
        Mc[pb + (size_t)(i+q)*QMP + m] = val;
      }
    }
    #pragma unroll
    for (int ct=0; ct<4; ++ct) {
      f32x4 acc = tile64(Pf, r0, UtK, ct*16, lane);
      int t = r0 + ((lane>>4)<<2);
      int m = ct*16 + (lane&15);
      #pragma unroll
      for (int q=0;q<4;q++)
        Qt[pb + (size_t)(t+q)*QMP + m] = gams[t+q]*bf2f(Qbf[(t+q)*SPITCH + m]) - acc[q];
    }
  }
}

// ---------------- stage one 4352-f32 chunk (Qt or Mc) into LDS ----------------
__device__ __forceinline__ void stage_qm(const float* __restrict__ src, float* dst,
                                         int wave, int lane)
{
  #pragma unroll
  for (int pass = 0; pass < 4; ++pass){
    int cb = pass*256 + wave*64;
    __builtin_amdgcn_global_load_lds(
      (const __attribute__((address_space(1))) void*)(src + (size_t)(cb+lane)*4),
      (__attribute__((address_space(3))) void*)(dst + cb*4), 16, 0, 0);
  }
  if (wave == 0)
    __builtin_amdgcn_global_load_lds(
      (const __attribute__((address_space(1))) void*)(src + 4096 + (size_t)lane*4),
      (__attribute__((address_space(3))) void*)(dst + 4096), 16, 0, 0);
}

// ---------------- fused pass B+C: sequential compose + output correction ----------------
__global__ __launch_bounds__(256) void compose_correct(
    const float* __restrict__ Mc, const float* __restrict__ Bc,
    const float* __restrict__ Qt, float* __restrict__ o_r)
{
  __shared__ float Ql[2][4352];   // staged Qt chunk [t][m] pitch 68
  __shared__ float Ml[2][4352];   // staged MT chunk [i][m] pitch 68
  __shared__ float SSl[1024];     // running state slice [64][16]
  const int bhe = blockIdx.x;
  const int j0  = blockIdx.y * 16;
  const int b = bhe >> 4, he = bhe & 15;
  const int tid = threadIdx.x;
  const int wave = tid >> 6, lane = tid & 63;
  const int rw = tid >> 2;        // row 0..63
  const int jg = tid & 3;         // j quad within slice

  for (int id = tid; id < 1024; id += 256) SSl[id] = 0.f;

  stage_qm(Mc + (size_t)(bhe*NC_)*QMSZ, Ml[0], wave, lane);
  float4 bcur = *(const float4*)&Bc[(size_t)(bhe*NC_)*8192 + rw*128 + j0 + jg*4];
  __syncthreads();

  int p = 0;
  for (int c = 0; c < NC_; ++c){
    float4 bnext = make_float4(0.f,0.f,0.f,0.f);
    if (c+1 < NC_){
      stage_qm(Qt + (size_t)(bhe*NC_ + c + 1)*QMSZ, Ql[p^1], wave, lane);
      if (c+1 < NC_-1){
        stage_qm(Mc + (size_t)(bhe*NC_ + c + 1)*QMSZ, Ml[p^1], wave, lane);
        bnext = *(const float4*)&Bc[(size_t)(bhe*NC_ + c + 1)*8192 + rw*128 + j0 + jg*4];
      }
    }
    const float4* SS4 = (const float4*)SSl;
    // correction: o_r[c] += Qt_c-row(rw) . SS (skip c=0, SS=0)
    if (c > 0){
      float4 oa = make_float4(0.f,0.f,0.f,0.f);
      const float* Qr = Ql[p] + rw*QMP;
      #pragma unroll
      for (int m = 0; m < 64; m += 4){
        float4 qv = *(const float4*)&Qr[m];
        float4 s0 = SS4[(m+0)*4 + jg];
        float4 s1 = SS4[(m+1)*4 + jg];
        float4 s2 = SS4[(m+2)*4 + jg];
        float4 s3 = SS4[(m+3)*4 + jg];
        oa.x += qv.x*s0.x + qv.y*s1.x + qv.z*s2.x + qv.w*s3.x;
        oa.y += qv.x*s0.y + qv.y*s1.y + qv.z*s2.y + qv.w*s3.y;
        oa.z += qv.x*s0.z + qv.y*s1.z + qv.z*s2.z + qv.w*s3.z;
        oa.w += qv.x*s0.w + qv.y*s1.w + qv.z*s2.w + qv.w*s3.w;
      }
      size_t oi = (((size_t)b*L_ + c*T_ + rw)*HE_ + he)*DV_ + j0 + jg*4;
      float4 o = *(float4*)&o_r[oi];
      o.x += oa.x; o.y += oa.y; o.z += oa.z; o.w += oa.w;
      *(float4*)&o_r[oi] = o;
    }
    // update: SS[i=rw] <- sum_m MT[rw][m]*SS[m] + B (skip at last chunk)
    float4 ns = bcur;
    if (c < NC_-1){
      const float* Mr = Ml[p] + rw*QMP;
      #pragma unroll
      for (int m = 0; m < 64; m += 4){
        float4 mv = *(const float4*)&Mr[m];
        float4 s0 = SS4[(m+0)*4 + jg];
        float4 s1 = SS4[(m+1)*4 + jg];
        float4 s2 = SS4[(m+2)*4 + jg];
        float4 s3 = SS4[(m+3)*4 + jg];
        ns.x += mv.x*s0.x + mv.y*s1.x + mv.z*s2.x + mv.w*s3.x;
        ns.y += mv.x*s0.y + mv.y*s1.y + mv.z*s2.y + mv.w*s3.y;
        ns.z += mv.x*s0.z + mv.y*s1.z + mv.z*s2.z + mv.w*s3.z;
        ns.w += mv.x*s0.w + mv.y*s1.w + mv.z*s2.w + mv.w*s3.w;
      }
    }
    __syncthreads();
    if (c < NC_-1) *(float4*)&SSl[rw*16 + jg*4] = ns;
    __syncthreads();     // SS visible + staged c+1 drained
    p ^= 1;
    bcur = bnext;
  }
}

// ---------------- expert combine + RMSNorm*SiLU(gate) -> bf16 ----------------
__global__ __launch_bounds__(128) void combine(const float* __restrict__ o_r,
    const float* __restrict__ w_buf, const float* __restrict__ kvgba,
    const float* __restrict__ norm_w, ushort* __restrict__ o_fin)
{
  int n  = blockIdx.x;
  int h  = n & 3;
  int bl = n >> 2;
  int j  = threadIdx.x;
  size_t wb = (size_t)bl*16 + h*4;
  size_t ob = wb*128 + j;
  float oc = 0.f;
  #pragma unroll
  for (int r = 0; r < 4; r++) oc += w_buf[wb+r] * o_r[ob + (size_t)r*128];
  float ss = oc*oc;
  #pragma unroll
  for (int off = 32; off > 0; off >>= 1) ss += __shfl_xor(ss, off);
  __shared__ float red[2];
  if ((threadIdx.x & 63) == 0) red[threadIdx.x >> 6] = ss;
  __syncthreads();
  float mean = (red[0] + red[1]) * (1.f/128.f);
  float sc = rsqrtf(mean + 1e-5f);
  float gv = kvgba[(size_t)bl*NCAT + 768 + h*128 + j];
  o_fin[(size_t)bl*512 + h*128 + j] = f2bf(oc * sc * norm_w[j] * (gv * sigmoidf_(gv)));
}

extern "C" void kernel_launch(void* const* d_in, const int* in_sizes, int n_in,
                              void* d_out, int out_size, void* d_ws, size_t ws_size,
                              hipStream_t stream)
{
  (void)in_sizes; (void)n_in; (void)out_size; (void)ws_size;
  const float* x       = (const float*)d_in[0];
  const float* Wq      = (const float*)d_in[1];
  const float* Wk      = (const float*)d_in[2];
  const float* Wv      = (const float*)d_in[3];
  const float* Wb      = (const float*)d_in[4];
  const float* Wa      = (const float*)d_in[5];
  const float* Wg      = (const float*)d_in[6];
  const float* Wo      = (const float*)d_in[7];
  const float* conv_q  = (const float*)d_in[8];
  const float* conv_k  = (const float*)d_in[9];
  const float* conv_v  = (const float*)d_in[10];
  const float* Wq_exp  = (const float*)d_in[11];
  const float* Wk_exp  = (const float*)d_in[12];
  const float* W_gate  = (const float*)d_in[13];
  const float* A_log   = (const float*)d_in[14];
  const float* dt_bias = (const float*)d_in[15];
  const float* norm_w  = (const float*)d_in[16];
  float* out = (float*)d_out;

  const size_t BL = (size_t)B_*L_;   // 4096
  float* p = (float*)d_ws;
  float* q_lin  = p; p += BL*256;
  float* kvgba  = p; p += BL*NCAT;
  float* q_conv = p; p += BL*256;
  float* v_conv = p; p += BL*512;
  float* w_buf  = p; p += BL*16;
  float* bt_buf = p; p += BL*16;
  float* g_buf  = p; p += BL*16;
  float* Mc     = p; p += (size_t)B_*HE_*NC_*QMSZ + 256;
  float* Bc     = p; p += (size_t)B_*HE_*NC_*64*128;
  float* Qt     = p; p += (size_t)B_*HE_*NC_*QMSZ + 256;
  float* o_r    = p; p += BL*16*128;
  ushort* xb    = (ushort*)p; p += BL*512;        // x bf16
  ushort* Wcat  = (ushort*)p; p += (NCAT*1024)/2; // concat weights bf16
  ushort* qc_bf = (ushort*)p; p += BL*128;        // q_conv bf16
  ushort* kc_bf = (ushort*)p; p += BL*128;        // k_conv bf16
  ushort* qeb   = (ushort*)p; p += BL*512;        // qe bf16 [4096][1024]
  ushort* keb   = (ushort*)p; p += BL*512;        // ke bf16
  ushort* Wqeb  = (ushort*)p; p += 32768;
  ushort* Wkeb  = (ushort*)p; p += 32768;
  ushort* Wob   = (ushort*)p; p += 262144;        // 1024*512 bf16
  ushort* o_finb= (ushort*)p; p += BL*256;        // bf16 [4096][512]

  // weight prep
  concat_wcat<<<dim3((NCAT*1024+255)/256), dim3(256), 0, stream>>>(Wk, Wv, Wg, Wb, Wa, Wcat);
  { int n = (int)(BL*1024); cast_bf16<<<dim3((n+255)/256), dim3(256), 0, stream>>>(x, xb, n); }
  { int n = 65536;  cast_bf16<<<dim3((n+255)/256), dim3(256), 0, stream>>>(Wq_exp, Wqeb, n); }
  { int n = 65536;  cast_bf16<<<dim3((n+255)/256), dim3(256), 0, stream>>>(Wk_exp, Wkeb, n); }
  { int n = 524288; cast_bf16<<<dim3((n+255)/256), dim3(256), 0, stream>>>(Wo, Wob, n); }

  // projections
  gemm_f32_db<<<dim3(4, 64), dim3(256), 0, stream>>>(x, 1024, Wq, 1024, q_lin, 256, 4096, 256, 1024);
  gemm_bf16<<<dim3(NCAT/128, 32), dim3(256), 0, stream>>>(xb, 1024, Wcat, 1024, kvgba, NCAT, 1024);

  // convs (+SiLU)
  { int tot = B_*L_*256; conv_silu<<<dim3((tot+255)/256), dim3(256), 0, stream>>>(q_lin, 256, conv_q, q_conv, qc_bf, 256, tot); }
  { int tot = B_*L_*256; conv_silu<<<dim3((tot+255)/256), dim3(256), 0, stream>>>(kvgba, NCAT, conv_k, (float*)nullptr, kc_bf, 256, tot); }
  { int tot = B_*L_*512; conv_silu<<<dim3((tot+255)/256), dim3(256), 0, stream>>>(kvgba + 256, NCAT, conv_v, v_conv, (ushort*)nullptr, 512, tot); }

  routing<<<dim3(64), dim3(256), 0, stream>>>(q_conv, kvgba, W_gate, A_log, dt_bias,
                                              w_buf, bt_buf, g_buf);

  gemm_expand_bf16<<<dim3(2, 32, 8), dim3(256), 0, stream>>>(qc_bf, kc_bf, Wqeb, Wkeb, qeb, keb);

  l2norm_rows_bf<<<dim3(16384), dim3(256), 0, stream>>>(qeb, 0.125f);
  l2norm_rows_bf<<<dim3(16384), dim3(256), 0, stream>>>(keb, 1.0f);

  // 1D grid: id = c*32 + bhe -> id%8 = bhe%8 (XCD-aligned with compose_correct)
  scan_chunk_mfma<<<dim3(NC_*HE_*B_), dim3(256), 0, stream>>>(keb, qeb, v_conv, bt_buf, g_buf,
                                                              o_r, Qt, Mc, Bc);
  compose_correct<<<dim3(32, 8), dim3(256), 0, stream>>>(Mc, Bc, Qt, o_r);
  combine<<<dim3(B_*L_*H_), dim3(128), 0, stream>>>(o_r, w_buf, kvgba, norm_w, o_finb);

  gemm_bf16<<<dim3(8, 32), dim3(256), 0, stream>>>(o_finb, 512, Wob, 512, out, 1024, 512);
}

// Round 8
// 360.881 us; speedup vs baseline: 3.0402x; 1.0307x over previous
//
#include <hip/hip_runtime.h>
#include <hip/hip_bf16.h>
#include <math.h>

#define B_    2
#define L_    2048
#define HID_  1024
#define H_    4
#define DK_   64
#define RATIO_ 4
#define HE_   16
#define DV_   128
#define T_    64
#define NC_   32   // L_/T_
#define SPITCH 72  // bf16 LDS row pitch (scan)
#define APITCH 68  // f32 A-matrix LDS pitch (scan)
#define NCAT  1408 // concat projection width: k256 v512 g512 b16 a16 pad96

typedef __attribute__((ext_vector_type(8))) short short8;
typedef __attribute__((ext_vector_type(4))) float f32x4;

__device__ __forceinline__ float sigmoidf_(float x){ return 1.f/(1.f+expf(-x)); }
__device__ __forceinline__ ushort f2bf(float x){
  __hip_bfloat16 h = __float2bfloat16(x);
  return *reinterpret_cast<ushort*>(&h);
}
__device__ __forceinline__ float bf2f(ushort u){
  union { uint32_t i; float f; } v; v.i = ((uint32_t)u) << 16; return v.f;
}
__device__ __forceinline__ void unpk8(uint4 w, float* f){
  f[0]=bf2f((ushort)(w.x&0xffff)); f[1]=bf2f((ushort)(w.x>>16));
  f[2]=bf2f((ushort)(w.y&0xffff)); f[3]=bf2f((ushort)(w.y>>16));
  f[4]=bf2f((ushort)(w.z&0xffff)); f[5]=bf2f((ushort)(w.z>>16));
  f[6]=bf2f((ushort)(w.w&0xffff)); f[7]=bf2f((ushort)(w.w>>16));
}

// ---------------- f32 -> bf16 cast ----------------
__global__ __launch_bounds__(256) void cast_bf16(const float* __restrict__ in,
                                                 ushort* __restrict__ out, int n)
{
  int i = blockIdx.x*256 + threadIdx.x;
  if (i < n) out[i] = f2bf(in[i]);
}

// ---------------- concat weights [k|v|g|b|a|pad] -> bf16 [1408][1024] ----------------
__global__ __launch_bounds__(256) void concat_wcat(const float* __restrict__ Wk,
    const float* __restrict__ Wv, const float* __restrict__ Wg,
    const float* __restrict__ Wb, const float* __restrict__ Wa,
    ushort* __restrict__ Wcat)
{
  int idx = blockIdx.x*256 + threadIdx.x;
  if (idx >= NCAT*1024) return;
  int r = idx >> 10, cc = idx & 1023;
  float v = 0.f;
  if      (r < 256)  v = Wk[(size_t)r*1024 + cc];
  else if (r < 768)  v = Wv[(size_t)(r-256)*1024 + cc];
  else if (r < 1280) v = Wg[(size_t)(r-768)*1024 + cc];
  else if (r < 1296) v = Wb[(size_t)(r-1280)*1024 + cc];
  else if (r < 1312) v = Wa[(size_t)(r-1296)*1024 + cc];
  Wcat[idx] = f2bf(v);
}

// ---------------- bf16 MFMA GEMM (f32 out): C = A(MxK) * B(NxK)^T ----------------
__global__ __launch_bounds__(256) void gemm_bf16(
    const ushort* __restrict__ A, int lda,
    const ushort* __restrict__ Bm, int ldb,
    float* __restrict__ C, int ldc, int K)
{
  __shared__ ushort As[128*32];
  __shared__ ushort Bs[128*32];
  const int tid  = threadIdx.x;
  const int wave = tid >> 6, lane = tid & 63;
  const int row0 = blockIdx.y*128, col0 = blockIdx.x*128;
  const int wr = (wave >> 1) * 64, wc = (wave & 1) * 64;
  const int frow = lane & 15;
  const int fko  = (lane >> 4) << 3;
  f32x4 acc[4][4];
  #pragma unroll
  for (int i=0;i<4;i++)
    #pragma unroll
    for (int j=0;j<4;j++) acc[i][j] = (f32x4){0.f,0.f,0.f,0.f};
  for (int k0 = 0; k0 < K; k0 += 32) {
    #pragma unroll
    for (int cc = 0; cc < 2; cc++) {
      int c  = wave*128 + cc*64 + lane;
      int r  = c >> 2;
      int ko = (c & 3) << 3;
      __builtin_amdgcn_global_load_lds(
        (const __attribute__((address_space(1))) void*)(A + (size_t)(row0+r)*lda + k0 + ko),
        (__attribute__((address_space(3))) void*)(As + (size_t)(wave*128 + cc*64)*8),
        16, 0, 0);
      __builtin_amdgcn_global_load_lds(
        (const __attribute__((address_space(1))) void*)(Bm + (size_t)(col0+r)*ldb + k0 + ko),
        (__attribute__((address_space(3))) void*)(Bs + (size_t)(wave*128 + cc*64)*8),
        16, 0, 0);
    }
    __syncthreads();
    short8 af[4], bfv[4];
    #pragma unroll
    for (int mi=0;mi<4;mi++)
      af[mi] = *reinterpret_cast<const short8*>(&As[(wr + mi*16 + frow)*32 + fko]);
    #pragma unroll
    for (int ni=0;ni<4;ni++)
      bfv[ni] = *reinterpret_cast<const short8*>(&Bs[(wc + ni*16 + frow)*32 + fko]);
    #pragma unroll
    for (int mi=0;mi<4;mi++)
      #pragma unroll
      for (int ni=0;ni<4;ni++)
        acc[mi][ni] = __builtin_amdgcn_mfma_f32_16x16x32_bf16(af[mi], bfv[ni], acc[mi][ni], 0, 0, 0);
    __syncthreads();
  }
  const int ocol = lane & 15;
  const int orow = (lane >> 4) << 2;
  #pragma unroll
  for (int mi=0;mi<4;mi++)
    #pragma unroll
    for (int ni=0;ni<4;ni++) {
      size_t base = (size_t)(row0 + wr + mi*16 + orow)*ldc + (col0 + wc + ni*16 + ocol);
      #pragma unroll
      for (int q=0;q<4;q++) C[base + (size_t)q*ldc] = acc[mi][ni][q];
    }
}

// ---------------- batched bf16 expansion GEMM (bf16 out), z = (q/k)*4 + h ----------------
__global__ __launch_bounds__(256) void gemm_expand_bf16(
    const ushort* __restrict__ qc_bf, const ushort* __restrict__ kc_bf,
    const ushort* __restrict__ Wqeb, const ushort* __restrict__ Wkeb,
    ushort* __restrict__ qeb, ushort* __restrict__ keb)
{
  const int z = blockIdx.z;
  const int hh = z & 3;
  const ushort* A  = (z < 4 ? qc_bf : kc_bf) + hh*64;      // lda 256
  const ushort* Bm = (z < 4 ? Wqeb  : Wkeb ) + (size_t)hh*16384; // ldb 64
  ushort* C        = (z < 4 ? qeb   : keb  ) + hh*256;     // ldc 1024
  const int lda = 256, ldb = 64, ldc = 1024, K = 64;
  __shared__ ushort As[128*32];
  __shared__ ushort Bs[128*32];
  const int tid  = threadIdx.x;
  const int wave = tid >> 6, lane = tid & 63;
  const int row0 = blockIdx.y*128, col0 = blockIdx.x*128;
  const int wr = (wave >> 1) * 64, wc = (wave & 1) * 64;
  const int frow = lane & 15;
  const int fko  = (lane >> 4) << 3;
  f32x4 acc[4][4];
  #pragma unroll
  for (int i=0;i<4;i++)
    #pragma unroll
    for (int j=0;j<4;j++) acc[i][j] = (f32x4){0.f,0.f,0.f,0.f};
  for (int k0 = 0; k0 < K; k0 += 32) {
    #pragma unroll
    for (int cc = 0; cc < 2; cc++) {
      int c  = wave*128 + cc*64 + lane;
      int r  = c >> 2;
      int ko = (c & 3) << 3;
      __builtin_amdgcn_global_load_lds(
        (const __attribute__((address_space(1))) void*)(A + (size_t)(row0+r)*lda + k0 + ko),
        (__attribute__((address_space(3))) void*)(As + (size_t)(wave*128 + cc*64)*8),
        16, 0, 0);
      __builtin_amdgcn_global_load_lds(
        (const __attribute__((address_space(1))) void*)(Bm + (size_t)(col0+r)*ldb + k0 + ko),
        (__attribute__((address_space(3))) void*)(Bs + (size_t)(wave*128 + cc*64)*8),
        16, 0, 0);
    }
    __syncthreads();
    short8 af[4], bfv[4];
    #pragma unroll
    for (int mi=0;mi<4;mi++)
      af[mi] = *reinterpret_cast<const short8*>(&As[(wr + mi*16 + frow)*32 + fko]);
    #pragma unroll
    for (int ni=0;ni<4;ni++)
      bfv[ni] = *reinterpret_cast<const short8*>(&Bs[(wc + ni*16 + frow)*32 + fko]);
    #pragma unroll
    for (int mi=0;mi<4;mi++)
      #pragma unroll
      for (int ni=0;ni<4;ni++)
        acc[mi][ni] = __builtin_amdgcn_mfma_f32_16x16x32_bf16(af[mi], bfv[ni], acc[mi][ni], 0, 0, 0);
    __syncthreads();
  }
  const int ocol = lane & 15;
  const int orow = (lane >> 4) << 2;
  #pragma unroll
  for (int mi=0;mi<4;mi++)
    #pragma unroll
    for (int ni=0;ni<4;ni++) {
      size_t base = (size_t)(row0 + wr + mi*16 + orow)*ldc + (col0 + wc + ni*16 + ocol);
      #pragma unroll
      for (int q=0;q<4;q++) C[base + (size_t)q*ldc] = f2bf(acc[mi][ni][q]);
    }
}

// ---------------- f32 GEMM with double-buffered LDS (Wq): C = A*B^T ----------------
__global__ __launch_bounds__(256) void gemm_f32_db(const float* __restrict__ A, int lda,
    const float* __restrict__ Bm, int ldb, float* __restrict__ C, int ldc,
    int M, int N, int K)
{
  __shared__ float As[2][32][64];
  __shared__ float Bs[2][32][64];
  const int tid = threadIdx.x;
  const int row0 = blockIdx.y * 64;
  const int col0 = blockIdx.x * 64;
  const int tx = tid & 15, ty = tid >> 4;
  const int r0s = tid >> 3;
  const int k4s = (tid & 7) << 2;
  float4 av0, av1, bv0, bv1;

  av0 = *(const float4*)&A[(size_t)(row0 + r0s)*lda + k4s];
  av1 = *(const float4*)&A[(size_t)(row0 + r0s + 32)*lda + k4s];
  bv0 = (col0 + r0s < N) ? *(const float4*)&Bm[(size_t)(col0 + r0s)*ldb + k4s] : make_float4(0,0,0,0);
  bv1 = (col0 + r0s + 32 < N) ? *(const float4*)&Bm[(size_t)(col0 + r0s + 32)*ldb + k4s] : make_float4(0,0,0,0);
  As[0][k4s+0][r0s] = av0.x; As[0][k4s+1][r0s] = av0.y; As[0][k4s+2][r0s] = av0.z; As[0][k4s+3][r0s] = av0.w;
  As[0][k4s+0][r0s+32] = av1.x; As[0][k4s+1][r0s+32] = av1.y; As[0][k4s+2][r0s+32] = av1.z; As[0][k4s+3][r0s+32] = av1.w;
  Bs[0][k4s+0][r0s] = bv0.x; Bs[0][k4s+1][r0s] = bv0.y; Bs[0][k4s+2][r0s] = bv0.z; Bs[0][k4s+3][r0s] = bv0.w;
  Bs[0][k4s+0][r0s+32] = bv1.x; Bs[0][k4s+1][r0s+32] = bv1.y; Bs[0][k4s+2][r0s+32] = bv1.z; Bs[0][k4s+3][r0s+32] = bv1.w;
  __syncthreads();

  float acc[4][4] = {};
  const int nt = K >> 5;
  for (int kt = 0; kt < nt; ++kt) {
    const int p = kt & 1;
    if (kt + 1 < nt) {
      int k0 = (kt+1) << 5;
      av0 = *(const float4*)&A[(size_t)(row0 + r0s)*lda + k0 + k4s];
      av1 = *(const float4*)&A[(size_t)(row0 + r0s + 32)*lda + k0 + k4s];
      bv0 = (col0 + r0s < N) ? *(const float4*)&Bm[(size_t)(col0 + r0s)*ldb + k0 + k4s] : make_float4(0,0,0,0);
      bv1 = (col0 + r0s + 32 < N) ? *(const float4*)&Bm[(size_t)(col0 + r0s + 32)*ldb + k0 + k4s] : make_float4(0,0,0,0);
    }
    #pragma unroll
    for (int kk = 0; kk < 32; kk++) {
      float4 a4 = *(const float4*)&As[p][kk][ty*4];
      float4 b4 = *(const float4*)&Bs[p][kk][tx*4];
      float a[4] = {a4.x,a4.y,a4.z,a4.w};
      float b[4] = {b4.x,b4.y,b4.z,b4.w};
      #pragma unroll
      for (int i=0;i<4;i++)
        #pragma unroll
        for (int j=0;j<4;j++) acc[i][j] += a[i]*b[j];
    }
    if (kt + 1 < nt) {
      const int q = p ^ 1;
      As[q][k4s+0][r0s] = av0.x; As[q][k4s+1][r0s] = av0.y; As[q][k4s+2][r0s] = av0.z; As[q][k4s+3][r0s] = av0.w;
      As[q][k4s+0][r0s+32] = av1.x; As[q][k4s+1][r0s+32] = av1.y; As[q][k4s+2][r0s+32] = av1.z; As[q][k4s+3][r0s+32] = av1.w;
      Bs[q][k4s+0][r0s] = bv0.x; Bs[q][k4s+1][r0s] = bv0.y; Bs[q][k4s+2][r0s] = bv0.z; Bs[q][k4s+3][r0s] = bv0.w;
      Bs[q][k4s+0][r0s+32] = bv1.x; Bs[q][k4s+1][r0s+32] = bv1.y; Bs[q][k4s+2][r0s+32] = bv1.z; Bs[q][k4s+3][r0s+32] = bv1.w;
    }
    __syncthreads();
  }
  #pragma unroll
  for (int i=0;i<4;i++) {
    int r = row0 + ty*4 + i;
    #pragma unroll
    for (int j=0;j<4;j++) {
      int cc = col0 + tx*4 + j;
      if (cc < N) C[(size_t)r*ldc + cc] = acc[i][j];
    }
  }
}

// ---------------- causal depthwise conv (KS=4) + SiLU, optional f32/bf16 outs ----------------
__global__ __launch_bounds__(256) void conv_silu(const float* __restrict__ in, int ild,
    const float* __restrict__ w, float* __restrict__ outf, ushort* __restrict__ outb,
    int C, int total)
{
  int n = blockIdx.x*256 + threadIdx.x;
  if (n >= total) return;
  int c = n % C;
  int t = (n / C) % L_;
  int b = n / (C*L_);
  float acc = 0.f;
  #pragma unroll
  for (int s = 0; s < 4; s++) {
    int tt = t - 3 + s;
    if (tt >= 0) acc += in[((size_t)b*L_ + tt)*ild + c] * w[c*4+s];
  }
  float y = acc * sigmoidf_(acc);
  if (outf) outf[n] = y;
  if (outb) outb[n] = f2bf(y);
}

// ---------------- routing + beta + g ----------------
__global__ __launch_bounds__(256) void routing(const float* __restrict__ qc,
    const float* __restrict__ kvgba, const float* __restrict__ Wg3,
    const float* __restrict__ A_log, const float* __restrict__ dt_bias,
    float* __restrict__ w_buf, float* __restrict__ bt_buf, float* __restrict__ g_buf)
{
  int n = blockIdx.x*256 + threadIdx.x;
  int h  = n & 3;
  int bl = n >> 2;
  const float* q = qc + (size_t)bl*256 + h*64;
  float l0=0.f, l1=0.f, l2=0.f;
  for (int d=0; d<64; d++) {
    float qd = q[d];
    l0 += qd*Wg3[d]; l1 += qd*Wg3[64+d]; l2 += qd*Wg3[128+d];
  }
  float mx = fmaxf(l0, fmaxf(l1, l2));
  float e0 = expf(l0-mx), e1 = expf(l1-mx), e2 = expf(l2-mx);
  float inv_s = 1.f/(e0+e1+e2);
  float p0 = e0*inv_s, p1 = e1*inv_s, p2 = e2*inv_s;
  int m1 = 0; float pm1 = p0;
  if (p1 > pm1) { m1 = 1; pm1 = p1; }
  if (p2 > pm1) { m1 = 2; pm1 = p2; }
  int ia = (m1==0) ? 1 : 0;
  int ib = (m1==2) ? 1 : 2;
  float pa = (m1==0) ? p1 : p0;
  float pb = (m1==2) ? p1 : p2;
  int   m2  = (pb > pa) ? ib : ia;
  float pm2 = (pb > pa) ? pb : pa;
  float inv_w = 1.f/(pm1 + pm2);
  float w1 = 0.5f*pm1*inv_w;
  float w2 = 0.5f*pm2*inv_w;
  #pragma unroll
  for (int r = 0; r < 4; r++) {
    float wr = (r==0) ? 0.5f : (((r-1)==m1) ? w1 : (((r-1)==m2) ? w2 : 0.f));
    int he = h*4 + r;
    size_t gi = (size_t)bl*16 + he;
    w_buf[gi] = wr;
    float mask = (wr > 0.f) ? 1.f : 0.f;
    bt_buf[gi] = mask * sigmoidf_(kvgba[(size_t)bl*NCAT + 1280 + he]);
    float av = kvgba[(size_t)bl*NCAT + 1296 + he] + dt_bias[he];
    float sp = fmaxf(av, 0.f) + log1pf(expf(-fabsf(av)));
    g_buf[gi] = -expf(A_log[he]) * sp * mask;
  }
}

// ---------------- l2norm over rows of 64 (bf16 in/out) ----------------
__global__ __launch_bounds__(256) void l2norm_rows_bf(ushort* __restrict__ v, float scale)
{
  int row  = blockIdx.x*4 + (threadIdx.x >> 6);
  int lane = threadIdx.x & 63;
  size_t idx = (size_t)row*64 + lane;
  float x = bf2f(v[idx]);
  float ss = x*x;
  #pragma unroll
  for (int off = 32; off > 0; off >>= 1) ss += __shfl_xor(ss, off);
  v[idx] = f2bf(x * rsqrtf(ss + 1e-6f) * scale);
}

// ---------------- MFMA tile helper ----------------
__device__ __forceinline__ f32x4 tile64(const ushort* Am, int r0,
                                        const ushort* Bm, int c0, int lane)
{
  f32x4 acc = {0.f,0.f,0.f,0.f};
  const int fr = lane & 15, fo = (lane >> 4) << 3;
  #pragma unroll
  for (int kk = 0; kk < 2; ++kk) {
    short8 a = *reinterpret_cast<const short8*>(&Am[(r0+fr)*SPITCH + fo + kk*32]);
    short8 b = *reinterpret_cast<const short8*>(&Bm[(c0+fr)*SPITCH + fo + kk*32]);
    acc = __builtin_amdgcn_mfma_f32_16x16x32_bf16(a, b, acc, 0, 0, 0);
  }
  return acc;
}

// ---------------- pass A via WY/UT transform + MFMA ----------------
// 1D grid, id = c*32 + bhe -> id%8 = bhe%8: all chunks of a bhe on ONE XCD.
// Mc/Qt stored bf16 [64][64] rows (128B lines), columns granule-swizzled:
// phys_col = ((m>>3)^(row&7))<<3 | (m&7)  (16B-granule XOR, rule m173/m201).
__global__ __launch_bounds__(256,2) void scan_chunk_mfma(
    const ushort* __restrict__ keb, const ushort* __restrict__ qeb,
    const ushort* __restrict__ vcb, const float* __restrict__ bt_buf,
    const float* __restrict__ g_buf, float* __restrict__ o_r,
    ushort* __restrict__ Qtb, ushort* __restrict__ Mcb, ushort* __restrict__ Bcb)
{
  __shared__ float smem[18496];                       // 73984 B
  ushort* Kbf = (ushort*)smem;                        // [64][72] bf16
  ushort* Qbf = (ushort*)(smem + 2304);               // [64][72] bf16
  ushort* KTD = (ushort*)(smem + 4608);               // [64][72] bf16 (K^T, D-scaled)
  float*  Af  = smem + 6912;                          // [64][68] f32 (A matrix)
  ushort* Pf  = (ushort*)(smem + 6912);               // overlay after substitution
  ushort* UV  = (ushort*)(smem + 11264);              // Vbf [64][128] then Ut [192][72]
  float*  cgs = smem + 18176;
  float*  bts = cgs + 64;
  float*  bGs = bts + 64;
  float*  Ds  = bGs + 64;
  float*  gams= Ds + 64;

  const int id = blockIdx.x;
  const int c   = id >> 5;
  const int bhe = id & 31;
  const int b  = bhe >> 4;
  const int he = bhe & 15;
  const int h = he >> 2;
  const int tid = threadIdx.x;
  const int wave = tid >> 6, lane = tid & 63;
  const size_t l0 = (size_t)b*L_ + (size_t)c*T_;

  // ---- ph0a: global loads to regs + g-scan (wave 0) ----
  const int tr = tid >> 2;      // row 0..63
  const int sg = tid & 3;       // quarter
  uint32_t kwv[8], qwv[8];
  uint4 vw0, vw1, vw2, vw3;
  {
    const uint4* kp = (const uint4*)(keb + (l0+tr)*1024 + he*64 + sg*16);
    const uint4* qp = (const uint4*)(qeb + (l0+tr)*1024 + he*64 + sg*16);
    uint4 k0 = kp[0], k1 = kp[1], q0 = qp[0], q1 = qp[1];
    kwv[0]=k0.x; kwv[1]=k0.y; kwv[2]=k0.z; kwv[3]=k0.w;
    kwv[4]=k1.x; kwv[5]=k1.y; kwv[6]=k1.z; kwv[7]=k1.w;
    qwv[0]=q0.x; qwv[1]=q0.y; qwv[2]=q0.z; qwv[3]=q0.w;
    qwv[4]=q1.x; qwv[5]=q1.y; qwv[6]=q1.z; qwv[7]=q1.w;
    const uint4* vp = (const uint4*)(vcb + (l0+tr)*512 + h*128 + sg*32);
    vw0 = vp[0]; vw1 = vp[1]; vw2 = vp[2]; vw3 = vp[3];
  }
  if (tid < 64) {
    float g  = g_buf[(l0+tid)*HE_ + he];
    float bt = bt_buf[(l0+tid)*HE_ + he];
    float cg = g;
    #pragma unroll
    for (int off = 1; off < 64; off <<= 1) {
      float o = __shfl_up(cg, off);
      if (tid >= off) cg += o;
    }
    float cg63 = __shfl(cg, 63);
    cgs[tid] = cg; bts[tid] = bt;
    float gm = expf(cg);
    gams[tid] = gm; bGs[tid] = bt*gm; Ds[tid] = expf(cg63 - cg);
  }
  __syncthreads();
  // ---- ph0b: LDS stores ----
  {
    float Dt = Ds[tr];
    uint2* kdst = (uint2*)(Kbf + tr*SPITCH + sg*16);
    uint2* qdst = (uint2*)(Qbf + tr*SPITCH + sg*16);
    #pragma unroll
    for (int i=0;i<4;i++){
      kdst[i] = make_uint2(kwv[2*i], kwv[2*i+1]);
      qdst[i] = make_uint2(qwv[2*i], qwv[2*i+1]);
    }
    #pragma unroll
    for (int i=0;i<8;i++){
      ushort lo = (ushort)(kwv[i] & 0xffff), hi = (ushort)(kwv[i] >> 16);
      int d = sg*16 + 2*i;
      KTD[(d+0)*SPITCH + tr] = f2bf(bf2f(lo)*Dt);
      KTD[(d+1)*SPITCH + tr] = f2bf(bf2f(hi)*Dt);
    }
    uint4* vdst = (uint4*)(UV + tr*128 + sg*32);
    vdst[0] = vw0; vdst[1] = vw1; vdst[2] = vw2; vdst[3] = vw3;
  }
  __syncthreads();
  // ---- ph1: CK = K.K^T -> A (scaled, strictly lower, zero elsewhere) ----
  {
    const int r0 = wave*16;
    #pragma unroll
    for (int ct=0; ct<4; ++ct) {
      f32x4 acc = tile64(Kbf, r0, Kbf, ct*16, lane);
      int t = r0 + ((lane>>4)<<2);
      int s = ct*16 + (lane&15);
      #pragma unroll
      for (int q=0;q<4;q++){
        int tq = t + q;
        Af[tq*APITCH + s] = (s < tq) ? bts[tq]*expf(cgs[tq]-cgs[s])*acc[q] : 0.f;
      }
    }
  }
  __syncthreads();
  // ---- ph2: forward substitution u = (I+A)^-1 [beta*V | betaGamma*K] ----
  float u[64];
  if (tid < 192) {
    if (tid < 128) {
      const ushort* Vb = UV;
      #pragma unroll
      for (int s=0;s<64;++s) u[s] = bts[s]*bf2f(Vb[s*128 + tid]);
    } else {
      #pragma unroll
      for (int s=0;s<64;++s) u[s] = bGs[s]*bf2f(Kbf[s*SPITCH + (tid-128)]);
    }
  }
  __syncthreads();
  if (tid < 192) {
    #pragma unroll
    for (int t=1;t<64;++t) {
      const float4* Ar = (const float4*)(Af + t*APITCH);
      float p0=0.f,p1=0.f,p2=0.f,p3=0.f;
      #pragma unroll
      for (int s4=0; s4*4<t; ++s4) {
        float4 a = Ar[s4];
        p0 += a.x*u[s4*4+0]; p1 += a.y*u[s4*4+1];
        p2 += a.z*u[s4*4+2]; p3 += a.w*u[s4*4+3];
      }
      u[t] -= (p0+p1)+(p2+p3);
    }
    ushort* Ut = UV;
    uint4* dst = (uint4*)&Ut[tid*SPITCH];
    #pragma unroll
    for (int i=0;i<8;++i) {
      uint32_t w0 = ((uint32_t)f2bf(u[8*i+1])<<16) | f2bf(u[8*i+0]);
      uint32_t w1 = ((uint32_t)f2bf(u[8*i+3])<<16) | f2bf(u[8*i+2]);
      uint32_t w2 = ((uint32_t)f2bf(u[8*i+5])<<16) | f2bf(u[8*i+4]);
      uint32_t w3 = ((uint32_t)f2bf(u[8*i+7])<<16) | f2bf(u[8*i+6]);
      dst[i] = make_uint4(w0,w1,w2,w3);
    }
  }
  __syncthreads();
  // ---- ph3: CQ = Q.K^T -> P (scaled, lower incl diag), overlays A ----
  {
    const int r0 = wave*16;
    f32x4 accs[4];
    #pragma unroll
    for (int ct=0; ct<4; ++ct) accs[ct] = tile64(Qbf, r0, Kbf, ct*16, lane);
    __syncthreads();
    #pragma unroll
    for (int ct=0; ct<4; ++ct) {
      int t = r0 + ((lane>>4)<<2);
      int s = ct*16 + (lane&15);
      #pragma unroll
      for (int q=0;q<4;q++){
        int tq = t + q;
        float val = (s <= tq) ? expf(cgs[tq]-cgs[s])*accs[ct][q] : 0.f;
        Pf[tq*SPITCH + s] = f2bf(val);
      }
    }
  }
  __syncthreads();
  // ---- ph4: output GEMMs ----
  {
    const int r0 = wave*16;
    const float gend = expf(cgs[63]);
    const ushort* Ut = UV;
    const ushort* UtK = UV + 128*SPITCH;
    const size_t bb = ((size_t)bhe*NC_ + c)*(size_t)(64*128);
    const size_t pb = ((size_t)bhe*NC_ + c)*(size_t)(64*64);
    #pragma unroll
    for (int jt=0; jt<8; ++jt) {
      f32x4 acc = tile64(Pf, r0, Ut, jt*16, lane);
      int t = r0 + ((lane>>4)<<2);
      int j = jt*16 + (lane&15);
      #pragma unroll
      for (int q=0;q<4;q++)
        o_r[((l0 + t + q)*HE_ + he)*DV_ + j] = acc[q];
    }
    #pragma unroll
    for (int jt=0; jt<8; ++jt) {
      f32x4 acc = tile64(KTD, r0, Ut, jt*16, lane);
      int i = r0 + ((lane>>4)<<2);
      int j = jt*16 + (lane&15);
      #pragma unroll
      for (int q=0;q<4;q++)
        Bcb[bb + (size_t)(i+q)*128 + j] = f2bf(acc[q]);
    }
    // Mc transposed MT[i][m], bf16, granule-swizzled columns
    #pragma unroll
    for (int ct=0; ct<4; ++ct) {
      f32x4 acc = tile64(KTD, r0, UtK, ct*16, lane);
      int i = r0 + ((lane>>4)<<2);
      int m = ct*16 + (lane&15);
      #pragma unroll
      for (int q=0;q<4;q++){
        float val = -acc[q];
        int row = i + q;
        if (row == m) val += gend;
        int pc = (((m>>3)^(row&7))<<3) | (m&7);
        Mcb[pb + (size_t)row*64 + pc] = f2bf(val);
      }
    }
    #pragma unroll
    for (int ct=0; ct<4; ++ct) {
      f32x4 acc = tile64(Pf, r0, UtK, ct*16, lane);
      int t = r0 + ((lane>>4)<<2);
      int m = ct*16 + (lane&15);
      #pragma unroll
      for (int q=0;q<4;q++){
        int row = t + q;
        int pc = (((m>>3)^(row&7))<<3) | (m&7);
        Qtb[pb + (size_t)row*64 + pc] = f2bf(gams[row]*bf2f(Qbf[row*SPITCH + m]) - acc[q]);
      }
    }
  }
}

// ---------------- stage one 4096-bf16 chunk (Qt or Mc) into LDS ----------------
__device__ __forceinline__ void stage_qm(const ushort* __restrict__ src, ushort* dst,
                                         int wave, int lane)
{
  #pragma unroll
  for (int pass = 0; pass < 2; ++pass){
    int idx = pass*256 + wave*64 + lane;   // 0..511, 16B each
    __builtin_amdgcn_global_load_lds(
      (const __attribute__((address_space(1))) void*)(src + (size_t)idx*8),
      (__attribute__((address_space(3))) void*)(dst + (size_t)idx*8), 16, 0, 0);
  }
}

// ---------------- fused pass B+C: sequential compose + output correction ----------------
// grid (32 bhe, 8 slices): linear id%8 = bhe%8 -> same XCD as producer.
__global__ __launch_bounds__(256) void compose_correct(
    const ushort* __restrict__ Mcb, const ushort* __restrict__ Bcb,
    const ushort* __restrict__ Qtb, float* __restrict__ o_r)
{
  __shared__ ushort Ql[2][4096];  // staged Qt chunk [t][64] swizzled
  __shared__ ushort Ml[2][4096];  // staged MT chunk [i][64] swizzled
  __shared__ float SSl[1024];     // running state slice [64][16]
  const int bhe = blockIdx.x;
  const int j0  = blockIdx.y * 16;
  const int b = bhe >> 4, he = bhe & 15;
  const int tid = threadIdx.x;
  const int wave = tid >> 6, lane = tid & 63;
  const int rw = tid >> 2;        // row 0..63
  const int jg = tid & 3;         // j quad within slice
  const int rsw = rw & 7;         // read-side granule swizzle

  for (int id = tid; id < 1024; id += 256) SSl[id] = 0.f;

  stage_qm(Mcb + (size_t)(bhe*NC_)*4096, Ml[0], wave, lane);
  float4 bcur;
  {
    uint2 bw = *(const uint2*)&Bcb[(size_t)(bhe*NC_)*8192 + rw*128 + j0 + jg*4];
    bcur = make_float4(bf2f((ushort)(bw.x&0xffff)), bf2f((ushort)(bw.x>>16)),
                       bf2f((ushort)(bw.y&0xffff)), bf2f((ushort)(bw.y>>16)));
  }
  __syncthreads();

  int p = 0;
  for (int c = 0; c < NC_; ++c){
    float4 bnext = make_float4(0.f,0.f,0.f,0.f);
    if (c+1 < NC_){
      stage_qm(Qtb + (size_t)(bhe*NC_ + c + 1)*4096, Ql[p^1], wave, lane);
      if (c+1 < NC_-1){
        stage_qm(Mcb + (size_t)(bhe*NC_ + c + 1)*4096, Ml[p^1], wave, lane);
        uint2 bw = *(const uint2*)&Bcb[(size_t)(bhe*NC_ + c + 1)*8192 + rw*128 + j0 + jg*4];
        bnext = make_float4(bf2f((ushort)(bw.x&0xffff)), bf2f((ushort)(bw.x>>16)),
                            bf2f((ushort)(bw.y&0xffff)), bf2f((ushort)(bw.y>>16)));
      }
    }
    const float4* SS4 = (const float4*)SSl;
    // correction: o_r[c] += Qt_c-row(rw) . SS (skip c=0, SS=0)
    if (c > 0){
      float4 oa = make_float4(0.f,0.f,0.f,0.f);
      const ushort* Qr = Ql[p] + rw*64;
      #pragma unroll
      for (int gb = 0; gb < 8; ++gb){
        uint4 w = *(const uint4*)&Qr[(gb ^ rsw) << 3];
        float f[8]; unpk8(w, f);
        #pragma unroll
        for (int e = 0; e < 8; ++e){
          float4 s = SS4[(gb*8+e)*4 + jg];
          oa.x += f[e]*s.x; oa.y += f[e]*s.y; oa.z += f[e]*s.z; oa.w += f[e]*s.w;
        }
      }
      size_t oi = (((size_t)b*L_ + c*T_ + rw)*HE_ + he)*DV_ + j0 + jg*4;
      float4 o = *(float4*)&o_r[oi];
      o.x += oa.x; o.y += oa.y; o.z += oa.z; o.w += oa.w;
      *(float4*)&o_r[oi] = o;
    }
    // update: SS[i=rw] <- sum_m MT[rw][m]*SS[m] + B (skip at last chunk)
    float4 ns = bcur;
    if (c < NC_-1){
      const ushort* Mr = Ml[p] + rw*64;
      #pragma unroll
      for (int gb = 0; gb < 8; ++gb){
        uint4 w = *(const uint4*)&Mr[(gb ^ rsw) << 3];
        float f[8]; unpk8(w, f);
        #pragma unroll
        for (int e = 0; e < 8; ++e){
          float4 s = SS4[(gb*8+e)*4 + jg];
          ns.x += f[e]*s.x; ns.y += f[e]*s.y; ns.z += f[e]*s.z; ns.w += f[e]*s.w;
        }
      }
    }
    __syncthreads();
    if (c < NC_-1) *(float4*)&SSl[rw*16 + jg*4] = ns;
    __syncthreads();     // SS visible + staged c+1 drained
    p ^= 1;
    bcur = bnext;
  }
}

// ---------------- expert combine + RMSNorm*SiLU(gate) -> bf16 ----------------
__global__ __launch_bounds__(128) void combine(const float* __restrict__ o_r,
    const float* __restrict__ w_buf, const float* __restrict__ kvgba,
    const float* __restrict__ norm_w, ushort* __restrict__ o_fin)
{
  int n  = blockIdx.x;
  int h  = n & 3;
  int bl = n >> 2;
  int j  = threadIdx.x;
  size_t wb = (size_t)bl*16 + h*4;
  size_t ob = wb*128 + j;
  float oc = 0.f;
  #pragma unroll
  for (int r = 0; r < 4; r++) oc += w_buf[wb+r] * o_r[ob + (size_t)r*128];
  float ss = oc*oc;
  #pragma unroll
  for (int off = 32; off > 0; off >>= 1) ss += __shfl_xor(ss, off);
  __shared__ float red[2];
  if ((threadIdx.x & 63) == 0) red[threadIdx.x >> 6] = ss;
  __syncthreads();
  float mean = (red[0] + red[1]) * (1.f/128.f);
  float sc = rsqrtf(mean + 1e-5f);
  float gv = kvgba[(size_t)bl*NCAT + 768 + h*128 + j];
  o_fin[(size_t)bl*512 + h*128 + j] = f2bf(oc * sc * norm_w[j] * (gv * sigmoidf_(gv)));
}

extern "C" void kernel_launch(void* const* d_in, const int* in_sizes, int n_in,
                              void* d_out, int out_size, void* d_ws, size_t ws_size,
                              hipStream_t stream)
{
  (void)in_sizes; (void)n_in; (void)out_size; (void)ws_size;
  const float* x       = (const float*)d_in[0];
  const float* Wq      = (const float*)d_in[1];
  const float* Wk      = (const float*)d_in[2];
  const float* Wv      = (const float*)d_in[3];
  const float* Wb      = (const float*)d_in[4];
  const float* Wa      = (const float*)d_in[5];
  const float* Wg      = (const float*)d_in[6];
  const float* Wo      = (const float*)d_in[7];
  const float* conv_q  = (const float*)d_in[8];
  const float* conv_k  = (const float*)d_in[9];
  const float* conv_v  = (const float*)d_in[10];
  const float* Wq_exp  = (const float*)d_in[11];
  const float* Wk_exp  = (const float*)d_in[12];
  const float* W_gate  = (const float*)d_in[13];
  const float* A_log   = (const float*)d_in[14];
  const float* dt_bias = (const float*)d_in[15];
  const float* norm_w  = (const float*)d_in[16];
  float* out = (float*)d_out;

  const size_t BL = (size_t)B_*L_;   // 4096
  float* p = (float*)d_ws;
  float* q_lin  = p; p += BL*256;
  float* kvgba  = p; p += BL*NCAT;
  float* q_conv = p; p += BL*256;
  float* w_buf  = p; p += BL*16;
  float* bt_buf = p; p += BL*16;
  float* g_buf  = p; p += BL*16;
  float* o_r    = p; p += BL*16*128;
  ushort* Mcb   = (ushort*)p; p += (size_t)B_*HE_*NC_*2048;  // bf16 [chunk][64][64]
  ushort* Qtb   = (ushort*)p; p += (size_t)B_*HE_*NC_*2048;
  ushort* Bcb   = (ushort*)p; p += (size_t)B_*HE_*NC_*4096;  // bf16 [chunk][64][128]
  ushort* v_convb=(ushort*)p; p += BL*256;        // v bf16 [bl][512]
  ushort* xb    = (ushort*)p; p += BL*512;        // x bf16
  ushort* Wcat  = (ushort*)p; p += (NCAT*1024)/2; // concat weights bf16
  ushort* qc_bf = (ushort*)p; p += BL*128;        // q_conv bf16
  ushort* kc_bf = (ushort*)p; p += BL*128;        // k_conv bf16
  ushort* qeb   = (ushort*)p; p += BL*512;        // qe bf16 [4096][1024]
  ushort* keb   = (ushort*)p; p += BL*512;        // ke bf16
  ushort* Wqeb  = (ushort*)p; p += 32768;
  ushort* Wkeb  = (ushort*)p; p += 32768;
  ushort* Wob   = (ushort*)p; p += 262144;        // 1024*512 bf16
  ushort* o_finb= (ushort*)p; p += BL*256;        // bf16 [4096][512]

  // weight prep
  concat_wcat<<<dim3((NCAT*1024+255)/256), dim3(256), 0, stream>>>(Wk, Wv, Wg, Wb, Wa, Wcat);
  { int n = (int)(BL*1024); cast_bf16<<<dim3((n+255)/256), dim3(256), 0, stream>>>(x, xb, n); }
  { int n = 65536;  cast_bf16<<<dim3((n+255)/256), dim3(256), 0, stream>>>(Wq_exp, Wqeb, n); }
  { int n = 65536;  cast_bf16<<<dim3((n+255)/256), dim3(256), 0, stream>>>(Wk_exp, Wkeb, n); }
  { int n = 524288; cast_bf16<<<dim3((n+255)/256), dim3(256), 0, stream>>>(Wo, Wob, n); }

  // projections
  gemm_f32_db<<<dim3(4, 64), dim3(256), 0, stream>>>(x, 1024, Wq, 1024, q_lin, 256, 4096, 256, 1024);
  gemm_bf16<<<dim3(NCAT/128, 32), dim3(256), 0, stream>>>(xb, 1024, Wcat, 1024, kvgba, NCAT, 1024);

  // convs (+SiLU)
  { int tot = B_*L_*256; conv_silu<<<dim3((tot+255)/256), dim3(256), 0, stream>>>(q_lin, 256, conv_q, q_conv, qc_bf, 256, tot); }
  { int tot = B_*L_*256; conv_silu<<<dim3((tot+255)/256), dim3(256), 0, stream>>>(kvgba, NCAT, conv_k, (float*)nullptr, kc_bf, 256, tot); }
  { int tot = B_*L_*512; conv_silu<<<dim3((tot+255)/256), dim3(256), 0, stream>>>(kvgba + 256, NCAT, conv_v, (float*)nullptr, v_convb, 512, tot); }

  routing<<<dim3(64), dim3(256), 0, stream>>>(q_conv, kvgba, W_gate, A_log, dt_bias,
                                              w_buf, bt_buf, g_buf);

  gemm_expand_bf16<<<dim3(2, 32, 8), dim3(256), 0, stream>>>(qc_bf, kc_bf, Wqeb, Wkeb, qeb, keb);

  l2norm_rows_bf<<<dim3(16384), dim3(256), 0, stream>>>(qeb, 0.125f);
  l2norm_rows_bf<<<dim3(16384), dim3(256), 0, stream>>>(keb, 1.0f);

  // 1D grid: id = c*32 + bhe -> id%8 = bhe%8 (XCD-aligned with compose_correct)
  scan_chunk_mfma<<<dim3(NC_*HE_*B_), dim3(256), 0, stream>>>(keb, qeb, v_convb, bt_buf, g_buf,
                                                              o_r, Qtb, Mcb, Bcb);
  compose_correct<<<dim3(32, 8), dim3(256), 0, stream>>>(Mcb, Bcb, Qtb, o_r);
  combine<<<dim3(B_*L_*H_), dim3(128), 0, stream>>>(o_r, w_buf, kvgba, norm_w, o_finb);

  gemm_bf16<<<dim3(8, 32), dim3(256), 0, stream>>>(o_finb, 512, Wob, 512, out, 1024, 512);
}

// Round 9
// 358.079 us; speedup vs baseline: 3.0640x; 1.0078x over previous
//
#include <hip/hip_runtime.h>
#include <hip/hip_bf16.h>
#include <math.h>

#define B_    2
#define L_    2048
#define HID_  1024
#define H_    4
#define DK_   64
#define RATIO_ 4
#define HE_   16
#define DV_   128
#define T_    64
#define NC_   32   // L_/T_
#define SPITCH 72  // bf16 LDS row pitch (scan)
#define APITCH 68  // f32 A-matrix LDS pitch (scan)
#define NCAT  1408 // concat projection width: k256 v512 g512 b16 a16 pad96

typedef __attribute__((ext_vector_type(8))) short short8;
typedef __attribute__((ext_vector_type(4))) float f32x4;

__device__ __forceinline__ float sigmoidf_(float x){ return 1.f/(1.f+expf(-x)); }
__device__ __forceinline__ ushort f2bf(float x){
  __hip_bfloat16 h = __float2bfloat16(x);
  return *reinterpret_cast<ushort*>(&h);
}
__device__ __forceinline__ float bf2f(ushort u){
  union { uint32_t i; float f; } v; v.i = ((uint32_t)u) << 16; return v.f;
}
__device__ __forceinline__ uint32_t pk2(float a, float b){
  return ((uint32_t)f2bf(b) << 16) | f2bf(a);
}
__device__ __forceinline__ void unpk8(uint4 w, float* f){
  f[0]=bf2f((ushort)(w.x&0xffff)); f[1]=bf2f((ushort)(w.x>>16));
  f[2]=bf2f((ushort)(w.y&0xffff)); f[3]=bf2f((ushort)(w.y>>16));
  f[4]=bf2f((ushort)(w.z&0xffff)); f[5]=bf2f((ushort)(w.z>>16));
  f[6]=bf2f((ushort)(w.w&0xffff)); f[7]=bf2f((ushort)(w.w>>16));
}

// ---------------- f32 -> bf16 cast ----------------
__global__ __launch_bounds__(256) void cast_bf16(const float* __restrict__ in,
                                                 ushort* __restrict__ out, int n)
{
  int i = blockIdx.x*256 + threadIdx.x;
  if (i < n) out[i] = f2bf(in[i]);
}

// ---------------- concat weights [k|v|g|b|a|pad] -> bf16 [1408][1024] ----------------
__global__ __launch_bounds__(256) void concat_wcat(const float* __restrict__ Wk,
    const float* __restrict__ Wv, const float* __restrict__ Wg,
    const float* __restrict__ Wb, const float* __restrict__ Wa,
    ushort* __restrict__ Wcat)
{
  int idx = blockIdx.x*256 + threadIdx.x;
  if (idx >= NCAT*1024) return;
  int r = idx >> 10, cc = idx & 1023;
  float v = 0.f;
  if      (r < 256)  v = Wk[(size_t)r*1024 + cc];
  else if (r < 768)  v = Wv[(size_t)(r-256)*1024 + cc];
  else if (r < 1280) v = Wg[(size_t)(r-768)*1024 + cc];
  else if (r < 1296) v = Wb[(size_t)(r-1280)*1024 + cc];
  else if (r < 1312) v = Wa[(size_t)(r-1296)*1024 + cc];
  Wcat[idx] = f2bf(v);
}

// ---------------- bf16 MFMA GEMM (f32 out): C = A(MxK) * B(NxK)^T ----------------
__global__ __launch_bounds__(256) void gemm_bf16(
    const ushort* __restrict__ A, int lda,
    const ushort* __restrict__ Bm, int ldb,
    float* __restrict__ C, int ldc, int K)
{
  __shared__ ushort As[128*32];
  __shared__ ushort Bs[128*32];
  const int tid  = threadIdx.x;
  const int wave = tid >> 6, lane = tid & 63;
  const int row0 = blockIdx.y*128, col0 = blockIdx.x*128;
  const int wr = (wave >> 1) * 64, wc = (wave & 1) * 64;
  const int frow = lane & 15;
  const int fko  = (lane >> 4) << 3;
  f32x4 acc[4][4];
  #pragma unroll
  for (int i=0;i<4;i++)
    #pragma unroll
    for (int j=0;j<4;j++) acc[i][j] = (f32x4){0.f,0.f,0.f,0.f};
  for (int k0 = 0; k0 < K; k0 += 32) {
    #pragma unroll
    for (int cc = 0; cc < 2; cc++) {
      int c  = wave*128 + cc*64 + lane;
      int r  = c >> 2;
      int ko = (c & 3) << 3;
      __builtin_amdgcn_global_load_lds(
        (const __attribute__((address_space(1))) void*)(A + (size_t)(row0+r)*lda + k0 + ko),
        (__attribute__((address_space(3))) void*)(As + (size_t)(wave*128 + cc*64)*8),
        16, 0, 0);
      __builtin_amdgcn_global_load_lds(
        (const __attribute__((address_space(1))) void*)(Bm + (size_t)(col0+r)*ldb + k0 + ko),
        (__attribute__((address_space(3))) void*)(Bs + (size_t)(wave*128 + cc*64)*8),
        16, 0, 0);
    }
    __syncthreads();
    short8 af[4], bfv[4];
    #pragma unroll
    for (int mi=0;mi<4;mi++)
      af[mi] = *reinterpret_cast<const short8*>(&As[(wr + mi*16 + frow)*32 + fko]);
    #pragma unroll
    for (int ni=0;ni<4;ni++)
      bfv[ni] = *reinterpret_cast<const short8*>(&Bs[(wc + ni*16 + frow)*32 + fko]);
    #pragma unroll
    for (int mi=0;mi<4;mi++)
      #pragma unroll
      for (int ni=0;ni<4;ni++)
        acc[mi][ni] = __builtin_amdgcn_mfma_f32_16x16x32_bf16(af[mi], bfv[ni], acc[mi][ni], 0, 0, 0);
    __syncthreads();
  }
  const int ocol = lane & 15;
  const int orow = (lane >> 4) << 2;
  #pragma unroll
  for (int mi=0;mi<4;mi++)
    #pragma unroll
    for (int ni=0;ni<4;ni++) {
      size_t base = (size_t)(row0 + wr + mi*16 + orow)*ldc + (col0 + wc + ni*16 + ocol);
      #pragma unroll
      for (int q=0;q<4;q++) C[base + (size_t)q*ldc] = acc[mi][ni][q];
    }
}

// ---------------- batched bf16 expansion GEMM (bf16 out), z = (q/k)*4 + h ----------------
__global__ __launch_bounds__(256) void gemm_expand_bf16(
    const ushort* __restrict__ qc_bf, const ushort* __restrict__ kc_bf,
    const ushort* __restrict__ Wqeb, const ushort* __restrict__ Wkeb,
    ushort* __restrict__ qeb, ushort* __restrict__ keb)
{
  const int z = blockIdx.z;
  const int hh = z & 3;
  const ushort* A  = (z < 4 ? qc_bf : kc_bf) + hh*64;      // lda 256
  const ushort* Bm = (z < 4 ? Wqeb  : Wkeb ) + (size_t)hh*16384; // ldb 64
  ushort* C        = (z < 4 ? qeb   : keb  ) + hh*256;     // ldc 1024
  const int lda = 256, ldb = 64, ldc = 1024, K = 64;
  __shared__ ushort As[128*32];
  __shared__ ushort Bs[128*32];
  const int tid  = threadIdx.x;
  const int wave = tid >> 6, lane = tid & 63;
  const int row0 = blockIdx.y*128, col0 = blockIdx.x*128;
  const int wr = (wave >> 1) * 64, wc = (wave & 1) * 64;
  const int frow = lane & 15;
  const int fko  = (lane >> 4) << 3;
  f32x4 acc[4][4];
  #pragma unroll
  for (int i=0;i<4;i++)
    #pragma unroll
    for (int j=0;j<4;j++) acc[i][j] = (f32x4){0.f,0.f,0.f,0.f};
  for (int k0 = 0; k0 < K; k0 += 32) {
    #pragma unroll
    for (int cc = 0; cc < 2; cc++) {
      int c  = wave*128 + cc*64 + lane;
      int r  = c >> 2;
      int ko = (c & 3) << 3;
      __builtin_amdgcn_global_load_lds(
        (const __attribute__((address_space(1))) void*)(A + (size_t)(row0+r)*lda + k0 + ko),
        (__attribute__((address_space(3))) void*)(As + (size_t)(wave*128 + cc*64)*8),
        16, 0, 0);
      __builtin_amdgcn_global_load_lds(
        (const __attribute__((address_space(1))) void*)(Bm + (size_t)(col0+r)*ldb + k0 + ko),
        (__attribute__((address_space(3))) void*)(Bs + (size_t)(wave*128 + cc*64)*8),
        16, 0, 0);
    }
    __syncthreads();
    short8 af[4], bfv[4];
    #pragma unroll
    for (int mi=0;mi<4;mi++)
      af[mi] = *reinterpret_cast<const short8*>(&As[(wr + mi*16 + frow)*32 + fko]);
    #pragma unroll
    for (int ni=0;ni<4;ni++)
      bfv[ni] = *reinterpret_cast<const short8*>(&Bs[(wc + ni*16 + frow)*32 + fko]);
    #pragma unroll
    for (int mi=0;mi<4;mi++)
      #pragma unroll
      for (int ni=0;ni<4;ni++)
        acc[mi][ni] = __builtin_amdgcn_mfma_f32_16x16x32_bf16(af[mi], bfv[ni], acc[mi][ni], 0, 0, 0);
    __syncthreads();
  }
  const int ocol = lane & 15;
  const int orow = (lane >> 4) << 2;
  #pragma unroll
  for (int mi=0;mi<4;mi++)
    #pragma unroll
    for (int ni=0;ni<4;ni++) {
      size_t base = (size_t)(row0 + wr + mi*16 + orow)*ldc + (col0 + wc + ni*16 + ocol);
      #pragma unroll
      for (int q=0;q<4;q++) C[base + (size_t)q*ldc] = f2bf(acc[mi][ni][q]);
    }
}

// ---------------- f32 GEMM with double-buffered LDS (Wq): C = A*B^T ----------------
__global__ __launch_bounds__(256) void gemm_f32_db(const float* __restrict__ A, int lda,
    const float* __restrict__ Bm, int ldb, float* __restrict__ C, int ldc,
    int M, int N, int K)
{
  __shared__ float As[2][32][64];
  __shared__ float Bs[2][32][64];
  const int tid = threadIdx.x;
  const int row0 = blockIdx.y * 64;
  const int col0 = blockIdx.x * 64;
  const int tx = tid & 15, ty = tid >> 4;
  const int r0s = tid >> 3;
  const int k4s = (tid & 7) << 2;
  float4 av0, av1, bv0, bv1;

  av0 = *(const float4*)&A[(size_t)(row0 + r0s)*lda + k4s];
  av1 = *(const float4*)&A[(size_t)(row0 + r0s + 32)*lda + k4s];
  bv0 = (col0 + r0s < N) ? *(const float4*)&Bm[(size_t)(col0 + r0s)*ldb + k4s] : make_float4(0,0,0,0);
  bv1 = (col0 + r0s + 32 < N) ? *(const float4*)&Bm[(size_t)(col0 + r0s + 32)*ldb + k4s] : make_float4(0,0,0,0);
  As[0][k4s+0][r0s] = av0.x; As[0][k4s+1][r0s] = av0.y; As[0][k4s+2][r0s] = av0.z; As[0][k4s+3][r0s] = av0.w;
  As[0][k4s+0][r0s+32] = av1.x; As[0][k4s+1][r0s+32] = av1.y; As[0][k4s+2][r0s+32] = av1.z; As[0][k4s+3][r0s+32] = av1.w;
  Bs[0][k4s+0][r0s] = bv0.x; Bs[0][k4s+1][r0s] = bv0.y; Bs[0][k4s+2][r0s] = bv0.z; Bs[0][k4s+3][r0s] = bv0.w;
  Bs[0][k4s+0][r0s+32] = bv1.x; Bs[0][k4s+1][r0s+32] = bv1.y; Bs[0][k4s+2][r0s+32] = bv1.z; Bs[0][k4s+3][r0s+32] = bv1.w;
  __syncthreads();

  float acc[4][4] = {};
  const int nt = K >> 5;
  for (int kt = 0; kt < nt; ++kt) {
    const int p = kt & 1;
    if (kt + 1 < nt) {
      int k0 = (kt+1) << 5;
      av0 = *(const float4*)&A[(size_t)(row0 + r0s)*lda + k0 + k4s];
      av1 = *(const float4*)&A[(size_t)(row0 + r0s + 32)*lda + k0 + k4s];
      bv0 = (col0 + r0s < N) ? *(const float4*)&Bm[(size_t)(col0 + r0s)*ldb + k0 + k4s] : make_float4(0,0,0,0);
      bv1 = (col0 + r0s + 32 < N) ? *(const float4*)&Bm[(size_t)(col0 + r0s + 32)*ldb + k0 + k4s] : make_float4(0,0,0,0);
    }
    #pragma unroll
    for (int kk = 0; kk < 32; kk++) {
      float4 a4 = *(const float4*)&As[p][kk][ty*4];
      float4 b4 = *(const float4*)&Bs[p][kk][tx*4];
      float a[4] = {a4.x,a4.y,a4.z,a4.w};
      float b[4] = {b4.x,b4.y,b4.z,b4.w};
      #pragma unroll
      for (int i=0;i<4;i++)
        #pragma unroll
        for (int j=0;j<4;j++) acc[i][j] += a[i]*b[j];
    }
    if (kt + 1 < nt) {
      const int q = p ^ 1;
      As[q][k4s+0][r0s] = av0.x; As[q][k4s+1][r0s] = av0.y; As[q][k4s+2][r0s] = av0.z; As[q][k4s+3][r0s] = av0.w;
      As[q][k4s+0][r0s+32] = av1.x; As[q][k4s+1][r0s+32] = av1.y; As[q][k4s+2][r0s+32] = av1.z; As[q][k4s+3][r0s+32] = av1.w;
      Bs[q][k4s+0][r0s] = bv0.x; Bs[q][k4s+1][r0s] = bv0.y; Bs[q][k4s+2][r0s] = bv0.z; Bs[q][k4s+3][r0s] = bv0.w;
      Bs[q][k4s+0][r0s+32] = bv1.x; Bs[q][k4s+1][r0s+32] = bv1.y; Bs[q][k4s+2][r0s+32] = bv1.z; Bs[q][k4s+3][r0s+32] = bv1.w;
    }
    __syncthreads();
  }
  #pragma unroll
  for (int i=0;i<4;i++) {
    int r = row0 + ty*4 + i;
    #pragma unroll
    for (int j=0;j<4;j++) {
      int cc = col0 + tx*4 + j;
      if (cc < N) C[(size_t)r*ldc + cc] = acc[i][j];
    }
  }
}

// ---------------- causal depthwise conv (KS=4) + SiLU, optional f32/bf16 outs ----------------
__global__ __launch_bounds__(256) void conv_silu(const float* __restrict__ in, int ild,
    const float* __restrict__ w, float* __restrict__ outf, ushort* __restrict__ outb,
    int C, int total)
{
  int n = blockIdx.x*256 + threadIdx.x;
  if (n >= total) return;
  int c = n % C;
  int t = (n / C) % L_;
  int b = n / (C*L_);
  float acc = 0.f;
  #pragma unroll
  for (int s = 0; s < 4; s++) {
    int tt = t - 3 + s;
    if (tt >= 0) acc += in[((size_t)b*L_ + tt)*ild + c] * w[c*4+s];
  }
  float y = acc * sigmoidf_(acc);
  if (outf) outf[n] = y;
  if (outb) outb[n] = f2bf(y);
}

// ---------------- routing + beta + g (bt/g stored TRANSPOSED [he][BL]) ----------------
__global__ __launch_bounds__(256) void routing(const float* __restrict__ qc,
    const float* __restrict__ kvgba, const float* __restrict__ Wg3,
    const float* __restrict__ A_log, const float* __restrict__ dt_bias,
    float* __restrict__ w_buf, float* __restrict__ bt_T, float* __restrict__ g_T)
{
  int n = blockIdx.x*256 + threadIdx.x;
  int h  = n & 3;
  int bl = n >> 2;
  const float* q = qc + (size_t)bl*256 + h*64;
  float l0=0.f, l1=0.f, l2=0.f;
  for (int d=0; d<64; d++) {
    float qd = q[d];
    l0 += qd*Wg3[d]; l1 += qd*Wg3[64+d]; l2 += qd*Wg3[128+d];
  }
  float mx = fmaxf(l0, fmaxf(l1, l2));
  float e0 = expf(l0-mx), e1 = expf(l1-mx), e2 = expf(l2-mx);
  float inv_s = 1.f/(e0+e1+e2);
  float p0 = e0*inv_s, p1 = e1*inv_s, p2 = e2*inv_s;
  int m1 = 0; float pm1 = p0;
  if (p1 > pm1) { m1 = 1; pm1 = p1; }
  if (p2 > pm1) { m1 = 2; pm1 = p2; }
  int ia = (m1==0) ? 1 : 0;
  int ib = (m1==2) ? 1 : 2;
  float pa = (m1==0) ? p1 : p0;
  float pb = (m1==2) ? p1 : p2;
  int   m2  = (pb > pa) ? ib : ia;
  float pm2 = (pb > pa) ? pb : pa;
  float inv_w = 1.f/(pm1 + pm2);
  float w1 = 0.5f*pm1*inv_w;
  float w2 = 0.5f*pm2*inv_w;
  #pragma unroll
  for (int r = 0; r < 4; r++) {
    float wr = (r==0) ? 0.5f : (((r-1)==m1) ? w1 : (((r-1)==m2) ? w2 : 0.f));
    int he = h*4 + r;
    w_buf[(size_t)bl*16 + he] = wr;
    float mask = (wr > 0.f) ? 1.f : 0.f;
    bt_T[(size_t)he*4096 + bl] = mask * sigmoidf_(kvgba[(size_t)bl*NCAT + 1280 + he]);
    float av = kvgba[(size_t)bl*NCAT + 1296 + he] + dt_bias[he];
    float sp = fmaxf(av, 0.f) + log1pf(expf(-fabsf(av)));
    g_T[(size_t)he*4096 + bl] = -expf(A_log[he]) * sp * mask;
  }
}

// ---------------- MFMA tile helper ----------------
__device__ __forceinline__ f32x4 tile64(const ushort* Am, int r0,
                                        const ushort* Bm, int c0, int lane)
{
  f32x4 acc = {0.f,0.f,0.f,0.f};
  const int fr = lane & 15, fo = (lane >> 4) << 3;
  #pragma unroll
  for (int kk = 0; kk < 2; ++kk) {
    short8 a = *reinterpret_cast<const short8*>(&Am[(r0+fr)*SPITCH + fo + kk*32]);
    short8 b = *reinterpret_cast<const short8*>(&Bm[(c0+fr)*SPITCH + fo + kk*32]);
    acc = __builtin_amdgcn_mfma_f32_16x16x32_bf16(a, b, acc, 0, 0, 0);
  }
  return acc;
}

// ---------------- pass A via WY/UT transform + MFMA, fused l2norm ----------------
// 1D grid, id = c*32 + s, s = r*8 + b*4 + h -> id%8 = (b*4+h): all 4 experts of
// (b,h) AND all chunks of a bhe on ONE XCD (V fetched once; compose L2-local).
__global__ __launch_bounds__(256,2) void scan_chunk_mfma(
    const ushort* __restrict__ keb, const ushort* __restrict__ qeb,
    const ushort* __restrict__ vcb, const float* __restrict__ bt_T,
    const float* __restrict__ g_T, ushort* __restrict__ o0b,
    ushort* __restrict__ Qtb, ushort* __restrict__ Mcb, ushort* __restrict__ Bcb)
{
  __shared__ float smem[18496];                       // 73984 B
  ushort* Kbf = (ushort*)smem;                        // [64][72] bf16 (l2-normalized)
  ushort* Qbf = (ushort*)(smem + 2304);               // [64][72] bf16 (l2-normalized*0.125)
  ushort* KTD = (ushort*)(smem + 4608);               // [64][72] bf16 (K^T, D-scaled)
  float*  Af  = smem + 6912;                          // [64][68] f32 (A matrix)
  ushort* Pf  = (ushort*)(smem + 6912);               // overlay after substitution
  ushort* UV  = (ushort*)(smem + 11264);              // Vbf [64][128] then Ut [192][72]
  float*  cgs = smem + 18176;
  float*  bts = cgs + 64;
  float*  bGs = bts + 64;
  float*  Ds  = bGs + 64;
  float*  gams= Ds + 64;

  const int id = blockIdx.x;
  const int c  = id >> 5;
  const int s  = id & 31;
  const int h  = s & 3;
  const int b  = (s >> 2) & 1;
  const int r  = s >> 3;
  const int he = h*4 + r;
  const int bhe = b*HE_ + he;
  const int tid = threadIdx.x;
  const int wave = tid >> 6, lane = tid & 63;
  const size_t l0 = (size_t)b*L_ + (size_t)c*T_;

  // ---- ph0a: global loads + per-row l2norm (quad shfl reduce) + g-scan ----
  const int tr = tid >> 2;      // row 0..63
  const int sg = tid & 3;       // quarter
  float kf[16], qf[16];
  uint4 vw0, vw1, vw2, vw3;
  float sk, sq;
  {
    const uint4* kp = (const uint4*)(keb + (l0+tr)*1024 + he*64 + sg*16);
    const uint4* qp = (const uint4*)(qeb + (l0+tr)*1024 + he*64 + sg*16);
    uint4 kv[2] = {kp[0], kp[1]};
    uint4 qv[2] = {qp[0], qp[1]};
    unpk8(kv[0], kf); unpk8(kv[1], kf+8);
    unpk8(qv[0], qf); unpk8(qv[1], qf+8);
    float ssk = 0.f, ssq = 0.f;
    #pragma unroll
    for (int i=0;i<16;i++){ ssk += kf[i]*kf[i]; ssq += qf[i]*qf[i]; }
    ssk += __shfl_xor(ssk, 1); ssk += __shfl_xor(ssk, 2);
    ssq += __shfl_xor(ssq, 1); ssq += __shfl_xor(ssq, 2);
    sk = rsqrtf(ssk + 1e-6f);
    sq = rsqrtf(ssq + 1e-6f) * 0.125f;   // DK^-0.5
    const uint4* vp = (const uint4*)(vcb + (l0+tr)*512 + h*128 + sg*32);
    vw0 = vp[0]; vw1 = vp[1]; vw2 = vp[2]; vw3 = vp[3];
  }
  if (tid < 64) {
    float g  = g_T[(size_t)he*4096 + l0 + tid];
    float bt = bt_T[(size_t)he*4096 + l0 + tid];
    float cg = g;
    #pragma unroll
    for (int off = 1; off < 64; off <<= 1) {
      float o = __shfl_up(cg, off);
      if (tid >= off) cg += o;
    }
    float cg63 = __shfl(cg, 63);
    cgs[tid] = cg; bts[tid] = bt;
    float gm = expf(cg);
    gams[tid] = gm; bGs[tid] = bt*gm; Ds[tid] = expf(cg63 - cg);
  }
  __syncthreads();
  // ---- ph0b: LDS stores (normalized) ----
  {
    float Dt = Ds[tr];
    uint2* kdst = (uint2*)(Kbf + tr*SPITCH + sg*16);
    uint2* qdst = (uint2*)(Qbf + tr*SPITCH + sg*16);
    #pragma unroll
    for (int i=0;i<4;i++){
      kdst[i] = make_uint2(pk2(kf[4*i+0]*sk, kf[4*i+1]*sk), pk2(kf[4*i+2]*sk, kf[4*i+3]*sk));
      qdst[i] = make_uint2(pk2(qf[4*i+0]*sq, qf[4*i+1]*sq), pk2(qf[4*i+2]*sq, qf[4*i+3]*sq));
    }
    float skD = sk*Dt;
    #pragma unroll
    for (int i=0;i<16;i++){
      int d = sg*16 + i;
      KTD[d*SPITCH + tr] = f2bf(kf[i]*skD);
    }
    uint4* vdst = (uint4*)(UV + tr*128 + sg*32);
    vdst[0] = vw0; vdst[1] = vw1; vdst[2] = vw2; vdst[3] = vw3;
  }
  __syncthreads();
  // ---- ph1: CK = K.K^T -> A (scaled, strictly lower, zero elsewhere) ----
  {
    const int r0 = wave*16;
    #pragma unroll
    for (int ct=0; ct<4; ++ct) {
      f32x4 acc = tile64(Kbf, r0, Kbf, ct*16, lane);
      int t = r0 + ((lane>>4)<<2);
      int ss = ct*16 + (lane&15);
      #pragma unroll
      for (int q=0;q<4;q++){
        int tq = t + q;
        Af[tq*APITCH + ss] = (ss < tq) ? bts[tq]*expf(cgs[tq]-cgs[ss])*acc[q] : 0.f;
      }
    }
  }
  __syncthreads();
  // ---- ph2: forward substitution u = (I+A)^-1 [beta*V | betaGamma*K] ----
  float u[64];
  if (tid < 192) {
    if (tid < 128) {
      const ushort* Vb = UV;
      #pragma unroll
      for (int ss=0;ss<64;++ss) u[ss] = bts[ss]*bf2f(Vb[ss*128 + tid]);
    } else {
      #pragma unroll
      for (int ss=0;ss<64;++ss) u[ss] = bGs[ss]*bf2f(Kbf[ss*SPITCH + (tid-128)]);
    }
  }
  __syncthreads();
  if (tid < 192) {
    #pragma unroll
    for (int t=1;t<64;++t) {
      const float4* Ar = (const float4*)(Af + t*APITCH);
      float p0=0.f,p1=0.f,p2=0.f,p3=0.f;
      #pragma unroll
      for (int s4=0; s4*4<t; ++s4) {
        float4 a = Ar[s4];
        p0 += a.x*u[s4*4+0]; p1 += a.y*u[s4*4+1];
        p2 += a.z*u[s4*4+2]; p3 += a.w*u[s4*4+3];
      }
      u[t] -= (p0+p1)+(p2+p3);
    }
    ushort* Ut = UV;
    uint4* dst = (uint4*)&Ut[tid*SPITCH];
    #pragma unroll
    for (int i=0;i<8;++i)
      dst[i] = make_uint4(pk2(u[8*i+0],u[8*i+1]), pk2(u[8*i+2],u[8*i+3]),
                          pk2(u[8*i+4],u[8*i+5]), pk2(u[8*i+6],u[8*i+7]));
  }
  __syncthreads();
  // ---- ph3: CQ = Q.K^T -> P (scaled, lower incl diag), overlays A ----
  {
    const int r0 = wave*16;
    f32x4 accs[4];
    #pragma unroll
    for (int ct=0; ct<4; ++ct) accs[ct] = tile64(Qbf, r0, Kbf, ct*16, lane);
    __syncthreads();
    #pragma unroll
    for (int ct=0; ct<4; ++ct) {
      int t = r0 + ((lane>>4)<<2);
      int ss = ct*16 + (lane&15);
      #pragma unroll
      for (int q=0;q<4;q++){
        int tq = t + q;
        float val = (ss <= tq) ? expf(cgs[tq]-cgs[ss])*accs[ct][q] : 0.f;
        Pf[tq*SPITCH + ss] = f2bf(val);
      }
    }
  }
  __syncthreads();
  // ---- ph4: output GEMMs ----
  {
    const int r0 = wave*16;
    const float gend = expf(cgs[63]);
    const ushort* Ut = UV;
    const ushort* UtK = UV + 128*SPITCH;
    const size_t bb = ((size_t)bhe*NC_ + c)*(size_t)(64*128);
    const size_t pb = ((size_t)bhe*NC_ + c)*(size_t)(64*64);
    #pragma unroll
    for (int jt=0; jt<8; ++jt) {
      f32x4 acc = tile64(Pf, r0, Ut, jt*16, lane);
      int t = r0 + ((lane>>4)<<2);
      int j = jt*16 + (lane&15);
      #pragma unroll
      for (int q=0;q<4;q++)
        o0b[((l0 + t + q)*HE_ + he)*DV_ + j] = f2bf(acc[q]);
    }
    #pragma unroll
    for (int jt=0; jt<8; ++jt) {
      f32x4 acc = tile64(KTD, r0, Ut, jt*16, lane);
      int i = r0 + ((lane>>4)<<2);
      int j = jt*16 + (lane&15);
      #pragma unroll
      for (int q=0;q<4;q++)
        Bcb[bb + (size_t)(i+q)*128 + j] = f2bf(acc[q]);
    }
    // Mc transposed MT[i][m], bf16, granule-swizzled columns
    #pragma unroll
    for (int ct=0; ct<4; ++ct) {
      f32x4 acc = tile64(KTD, r0, UtK, ct*16, lane);
      int i = r0 + ((lane>>4)<<2);
      int m = ct*16 + (lane&15);
      #pragma unroll
      for (int q=0;q<4;q++){
        float val = -acc[q];
        int row = i + q;
        if (row == m) val += gend;
        int pc = (((m>>3)^(row&7))<<3) | (m&7);
        Mcb[pb + (size_t)row*64 + pc] = f2bf(val);
      }
    }
    #pragma unroll
    for (int ct=0; ct<4; ++ct) {
      f32x4 acc = tile64(Pf, r0, UtK, ct*16, lane);
      int t = r0 + ((lane>>4)<<2);
      int m = ct*16 + (lane&15);
      #pragma unroll
      for (int q=0;q<4;q++){
        int row = t + q;
        int pc = (((m>>3)^(row&7))<<3) | (m&7);
        Qtb[pb + (size_t)row*64 + pc] = f2bf(gams[row]*bf2f(Qbf[row*SPITCH + m]) - acc[q]);
      }
    }
  }
}

// ---------------- stage one 4096-bf16 chunk (Qt or Mc) into LDS ----------------
__device__ __forceinline__ void stage_qm(const ushort* __restrict__ src, ushort* dst,
                                         int wave, int lane)
{
  #pragma unroll
  for (int pass = 0; pass < 2; ++pass){
    int idx = pass*256 + wave*64 + lane;   // 0..511, 16B each
    __builtin_amdgcn_global_load_lds(
      (const __attribute__((address_space(1))) void*)(src + (size_t)idx*8),
      (__attribute__((address_space(3))) void*)(dst + (size_t)idx*8), 16, 0, 0);
  }
}

// ---------------- fused pass B+C: sequential compose + correction (write-only) -----
// grid (32 s, 8 slices): linear id%8 = s%8 = b*4+h -> same XCD as producer.
__global__ __launch_bounds__(256) void compose_correct(
    const ushort* __restrict__ Mcb, const ushort* __restrict__ Bcb,
    const ushort* __restrict__ Qtb, ushort* __restrict__ o_corrb)
{
  __shared__ ushort Ql[2][4096];  // staged Qt chunk [t][64] swizzled
  __shared__ ushort Ml[2][4096];  // staged MT chunk [i][64] swizzled
  __shared__ float SSl[1024];     // running state slice [64][16]
  const int s   = blockIdx.x;
  const int h   = s & 3;
  const int b   = (s >> 2) & 1;
  const int r   = s >> 3;
  const int he  = h*4 + r;
  const int bhe = b*HE_ + he;
  const int j0  = blockIdx.y * 16;
  const int tid = threadIdx.x;
  const int wave = tid >> 6, lane = tid & 63;
  const int rw = tid >> 2;        // row 0..63
  const int jg = tid & 3;         // j quad within slice
  const int rsw = rw & 7;         // read-side granule swizzle

  for (int id = tid; id < 1024; id += 256) SSl[id] = 0.f;

  stage_qm(Mcb + (size_t)(bhe*NC_)*4096, Ml[0], wave, lane);
  float4 bcur;
  {
    uint2 bw = *(const uint2*)&Bcb[(size_t)(bhe*NC_)*8192 + rw*128 + j0 + jg*4];
    bcur = make_float4(bf2f((ushort)(bw.x&0xffff)), bf2f((ushort)(bw.x>>16)),
                       bf2f((ushort)(bw.y&0xffff)), bf2f((ushort)(bw.y>>16)));
  }
  __syncthreads();

  int p = 0;
  for (int c = 0; c < NC_; ++c){
    float4 bnext = make_float4(0.f,0.f,0.f,0.f);
    if (c+1 < NC_){
      stage_qm(Qtb + (size_t)(bhe*NC_ + c + 1)*4096, Ql[p^1], wave, lane);
      if (c+1 < NC_-1){
        stage_qm(Mcb + (size_t)(bhe*NC_ + c + 1)*4096, Ml[p^1], wave, lane);
        uint2 bw = *(const uint2*)&Bcb[(size_t)(bhe*NC_ + c + 1)*8192 + rw*128 + j0 + jg*4];
        bnext = make_float4(bf2f((ushort)(bw.x&0xffff)), bf2f((ushort)(bw.x>>16)),
                            bf2f((ushort)(bw.y&0xffff)), bf2f((ushort)(bw.y>>16)));
      }
    }
    const float4* SS4 = (const float4*)SSl;
    // correction term (zero at c=0) -> o_corrb (write-only, no RMW)
    float4 oa = make_float4(0.f,0.f,0.f,0.f);
    if (c > 0){
      const ushort* Qr = Ql[p] + rw*64;
      #pragma unroll
      for (int gb = 0; gb < 8; ++gb){
        uint4 w = *(const uint4*)&Qr[(gb ^ rsw) << 3];
        float f[8]; unpk8(w, f);
        #pragma unroll
        for (int e = 0; e < 8; ++e){
          float4 sv = SS4[(gb*8+e)*4 + jg];
          oa.x += f[e]*sv.x; oa.y += f[e]*sv.y; oa.z += f[e]*sv.z; oa.w += f[e]*sv.w;
        }
      }
    }
    {
      size_t oi = (((size_t)b*L_ + c*T_ + rw)*HE_ + he)*DV_ + j0 + jg*4;
      *(uint2*)&o_corrb[oi] = make_uint2(pk2(oa.x, oa.y), pk2(oa.z, oa.w));
    }
    // update: SS[i=rw] <- sum_m MT[rw][m]*SS[m] + B (skip at last chunk)
    float4 ns = bcur;
    if (c < NC_-1){
      const ushort* Mr = Ml[p] + rw*64;
      #pragma unroll
      for (int gb = 0; gb < 8; ++gb){
        uint4 w = *(const uint4*)&Mr[(gb ^ rsw) << 3];
        float f[8]; unpk8(w, f);
        #pragma unroll
        for (int e = 0; e < 8; ++e){
          float4 sv = SS4[(gb*8+e)*4 + jg];
          ns.x += f[e]*sv.x; ns.y += f[e]*sv.y; ns.z += f[e]*sv.z; ns.w += f[e]*sv.w;
        }
      }
    }
    __syncthreads();
    if (c < NC_-1) *(float4*)&SSl[rw*16 + jg*4] = ns;
    __syncthreads();     // SS visible + staged c+1 drained
    p ^= 1;
    bcur = bnext;
  }
}

// ---------------- expert combine + RMSNorm*SiLU(gate) -> bf16 ----------------
__global__ __launch_bounds__(128) void combine(const ushort* __restrict__ o0b,
    const ushort* __restrict__ o_corrb, const float* __restrict__ w_buf,
    const float* __restrict__ kvgba, const float* __restrict__ norm_w,
    ushort* __restrict__ o_fin)
{
  int n  = blockIdx.x;
  int h  = n & 3;
  int bl = n >> 2;
  int j  = threadIdx.x;
  size_t wb = (size_t)bl*16 + h*4;
  size_t ob = wb*128 + j;
  float oc = 0.f;
  #pragma unroll
  for (int r = 0; r < 4; r++){
    size_t oi = ob + (size_t)r*128;
    oc += w_buf[wb+r] * (bf2f(o0b[oi]) + bf2f(o_corrb[oi]));
  }
  float ss = oc*oc;
  #pragma unroll
  for (int off = 32; off > 0; off >>= 1) ss += __shfl_xor(ss, off);
  __shared__ float red[2];
  if ((threadIdx.x & 63) == 0) red[threadIdx.x >> 6] = ss;
  __syncthreads();
  float mean = (red[0] + red[1]) * (1.f/128.f);
  float sc = rsqrtf(mean + 1e-5f);
  float gv = kvgba[(size_t)bl*NCAT + 768 + h*128 + j];
  o_fin[(size_t)bl*512 + h*128 + j] = f2bf(oc * sc * norm_w[j] * (gv * sigmoidf_(gv)));
}

extern "C" void kernel_launch(void* const* d_in, const int* in_sizes, int n_in,
                              void* d_out, int out_size, void* d_ws, size_t ws_size,
                              hipStream_t stream)
{
  (void)in_sizes; (void)n_in; (void)out_size; (void)ws_size;
  const float* x       = (const float*)d_in[0];
  const float* Wq      = (const float*)d_in[1];
  const float* Wk      = (const float*)d_in[2];
  const float* Wv      = (const float*)d_in[3];
  const float* Wb      = (const float*)d_in[4];
  const float* Wa      = (const float*)d_in[5];
  const float* Wg      = (const float*)d_in[6];
  const float* Wo      = (const float*)d_in[7];
  const float* conv_q  = (const float*)d_in[8];
  const float* conv_k  = (const float*)d_in[9];
  const float* conv_v  = (const float*)d_in[10];
  const float* Wq_exp  = (const float*)d_in[11];
  const float* Wk_exp  = (const float*)d_in[12];
  const float* W_gate  = (const float*)d_in[13];
  const float* A_log   = (const float*)d_in[14];
  const float* dt_bias = (const float*)d_in[15];
  const float* norm_w  = (const float*)d_in[16];
  float* out = (float*)d_out;

  const size_t BL = (size_t)B_*L_;   // 4096
  float* p = (float*)d_ws;
  float* q_lin  = p; p += BL*256;
  float* kvgba  = p; p += BL*NCAT;
  float* q_conv = p; p += BL*256;
  float* w_buf  = p; p += BL*16;
  float* bt_T   = p; p += BL*16;   // [16][4096]
  float* g_T    = p; p += BL*16;   // [16][4096]
  ushort* o0b   = (ushort*)p; p += BL*16*64;   // bf16 [bl][16][128]
  ushort* o_corrb=(ushort*)p; p += BL*16*64;   // bf16 [bl][16][128]
  ushort* Mcb   = (ushort*)p; p += (size_t)B_*HE_*NC_*2048;  // bf16 [chunk][64][64]
  ushort* Qtb   = (ushort*)p; p += (size_t)B_*HE_*NC_*2048;
  ushort* Bcb   = (ushort*)p; p += (size_t)B_*HE_*NC_*4096;  // bf16 [chunk][64][128]
  ushort* v_convb=(ushort*)p; p += BL*256;        // v bf16 [bl][512]
  ushort* xb    = (ushort*)p; p += BL*512;        // x bf16
  ushort* Wcat  = (ushort*)p; p += (NCAT*1024)/2; // concat weights bf16
  ushort* qc_bf = (ushort*)p; p += BL*128;        // q_conv bf16
  ushort* kc_bf = (ushort*)p; p += BL*128;        // k_conv bf16
  ushort* qeb   = (ushort*)p; p += BL*512;        // qe bf16 [4096][1024]
  ushort* keb   = (ushort*)p; p += BL*512;        // ke bf16
  ushort* Wqeb  = (ushort*)p; p += 32768;
  ushort* Wkeb  = (ushort*)p; p += 32768;
  ushort* Wob   = (ushort*)p; p += 262144;        // 1024*512 bf16
  ushort* o_finb= (ushort*)p; p += BL*256;        // bf16 [4096][512]

  // weight prep
  concat_wcat<<<dim3((NCAT*1024+255)/256), dim3(256), 0, stream>>>(Wk, Wv, Wg, Wb, Wa, Wcat);
  { int n = (int)(BL*1024); cast_bf16<<<dim3((n+255)/256), dim3(256), 0, stream>>>(x, xb, n); }
  { int n = 65536;  cast_bf16<<<dim3((n+255)/256), dim3(256), 0, stream>>>(Wq_exp, Wqeb, n); }
  { int n = 65536;  cast_bf16<<<dim3((n+255)/256), dim3(256), 0, stream>>>(Wk_exp, Wkeb, n); }
  { int n = 524288; cast_bf16<<<dim3((n+255)/256), dim3(256), 0, stream>>>(Wo, Wob, n); }

  // projections
  gemm_f32_db<<<dim3(4, 64), dim3(256), 0, stream>>>(x, 1024, Wq, 1024, q_lin, 256, 4096, 256, 1024);
  gemm_bf16<<<dim3(NCAT/128, 32), dim3(256), 0, stream>>>(xb, 1024, Wcat, 1024, kvgba, NCAT, 1024);

  // convs (+SiLU)
  { int tot = B_*L_*256; conv_silu<<<dim3((tot+255)/256), dim3(256), 0, stream>>>(q_lin, 256, conv_q, q_conv, qc_bf, 256, tot); }
  { int tot = B_*L_*256; conv_silu<<<dim3((tot+255)/256), dim3(256), 0, stream>>>(kvgba, NCAT, conv_k, (float*)nullptr, kc_bf, 256, tot); }
  { int tot = B_*L_*512; conv_silu<<<dim3((tot+255)/256), dim3(256), 0, stream>>>(kvgba + 256, NCAT, conv_v, (float*)nullptr, v_convb, 512, tot); }

  routing<<<dim3(64), dim3(256), 0, stream>>>(q_conv, kvgba, W_gate, A_log, dt_bias,
                                              w_buf, bt_T, g_T);

  gemm_expand_bf16<<<dim3(2, 32, 8), dim3(256), 0, stream>>>(qc_bf, kc_bf, Wqeb, Wkeb, qeb, keb);

  // scan (fused l2norm): id = c*32 + s, s = r*8 + b*4 + h
  scan_chunk_mfma<<<dim3(NC_*HE_*B_), dim3(256), 0, stream>>>(keb, qeb, v_convb, bt_T, g_T,
                                                              o0b, Qtb, Mcb, Bcb);
  compose_correct<<<dim3(32, 8), dim3(256), 0, stream>>>(Mcb, Bcb, Qtb, o_corrb);
  combine<<<dim3(B_*L_*H_), dim3(128), 0, stream>>>(o0b, o_corrb, w_buf, kvgba, norm_w, o_finb);

  gemm_bf16<<<dim3(8, 32), dim3(256), 0, stream>>>(o_finb, 512, Wob, 512, out, 1024, 512);
}